// Round 3
// baseline (2721.388 us; speedup 1.0000x reference)
//
#include <hip/hip_runtime.h>
#include <hip/hip_bf16.h>

#define H 4
#define D 32
#define HD 128
#define ND 10000
#define NG 30000
#define E_DG 150000
#define E_GD 150000
#define E_GG 300000
#define NE (E_DG + E_GD + E_GG)
#define NLAYER 2

typedef __hip_bfloat16 bf16;

__device__ __forceinline__ float bu(unsigned short u) {
    return __uint_as_float(((unsigned)u) << 16);
}
__device__ __forceinline__ int f2ord(float f) {
    int b = __float_as_int(f);
    return (b >= 0) ? b : (b ^ 0x7fffffff);
}
__device__ __forceinline__ float ord2f(int k) {
    return __int_as_float((k >= 0) ? k : (k ^ 0x7fffffff));
}
__device__ __forceinline__ float gelu(float v) {
    // jax.nn.gelu default (approximate=True, tanh form)
    const float c = 0.79788456080286536f * (v + 0.044715f * v * v * v);
    return 0.5f * v * (1.0f + tanhf(c));
}

// ---------------------------------------------------------------------------
// Input dtype detection: genuine bf16 N(0,1) data never has |v| > 1e6; fp32
// data misread as bf16 has many huge/inf/NaN values in its low halves.
// flag=1 -> inputs are fp32; flag=0 -> inputs are bf16.
__global__ void k_detect(const unsigned short* __restrict__ x, int* __restrict__ flag) {
    int bad = 0;
    for (int i = threadIdx.x; i < 4096; i += 256) {
        const float v = bu(x[i]);
        if (!(fabsf(v) < 1e6f)) bad = 1;  // catches huge, inf, NaN
    }
    if (bad) atomicOr(flag, 1);
}

// ---------------------------------------------------------------------------
// Batched conversion of all float inputs -> canonical fp32 ws buffers.
#define NSEG 15
struct CvtDesc {
    const void* src[NSEG];
    float* dst[NSEG];
    int nelem[NSEG];
    int blk0[NSEG];   // prefix of ceil(n/1024)
};

__global__ __launch_bounds__(256) void k_cvt_all(CvtDesc d, const int* __restrict__ flag) {
    const int b = blockIdx.x;
    int s = 0;
    while (s + 1 < NSEG && b >= d.blk0[s + 1]) s++;
    const int i0 = (b - d.blk0[s]) * 1024 + threadIdx.x * 4;
    const int n = d.nelem[s];
    if (i0 >= n) return;
    const bool isf32 = (*flag != 0);
    float* dst = d.dst[s];
    if (i0 + 4 <= n) {
        float4 v;
        if (isf32) {
            v = *(const float4*)((const float*)d.src[s] + i0);
        } else {
            const ushort4 u = *(const ushort4*)((const unsigned short*)d.src[s] + i0);
            v = make_float4(bu(u.x), bu(u.y), bu(u.z), bu(u.w));
        }
        *(float4*)(dst + i0) = v;
    } else {
        for (int j = i0; j < n; j++)
            dst[j] = isf32 ? ((const float*)d.src[s])[j] : bu(((const unsigned short*)d.src[s])[j]);
    }
}

// ---------------------------------------------------------------------------
// Fused KQV projection + per-edge-type relation transform (per node type).
// Block = 192 threads, 16 nodes per block.
// GENE=0: outputs qtab, k0 = k . relA0, v0 = v . relM0
// GENE=1: additionally k1 = k . relA1, v1 = v . relM1
template <int GENE>
__global__ __launch_bounds__(192) void k_kqv(
    const float* __restrict__ x,          // [N][128] fp32
    const float* __restrict__ W,          // [128][384] (layer slice, fp32 canonical)
    const float* __restrict__ bias,       // [384]
    const float* __restrict__ relA0, const float* __restrict__ relM0,
    const float* __restrict__ relA1, const float* __restrict__ relM1,
    bf16* __restrict__ qtab,
    bf16* __restrict__ k0, bf16* __restrict__ v0,
    bf16* __restrict__ k1, bf16* __restrict__ v1) {
    __shared__ float xs[16 * HD];     // [n][d]
    __shared__ float kqv[16 * 384];   // [n][o]
    const int tid = threadIdx.x;
    const int node0 = blockIdx.x * 16;

    for (int f4 = tid; f4 < 512; f4 += 192) {
        const int n = f4 >> 5, dp = f4 & 31;
        const float4 v = *(const float4*)(x + (size_t)(node0 + n) * HD + dp * 4);
        *(float4*)(xs + n * HD + dp * 4) = v;
    }
    __syncthreads();

    float acc0[16], acc1[16];
#pragma unroll
    for (int n = 0; n < 16; n++) { acc0[n] = 0.f; acc1[n] = 0.f; }
    const int o0 = tid, o1 = tid + 192;
    for (int d = 0; d < HD; d += 4) {
        float4 xv[16];
#pragma unroll
        for (int n = 0; n < 16; n++) xv[n] = *(const float4*)(xs + n * HD + d);
#pragma unroll
        for (int j = 0; j < 4; j++) {
            const float w0 = W[(d + j) * 384 + o0];
            const float w1 = W[(d + j) * 384 + o1];
#pragma unroll
            for (int n = 0; n < 16; n++) {
                const float xvn = ((const float*)&xv[n])[j];
                acc0[n] = fmaf(xvn, w0, acc0[n]);
                acc1[n] = fmaf(xvn, w1, acc1[n]);
            }
        }
    }
    const float bb0 = bias[o0];
    const float bb1 = bias[o1];
#pragma unroll
    for (int n = 0; n < 16; n++) { acc0[n] += bb0; acc1[n] += bb1; }
#pragma unroll
    for (int n = 0; n < 16; n++) {
        kqv[n * 384 + o0] = acc0[n];
        kqv[n * 384 + o1] = acc1[n];
    }
    // q columns are 128..255 -> write straight to qtab (bf16)
    if (o0 >= 128) {
#pragma unroll
        for (int n = 0; n < 16; n++)
            qtab[(size_t)(node0 + n) * HD + (o0 - 128)] = __float2bfloat16(acc0[n]);
    }
    if (o1 < 256) {
#pragma unroll
        for (int n = 0; n < 16; n++)
            qtab[(size_t)(node0 + n) * HD + (o1 - 128)] = __float2bfloat16(acc1[n]);
    }
    __syncthreads();

    // relation transforms: out[n][h*32+f] = sum_dd kqv[n][src+h*32+dd] * mat[h][dd][f]
    const int ncols = GENE ? 512 : 256;
    for (int j = tid; j < ncols; j += 192) {
        const int set = j >> 7;       // 0:k.A0 1:v.M0 2:k.A1 3:v.M1
        const int jj = j & 127;
        const int h = jj >> 5, f = jj & 31;
        const int srcoff = (set & 1) ? 256 : 0;
        const float* mat = (set == 0) ? relA0 : (set == 1) ? relM0 : (set == 2) ? relA1 : relM1;
        bf16* outp = (set == 0) ? k0 : (set == 1) ? v0 : (set == 2) ? k1 : v1;
        mat += h * D * D + f;
        float acc[16];
#pragma unroll
        for (int n = 0; n < 16; n++) acc[n] = 0.f;
        for (int dd = 0; dd < D; dd++) {
            const float m = mat[dd * D];
            const int coff = srcoff + h * D + dd;
#pragma unroll
            for (int n = 0; n < 16; n++)
                acc[n] = fmaf(kqv[n * 384 + coff], m, acc[n]);
        }
#pragma unroll
        for (int n = 0; n < 16; n++)
            outp[(size_t)(node0 + n) * HD + jj] = __float2bfloat16(acc[n]);
    }
}

// ---------------------------------------------------------------------------
// Pass A: per-edge attention logits + segment max (int-encoded atomicMax).
// 32 lanes per edge; lane i covers dims 4i..4i+3 (head = i>>3).
__global__ __launch_bounds__(256) void k_edge_alpha(
    const int* __restrict__ src_dg, const int* __restrict__ dst_dg,
    const int* __restrict__ src_gd, const int* __restrict__ dst_gd,
    const int* __restrict__ src_gg, const int* __restrict__ dst_gg,
    const bf16* __restrict__ qd, const bf16* __restrict__ qg,
    const bf16* __restrict__ kd0, const bf16* __restrict__ kg1,
    const bf16* __restrict__ kg2,
    const float* __restrict__ prel,    // [3][H] layer slice (fp32)
    float* __restrict__ alpha,
    int* __restrict__ amaxd, int* __restrict__ amaxg) {
    const int e = blockIdx.x * 8 + (threadIdx.x >> 5);
    if (e >= NE) return;
    const int lane = threadIdx.x & 31;
    const int *srcp, *dstp;
    const bf16 *qt, *kt;
    int* am;
    int et, el;
    if (e < E_DG) {
        et = 0; el = e; srcp = src_dg; dstp = dst_dg; qt = qg; kt = kd0; am = amaxg;
    } else if (e < E_DG + E_GD) {
        et = 1; el = e - E_DG; srcp = src_gd; dstp = dst_gd; qt = qd; kt = kg1; am = amaxd;
    } else {
        et = 2; el = e - (E_DG + E_GD); srcp = src_gg; dstp = dst_gg; qt = qg; kt = kg2; am = amaxg;
    }
    const int s = srcp[el], dn = dstp[el];
    const ushort4 qu = *(const ushort4*)(qt + (size_t)dn * HD + lane * 4);
    const ushort4 ku = *(const ushort4*)(kt + (size_t)s * HD + lane * 4);
    float p = bu(qu.x) * bu(ku.x) + bu(qu.y) * bu(ku.y) +
              bu(qu.z) * bu(ku.z) + bu(qu.w) * bu(ku.w);
    p += __shfl_xor(p, 1);
    p += __shfl_xor(p, 2);
    p += __shfl_xor(p, 4);
    if ((lane & 7) == 0) {
        const int h = lane >> 3;
        const float a = p * 0.17677669529663689f * prel[et * H + h];
        alpha[(size_t)e * H + h] = a;
        atomicMax(am + dn * H + h, f2ord(a));
    }
}

// ---------------------------------------------------------------------------
// Pass B: ex = exp(a - amax); den += ex; agg[dst] += ex * v_rel[src]
__global__ __launch_bounds__(256) void k_edge_agg(
    const int* __restrict__ src_dg, const int* __restrict__ dst_dg,
    const int* __restrict__ src_gd, const int* __restrict__ dst_gd,
    const int* __restrict__ src_gg, const int* __restrict__ dst_gg,
    const bf16* __restrict__ vd0, const bf16* __restrict__ vg1,
    const bf16* __restrict__ vg2,
    const float* __restrict__ alpha,
    const int* __restrict__ amaxd, const int* __restrict__ amaxg,
    float* __restrict__ dend, float* __restrict__ deng,
    float* __restrict__ aggd, float* __restrict__ aggg) {
    const int e = blockIdx.x * 8 + (threadIdx.x >> 5);
    if (e >= NE) return;
    const int lane = threadIdx.x & 31;
    const int *srcp, *dstp;
    const bf16* vt;
    const int* am;
    float *den, *agg;
    int el;
    if (e < E_DG) {
        el = e; srcp = src_dg; dstp = dst_dg; vt = vd0; am = amaxg; den = deng; agg = aggg;
    } else if (e < E_DG + E_GD) {
        el = e - E_DG; srcp = src_gd; dstp = dst_gd; vt = vg1; am = amaxd; den = dend; agg = aggd;
    } else {
        el = e - (E_DG + E_GD); srcp = src_gg; dstp = dst_gg; vt = vg2; am = amaxg; den = deng; agg = aggg;
    }
    const int s = srcp[el], dn = dstp[el];
    const int h = lane >> 3;
    const float a = alpha[(size_t)e * H + h];
    const float mx = ord2f(am[dn * H + h]);
    const float ex = __expf(a - mx);
    if ((lane & 7) == 0) atomicAdd(den + dn * H + h, ex);
    const ushort4 vu = *(const ushort4*)(vt + (size_t)s * HD + lane * 4);
    float* ag = agg + (size_t)dn * HD + lane * 4;
    atomicAdd(ag + 0, ex * bu(vu.x));
    atomicAdd(ag + 1, ex * bu(vu.y));
    atomicAdd(ag + 2, ex * bu(vu.z));
    atomicAdd(ag + 3, ex * bu(vu.w));
}

// ---------------------------------------------------------------------------
// Update: agg/den -> gelu -> @Wout + bout -> skip-gate mix; write fp32 x (+fp32 out)
template <int LAST>
__global__ __launch_bounds__(128) void k_update(
    const float* __restrict__ agg, const float* __restrict__ den,
    const float* __restrict__ Wout, const float* __restrict__ bout,
    const float* __restrict__ skip,
    float* __restrict__ x, float* __restrict__ xout) {
    __shared__ float gs[16 * HD];   // gelu(agg/den), [n][d]
    const int tid = threadIdx.x;
    const int node0 = blockIdx.x * 16;
    for (int f4 = tid; f4 < 512; f4 += 128) {
        const int n = f4 >> 5, dp = f4 & 31;
        float4 v = *(const float4*)(agg + (size_t)(node0 + n) * HD + dp * 4);
        const float dnv = den[(node0 + n) * H + (dp >> 3)];
        const float inv = (dnv > 0.f) ? (1.f / dnv) : 0.f;   // edgeless node -> agg 0
        v.x = gelu(v.x * inv);
        v.y = gelu(v.y * inv);
        v.z = gelu(v.z * inv);
        v.w = gelu(v.w * inv);
        *(float4*)(gs + n * HD + dp * 4) = v;
    }
    __syncthreads();
    float acc[16];
#pragma unroll
    for (int n = 0; n < 16; n++) acc[n] = 0.f;
    const int o = tid;
    for (int d = 0; d < HD; d += 4) {
        float4 xv[16];
#pragma unroll
        for (int n = 0; n < 16; n++) xv[n] = *(const float4*)(gs + n * HD + d);
#pragma unroll
        for (int j = 0; j < 4; j++) {
            const float w = Wout[(d + j) * HD + o];
#pragma unroll
            for (int n = 0; n < 16; n++)
                acc[n] = fmaf(((const float*)&xv[n])[j], w, acc[n]);
        }
    }
    const float bb = bout[o];
    const float g = 1.f / (1.f + expf(-skip[0]));
#pragma unroll
    for (int n = 0; n < 16; n++) {
        const size_t idx = (size_t)(node0 + n) * HD + o;
        const float xn = g * (acc[n] + bb) + (1.f - g) * x[idx];
        x[idx] = xn;
        if (LAST) xout[idx] = xn;   // OUTPUT IS FP32 (reference returns float32)
    }
}

// ---------------------------------------------------------------------------
static inline size_t alignup(size_t v) { return (v + 15) & ~(size_t)15; }

extern "C" void kernel_launch(void* const* d_in, const int* in_sizes, int n_in,
                              void* d_out, int out_size, void* d_ws, size_t ws_size,
                              hipStream_t stream) {
    (void)in_sizes; (void)n_in; (void)out_size; (void)ws_size;
    const int* src_dg = (const int*)d_in[2];
    const int* dst_dg = (const int*)d_in[3];
    const int* src_gd = (const int*)d_in[4];
    const int* dst_gd = (const int*)d_in[5];
    const int* src_gg = (const int*)d_in[6];
    const int* dst_gg = (const int*)d_in[7];

    // ---- workspace carve-up (fp32 part, each segment 64B-aligned) ----
    float* ws = (float*)d_ws;
    float* xd    = ws; ws += alignup((size_t)ND * HD);
    float* xg    = ws; ws += alignup((size_t)NG * HD);
    float* alpha = ws; ws += alignup((size_t)NE * H);
    float* dend  = ws; ws += alignup((size_t)ND * H);
    float* deng  = ws; ws += alignup((size_t)NG * H);
    float* aggd  = ws; ws += alignup((size_t)ND * HD);
    float* aggg  = ws; ws += alignup((size_t)NG * HD);
    int* amaxd = (int*)ws; ws += alignup((size_t)ND * H);
    int* amaxg = (int*)ws; ws += alignup((size_t)NG * H);
    int* flag  = (int*)ws; ws += 16;
    // canonical fp32 copies of all float inputs
    float* wkqvd = ws; ws += alignup((size_t)NLAYER * HD * 3 * HD);
    float* bkqvd = ws; ws += alignup((size_t)NLAYER * 3 * HD);
    float* wkqvg = ws; ws += alignup((size_t)NLAYER * HD * 3 * HD);
    float* bkqvg = ws; ws += alignup((size_t)NLAYER * 3 * HD);
    float* woutd = ws; ws += alignup((size_t)NLAYER * HD * HD);
    float* boutd = ws; ws += alignup((size_t)NLAYER * HD);
    float* woutg = ws; ws += alignup((size_t)NLAYER * HD * HD);
    float* boutg = ws; ws += alignup((size_t)NLAYER * HD);
    float* skipd = ws; ws += 16;
    float* skipg = ws; ws += 16;
    float* arelc = ws; ws += alignup((size_t)NLAYER * 3 * H * D * D);
    float* mrelc = ws; ws += alignup((size_t)NLAYER * 3 * H * D * D);
    float* prelc = ws; ws += 16;
    // bf16 q/k/v tables
    bf16* qd  = (bf16*)ws;
    bf16* qg  = qd  + (size_t)ND * HD;
    bf16* kd0 = qg  + (size_t)NG * HD;
    bf16* vd0 = kd0 + (size_t)ND * HD;
    bf16* kg1 = vd0 + (size_t)ND * HD;
    bf16* vg1 = kg1 + (size_t)NG * HD;
    bf16* kg2 = vg1 + (size_t)NG * HD;
    bf16* vg2 = kg2 + (size_t)NG * HD;

    // ---- dtype detect + canonicalize all float inputs to fp32 ----
    hipMemsetAsync(flag, 0, 4, stream);
    k_detect<<<1, 256, 0, stream>>>((const unsigned short*)d_in[0], flag);

    CvtDesc cd;
    const int seg_in[NSEG] = {0, 1, 8, 9, 10, 11, 12, 13, 14, 15, 16, 17, 18, 19, 20};
    float* const seg_dst[NSEG] = {xd, xg, wkqvd, bkqvd, wkqvg, bkqvg, woutd, boutd,
                                  woutg, boutg, skipd, skipg, arelc, mrelc, prelc};
    const int seg_n[NSEG] = {ND * HD, NG * HD,
                             NLAYER * HD * 3 * HD, NLAYER * 3 * HD,
                             NLAYER * HD * 3 * HD, NLAYER * 3 * HD,
                             NLAYER * HD * HD, NLAYER * HD,
                             NLAYER * HD * HD, NLAYER * HD,
                             NLAYER, NLAYER,
                             NLAYER * 3 * H * D * D, NLAYER * 3 * H * D * D,
                             NLAYER * 3 * H};
    int nblk = 0;
    for (int s = 0; s < NSEG; s++) {
        cd.src[s] = d_in[seg_in[s]];
        cd.dst[s] = seg_dst[s];
        cd.nelem[s] = seg_n[s];
        cd.blk0[s] = nblk;
        nblk += (seg_n[s] + 1023) / 1024;
    }
    k_cvt_all<<<nblk, 256, 0, stream>>>(cd, flag);

    for (int l = 0; l < NLAYER; l++) {
        // 0x80808080 decodes (via ord2f) to very negative: safe "-inf" for atomicMax keys
        hipMemsetAsync(amaxd, 0x80, sizeof(int) * ND * H, stream);
        hipMemsetAsync(amaxg, 0x80, sizeof(int) * NG * H, stream);
        hipMemsetAsync(dend, 0, sizeof(float) * ND * H, stream);
        hipMemsetAsync(deng, 0, sizeof(float) * NG * H, stream);
        hipMemsetAsync(aggd, 0, sizeof(float) * (size_t)ND * HD, stream);
        hipMemsetAsync(aggg, 0, sizeof(float) * (size_t)NG * HD, stream);

        const float* arl = arelc + (size_t)l * 3 * H * D * D;
        const float* mrl = mrelc + (size_t)l * 3 * H * D * D;
        k_kqv<0><<<ND / 16, 192, 0, stream>>>(
            xd, wkqvd + (size_t)l * HD * 3 * HD, bkqvd + l * 3 * HD,
            arl + 0 * H * D * D, mrl + 0 * H * D * D, nullptr, nullptr,
            qd, kd0, vd0, nullptr, nullptr);
        k_kqv<1><<<NG / 16, 192, 0, stream>>>(
            xg, wkqvg + (size_t)l * HD * 3 * HD, bkqvg + l * 3 * HD,
            arl + 1 * H * D * D, mrl + 1 * H * D * D,
            arl + 2 * H * D * D, mrl + 2 * H * D * D,
            qg, kg1, vg1, kg2, vg2);
        k_edge_alpha<<<NE / 8, 256, 0, stream>>>(
            src_dg, dst_dg, src_gd, dst_gd, src_gg, dst_gg,
            qd, qg, kd0, kg1, kg2, prelc + l * 3 * H, alpha, amaxd, amaxg);
        k_edge_agg<<<NE / 8, 256, 0, stream>>>(
            src_dg, dst_dg, src_gd, dst_gd, src_gg, dst_gg,
            vd0, vg1, vg2, alpha, amaxd, amaxg, dend, deng, aggd, aggg);
        if (l == NLAYER - 1) {
            k_update<1><<<ND / 16, 128, 0, stream>>>(
                aggd, dend, woutd + (size_t)l * HD * HD, boutd + l * HD,
                skipd + l, xd, (float*)d_out);
            k_update<1><<<NG / 16, 128, 0, stream>>>(
                aggg, deng, woutg + (size_t)l * HD * HD, boutg + l * HD,
                skipg + l, xg, (float*)d_out + (size_t)ND * HD);
        } else {
            k_update<0><<<ND / 16, 128, 0, stream>>>(
                aggd, dend, woutd + (size_t)l * HD * HD, boutd + l * HD,
                skipd + l, xd, nullptr);
            k_update<0><<<NG / 16, 128, 0, stream>>>(
                aggg, deng, woutg + (size_t)l * HD * HD, boutg + l * HD,
                skipg + l, xg, nullptr);
        }
    }
}

// Round 4
// 887.954 us; speedup vs baseline: 3.0648x; 3.0648x over previous
//
#include <hip/hip_runtime.h>
#include <hip/hip_bf16.h>

#define H 4
#define D 32
#define HD 128
#define ND 10000
#define NG 30000
#define E_DG 150000
#define E_GD 150000
#define E_GG 300000
#define NE (E_DG + E_GD + E_GG)
#define EG (E_DG + E_GG)   // edges into gene nodes
#define NLAYER 2

typedef __hip_bfloat16 bf16;

__device__ __forceinline__ float bu(unsigned short u) {
    return __uint_as_float(((unsigned)u) << 16);
}
__device__ __forceinline__ float gelu(float v) {
    // jax.nn.gelu default (approximate=True, tanh form)
    const float c = 0.79788456080286536f * (v + 0.044715f * v * v * v);
    return 0.5f * v * (1.0f + tanhf(c));
}

// ---------------------------------------------------------------------------
// Input dtype detection (see r1/r2 notes): flag=1 -> inputs fp32, 0 -> bf16.
__global__ void k_detect(const unsigned short* __restrict__ x, int* __restrict__ flag) {
    int bad = 0;
    for (int i = threadIdx.x; i < 4096; i += 256) {
        const float v = bu(x[i]);
        if (!(fabsf(v) < 1e6f)) bad = 1;
    }
    if (bad) atomicOr(flag, 1);
}

// ---------------------------------------------------------------------------
// Batched conversion of all float inputs -> canonical fp32 ws buffers.
#define NSEG 15
struct CvtDesc {
    const void* src[NSEG];
    float* dst[NSEG];
    int nelem[NSEG];
    int blk0[NSEG];
};

__global__ __launch_bounds__(256) void k_cvt_all(CvtDesc d, const int* __restrict__ flag) {
    const int b = blockIdx.x;
    int s = 0;
    while (s + 1 < NSEG && b >= d.blk0[s + 1]) s++;
    const int i0 = (b - d.blk0[s]) * 1024 + threadIdx.x * 4;
    const int n = d.nelem[s];
    if (i0 >= n) return;
    const bool isf32 = (*flag != 0);
    float* dst = d.dst[s];
    if (i0 + 4 <= n) {
        float4 v;
        if (isf32) {
            v = *(const float4*)((const float*)d.src[s] + i0);
        } else {
            const ushort4 u = *(const ushort4*)((const unsigned short*)d.src[s] + i0);
            v = make_float4(bu(u.x), bu(u.y), bu(u.z), bu(u.w));
        }
        *(float4*)(dst + i0) = v;
    } else {
        for (int j = i0; j < n; j++)
            dst[j] = isf32 ? ((const float*)d.src[s])[j] : bu(((const unsigned short*)d.src[s])[j]);
    }
}

// ---------------------------------------------------------------------------
// CSR build: histogram -> scan -> scatter. Graph is layer-invariant: built once.
__global__ __launch_bounds__(256) void k_hist(
    const int* __restrict__ dst_dg, const int* __restrict__ dst_gg,
    const int* __restrict__ dst_gd,
    int* __restrict__ cnt_g, int* __restrict__ cnt_d) {
    const int i = blockIdx.x * 256 + threadIdx.x;
    if (i < E_DG) atomicAdd(cnt_g + dst_dg[i], 1);
    else if (i < EG) atomicAdd(cnt_g + dst_gg[i - E_DG], 1);
    else if (i < NE) atomicAdd(cnt_d + dst_gd[i - EG], 1);
}

// single-workgroup chunked inclusive scan -> rowptr (n+1) and cursor (=rowptr[i])
__global__ __launch_bounds__(256) void k_scan(
    const int* __restrict__ cnt, int* __restrict__ rowptr,
    int* __restrict__ cursor, int n) {
    __shared__ int sdata[256];
    __shared__ int sbase;
    if (threadIdx.x == 0) { sbase = 0; rowptr[0] = 0; }
    __syncthreads();
    for (int i0 = 0; i0 < n; i0 += 256) {
        const int i = i0 + threadIdx.x;
        const int v = (i < n) ? cnt[i] : 0;
        sdata[threadIdx.x] = v;
        __syncthreads();
        for (int dlt = 1; dlt < 256; dlt <<= 1) {
            const int t = (threadIdx.x >= dlt) ? sdata[threadIdx.x - dlt] : 0;
            __syncthreads();
            sdata[threadIdx.x] += t;
            __syncthreads();
        }
        const int incl = sdata[threadIdx.x];
        const int base = sbase;
        if (i < n) {
            rowptr[i + 1] = base + incl;
            cursor[i] = base + incl - v;
        }
        __syncthreads();
        if (threadIdx.x == 255) sbase = base + incl;
        __syncthreads();
    }
}

// edge record: (src << 2) | edge_type
__global__ __launch_bounds__(256) void k_scatter(
    const int* __restrict__ src_dg, const int* __restrict__ dst_dg,
    const int* __restrict__ src_gg, const int* __restrict__ dst_gg,
    const int* __restrict__ src_gd, const int* __restrict__ dst_gd,
    int* __restrict__ cur_g, int* __restrict__ cur_d,
    int* __restrict__ edges_g, int* __restrict__ edges_d) {
    const int i = blockIdx.x * 256 + threadIdx.x;
    if (i < E_DG) {
        const int pos = atomicAdd(cur_g + dst_dg[i], 1);
        edges_g[pos] = (src_dg[i] << 2) | 0;
    } else if (i < EG) {
        const int j = i - E_DG;
        const int pos = atomicAdd(cur_g + dst_gg[j], 1);
        edges_g[pos] = (src_gg[j] << 2) | 2;
    } else if (i < NE) {
        const int j = i - EG;
        const int pos = atomicAdd(cur_d + dst_gd[j], 1);
        edges_d[pos] = src_gd[j] << 2;
    }
}

// ---------------------------------------------------------------------------
// Fused KQV projection + per-edge-type relation transform (per node type).
// Block = 192 threads, 16 nodes per block.
template <int GENE>
__global__ __launch_bounds__(192) void k_kqv(
    const float* __restrict__ x,
    const float* __restrict__ W,
    const float* __restrict__ bias,
    const float* __restrict__ relA0, const float* __restrict__ relM0,
    const float* __restrict__ relA1, const float* __restrict__ relM1,
    bf16* __restrict__ qtab,
    bf16* __restrict__ k0, bf16* __restrict__ v0,
    bf16* __restrict__ k1, bf16* __restrict__ v1) {
    __shared__ float xs[16 * HD];
    __shared__ float kqv[16 * 384];
    const int tid = threadIdx.x;
    const int node0 = blockIdx.x * 16;

    for (int f4 = tid; f4 < 512; f4 += 192) {
        const int n = f4 >> 5, dp = f4 & 31;
        const float4 v = *(const float4*)(x + (size_t)(node0 + n) * HD + dp * 4);
        *(float4*)(xs + n * HD + dp * 4) = v;
    }
    __syncthreads();

    float acc0[16], acc1[16];
#pragma unroll
    for (int n = 0; n < 16; n++) { acc0[n] = 0.f; acc1[n] = 0.f; }
    const int o0 = tid, o1 = tid + 192;
    for (int d = 0; d < HD; d += 4) {
        float4 xv[16];
#pragma unroll
        for (int n = 0; n < 16; n++) xv[n] = *(const float4*)(xs + n * HD + d);
#pragma unroll
        for (int j = 0; j < 4; j++) {
            const float w0 = W[(d + j) * 384 + o0];
            const float w1 = W[(d + j) * 384 + o1];
#pragma unroll
            for (int n = 0; n < 16; n++) {
                const float xvn = ((const float*)&xv[n])[j];
                acc0[n] = fmaf(xvn, w0, acc0[n]);
                acc1[n] = fmaf(xvn, w1, acc1[n]);
            }
        }
    }
    const float bb0 = bias[o0];
    const float bb1 = bias[o1];
#pragma unroll
    for (int n = 0; n < 16; n++) { acc0[n] += bb0; acc1[n] += bb1; }
#pragma unroll
    for (int n = 0; n < 16; n++) {
        kqv[n * 384 + o0] = acc0[n];
        kqv[n * 384 + o1] = acc1[n];
    }
    if (o0 >= 128) {
#pragma unroll
        for (int n = 0; n < 16; n++)
            qtab[(size_t)(node0 + n) * HD + (o0 - 128)] = __float2bfloat16(acc0[n]);
    }
    if (o1 < 256) {
#pragma unroll
        for (int n = 0; n < 16; n++)
            qtab[(size_t)(node0 + n) * HD + (o1 - 128)] = __float2bfloat16(acc1[n]);
    }
    __syncthreads();

    const int ncols = GENE ? 512 : 256;
    for (int j = tid; j < ncols; j += 192) {
        const int set = j >> 7;       // 0:k.A0 1:v.M0 2:k.A1 3:v.M1
        const int jj = j & 127;
        const int h = jj >> 5, f = jj & 31;
        const int srcoff = (set & 1) ? 256 : 0;
        const float* mat = (set == 0) ? relA0 : (set == 1) ? relM0 : (set == 2) ? relA1 : relM1;
        bf16* outp = (set == 0) ? k0 : (set == 1) ? v0 : (set == 2) ? k1 : v1;
        mat += h * D * D + f;
        float acc[16];
#pragma unroll
        for (int n = 0; n < 16; n++) acc[n] = 0.f;
        for (int dd = 0; dd < D; dd++) {
            const float m = mat[dd * D];
            const int coff = srcoff + h * D + dd;
#pragma unroll
            for (int n = 0; n < 16; n++)
                acc[n] = fmaf(kqv[n * 384 + coff], m, acc[n]);
        }
#pragma unroll
        for (int n = 0; n < 16; n++)
            outp[(size_t)(node0 + n) * HD + jj] = __float2bfloat16(acc[n]);
    }
}

// ---------------------------------------------------------------------------
// Gather-style per-node aggregation: one wave per dst node, online softmax
// over the node's CSR edge list. No global atomics. Writes normalized agg.
// Lane l: head h = l>>4, dims (l&15)*2 .. +1 of that head.
template <int GENE>
__global__ __launch_bounds__(256) void k_node_agg(
    const int* __restrict__ rowptr, const int* __restrict__ edges,
    const bf16* __restrict__ q,
    const bf16* __restrict__ kA, const bf16* __restrict__ vA,   // et0 (gene) / et1 (dis)
    const bf16* __restrict__ kB, const bf16* __restrict__ vB,   // et2 (gene only)
    const float* __restrict__ prel,    // [3][H] layer slice
    float* __restrict__ agg, int nnode) {
    const int node = blockIdx.x * 4 + (threadIdx.x >> 6);
    if (node >= nnode) return;
    const int lane = threadIdx.x & 63;
    const int h = lane >> 4;
    const int off = h * D + (lane & 15) * 2;
    const float scale = 0.17677669529663689f;
    const float pA = prel[(GENE ? 0 : 1) * H + h] * scale;
    const float pB = GENE ? prel[2 * H + h] * scale : 0.f;

    const ushort2 qu = *(const ushort2*)(q + (size_t)node * HD + off);
    const float q0 = bu(qu.x), q1 = bu(qu.y);

    float m = -1e30f, s = 0.f, a0 = 0.f, a1 = 0.f;
    const int e1 = rowptr[node + 1];
    for (int e = rowptr[node]; e < e1; e++) {
        const int rec = edges[e];
        const int src = rec >> 2;
        const bool isB = GENE && ((rec & 3) == 2);
        const bf16* kt = isB ? kB : kA;
        const bf16* vt = isB ? vB : vA;
        const ushort2 ku = *(const ushort2*)(kt + (size_t)src * HD + off);
        float p = q0 * bu(ku.x) + q1 * bu(ku.y);
        p += __shfl_xor(p, 1);
        p += __shfl_xor(p, 2);
        p += __shfl_xor(p, 4);
        p += __shfl_xor(p, 8);
        const float a = p * (isB ? pB : pA);
        const ushort2 vu = *(const ushort2*)(vt + (size_t)src * HD + off);
        const float mn = fmaxf(m, a);
        const float c = __expf(m - mn);    // first iter: exp(-huge)=0
        const float ea = __expf(a - mn);
        s = s * c + ea;
        a0 = a0 * c + ea * bu(vu.x);
        a1 = a1 * c + ea * bu(vu.y);
        m = mn;
    }
    const float inv = (s > 0.f) ? (1.f / s) : 0.f;   // edgeless node -> 0
    *(float2*)(agg + (size_t)node * HD + off) = make_float2(a0 * inv, a1 * inv);
}

// ---------------------------------------------------------------------------
// Update: gelu(agg) @ Wout + bout -> skip-gate mix; write fp32 x (+fp32 out)
template <int LAST>
__global__ __launch_bounds__(128) void k_update(
    const float* __restrict__ agg,
    const float* __restrict__ Wout, const float* __restrict__ bout,
    const float* __restrict__ skip,
    float* __restrict__ x, float* __restrict__ xout) {
    __shared__ float gs[16 * HD];
    const int tid = threadIdx.x;
    const int node0 = blockIdx.x * 16;
    for (int f4 = tid; f4 < 512; f4 += 128) {
        const int n = f4 >> 5, dp = f4 & 31;
        float4 v = *(const float4*)(agg + (size_t)(node0 + n) * HD + dp * 4);
        v.x = gelu(v.x);
        v.y = gelu(v.y);
        v.z = gelu(v.z);
        v.w = gelu(v.w);
        *(float4*)(gs + n * HD + dp * 4) = v;
    }
    __syncthreads();
    float acc[16];
#pragma unroll
    for (int n = 0; n < 16; n++) acc[n] = 0.f;
    const int o = tid;
    for (int d = 0; d < HD; d += 4) {
        float4 xv[16];
#pragma unroll
        for (int n = 0; n < 16; n++) xv[n] = *(const float4*)(gs + n * HD + d);
#pragma unroll
        for (int j = 0; j < 4; j++) {
            const float w = Wout[(d + j) * HD + o];
#pragma unroll
            for (int n = 0; n < 16; n++)
                acc[n] = fmaf(((const float*)&xv[n])[j], w, acc[n]);
        }
    }
    const float bb = bout[o];
    const float g = 1.f / (1.f + expf(-skip[0]));
#pragma unroll
    for (int n = 0; n < 16; n++) {
        const size_t idx = (size_t)(node0 + n) * HD + o;
        const float xn = g * (acc[n] + bb) + (1.f - g) * x[idx];
        x[idx] = xn;
        if (LAST) xout[idx] = xn;
    }
}

// ---------------------------------------------------------------------------
static inline size_t alignup(size_t v) { return (v + 15) & ~(size_t)15; }

extern "C" void kernel_launch(void* const* d_in, const int* in_sizes, int n_in,
                              void* d_out, int out_size, void* d_ws, size_t ws_size,
                              hipStream_t stream) {
    (void)in_sizes; (void)n_in; (void)out_size; (void)ws_size;
    const int* src_dg = (const int*)d_in[2];
    const int* dst_dg = (const int*)d_in[3];
    const int* src_gd = (const int*)d_in[4];
    const int* dst_gd = (const int*)d_in[5];
    const int* src_gg = (const int*)d_in[6];
    const int* dst_gg = (const int*)d_in[7];

    // ---- workspace carve-up ----
    float* ws = (float*)d_ws;
    float* xd   = ws; ws += alignup((size_t)ND * HD);
    float* xg   = ws; ws += alignup((size_t)NG * HD);
    float* aggd = ws; ws += alignup((size_t)ND * HD);
    float* aggg = ws; ws += alignup((size_t)NG * HD);
    int* flag = (int*)ws; ws += 16;
    // CSR
    int* cnt_g  = (int*)ws; ws += alignup(NG);
    int* cnt_d  = (int*)ws; ws += alignup(ND);
    int* rp_g   = (int*)ws; ws += alignup(NG + 1);
    int* rp_d   = (int*)ws; ws += alignup(ND + 1);
    int* cur_g  = (int*)ws; ws += alignup(NG);
    int* cur_d  = (int*)ws; ws += alignup(ND);
    int* edges_g = (int*)ws; ws += alignup(EG);
    int* edges_d = (int*)ws; ws += alignup(E_GD);
    // canonical fp32 inputs
    float* wkqvd = ws; ws += alignup((size_t)NLAYER * HD * 3 * HD);
    float* bkqvd = ws; ws += alignup((size_t)NLAYER * 3 * HD);
    float* wkqvg = ws; ws += alignup((size_t)NLAYER * HD * 3 * HD);
    float* bkqvg = ws; ws += alignup((size_t)NLAYER * 3 * HD);
    float* woutd = ws; ws += alignup((size_t)NLAYER * HD * HD);
    float* boutd = ws; ws += alignup((size_t)NLAYER * HD);
    float* woutg = ws; ws += alignup((size_t)NLAYER * HD * HD);
    float* boutg = ws; ws += alignup((size_t)NLAYER * HD);
    float* skipd = ws; ws += 16;
    float* skipg = ws; ws += 16;
    float* arelc = ws; ws += alignup((size_t)NLAYER * 3 * H * D * D);
    float* mrelc = ws; ws += alignup((size_t)NLAYER * 3 * H * D * D);
    float* prelc = ws; ws += 16;
    // bf16 q/k/v tables
    bf16* qd  = (bf16*)ws;
    bf16* qg  = qd  + (size_t)ND * HD;
    bf16* kd0 = qg  + (size_t)NG * HD;
    bf16* vd0 = kd0 + (size_t)ND * HD;
    bf16* kg1 = vd0 + (size_t)ND * HD;
    bf16* vg1 = kg1 + (size_t)NG * HD;
    bf16* kg2 = vg1 + (size_t)NG * HD;
    bf16* vg2 = kg2 + (size_t)NG * HD;

    // ---- dtype detect + canonicalize ----
    hipMemsetAsync(flag, 0, 4, stream);
    k_detect<<<1, 256, 0, stream>>>((const unsigned short*)d_in[0], flag);

    CvtDesc cd;
    const int seg_in[NSEG] = {0, 1, 8, 9, 10, 11, 12, 13, 14, 15, 16, 17, 18, 19, 20};
    float* const seg_dst[NSEG] = {xd, xg, wkqvd, bkqvd, wkqvg, bkqvg, woutd, boutd,
                                  woutg, boutg, skipd, skipg, arelc, mrelc, prelc};
    const int seg_n[NSEG] = {ND * HD, NG * HD,
                             NLAYER * HD * 3 * HD, NLAYER * 3 * HD,
                             NLAYER * HD * 3 * HD, NLAYER * 3 * HD,
                             NLAYER * HD * HD, NLAYER * HD,
                             NLAYER * HD * HD, NLAYER * HD,
                             NLAYER, NLAYER,
                             NLAYER * 3 * H * D * D, NLAYER * 3 * H * D * D,
                             NLAYER * 3 * H};
    int nblk = 0;
    for (int s = 0; s < NSEG; s++) {
        cd.src[s] = d_in[seg_in[s]];
        cd.dst[s] = seg_dst[s];
        cd.nelem[s] = seg_n[s];
        cd.blk0[s] = nblk;
        nblk += (seg_n[s] + 1023) / 1024;
    }
    k_cvt_all<<<nblk, 256, 0, stream>>>(cd, flag);

    // ---- CSR build (once; graph is layer-invariant) ----
    hipMemsetAsync(cnt_g, 0, sizeof(int) * NG, stream);
    hipMemsetAsync(cnt_d, 0, sizeof(int) * ND, stream);
    k_hist<<<(NE + 255) / 256, 256, 0, stream>>>(dst_dg, dst_gg, dst_gd, cnt_g, cnt_d);
    k_scan<<<1, 256, 0, stream>>>(cnt_g, rp_g, cur_g, NG);
    k_scan<<<1, 256, 0, stream>>>(cnt_d, rp_d, cur_d, ND);
    k_scatter<<<(NE + 255) / 256, 256, 0, stream>>>(
        src_dg, dst_dg, src_gg, dst_gg, src_gd, dst_gd,
        cur_g, cur_d, edges_g, edges_d);

    for (int l = 0; l < NLAYER; l++) {
        const float* arl = arelc + (size_t)l * 3 * H * D * D;
        const float* mrl = mrelc + (size_t)l * 3 * H * D * D;
        k_kqv<0><<<ND / 16, 192, 0, stream>>>(
            xd, wkqvd + (size_t)l * HD * 3 * HD, bkqvd + l * 3 * HD,
            arl + 0 * H * D * D, mrl + 0 * H * D * D, nullptr, nullptr,
            qd, kd0, vd0, nullptr, nullptr);
        k_kqv<1><<<NG / 16, 192, 0, stream>>>(
            xg, wkqvg + (size_t)l * HD * 3 * HD, bkqvg + l * 3 * HD,
            arl + 1 * H * D * D, mrl + 1 * H * D * D,
            arl + 2 * H * D * D, mrl + 2 * H * D * D,
            qg, kg1, vg1, kg2, vg2);
        // gene nodes aggregate et0 (d->g) + et2 (g->g); disease nodes et1 (g->d)
        k_node_agg<1><<<(NG + 3) / 4, 256, 0, stream>>>(
            rp_g, edges_g, qg, kd0, vd0, kg2, vg2, prelc + l * 3 * H, aggg, NG);
        k_node_agg<0><<<(ND + 3) / 4, 256, 0, stream>>>(
            rp_d, edges_d, qd, kg1, vg1, kg1, vg1, prelc + l * 3 * H, aggd, ND);
        if (l == NLAYER - 1) {
            k_update<1><<<ND / 16, 128, 0, stream>>>(
                aggd, woutd + (size_t)l * HD * HD, boutd + l * HD,
                skipd + l, xd, (float*)d_out);
            k_update<1><<<NG / 16, 128, 0, stream>>>(
                aggg, woutg + (size_t)l * HD * HD, boutg + l * HD,
                skipg + l, xg, (float*)d_out + (size_t)ND * HD);
        } else {
            k_update<0><<<ND / 16, 128, 0, stream>>>(
                aggd, woutd + (size_t)l * HD * HD, boutd + l * HD,
                skipd + l, xd, nullptr);
            k_update<0><<<NG / 16, 128, 0, stream>>>(
                aggg, woutg + (size_t)l * HD * HD, boutg + l * HD,
                skipg + l, xg, nullptr);
        }
    }
}

// Round 5
// 722.042 us; speedup vs baseline: 3.7690x; 1.2298x over previous
//
#include <hip/hip_runtime.h>
#include <hip/hip_bf16.h>

#define H 4
#define D 32
#define HD 128
#define ND 10000
#define NG 30000
#define E_DG 150000
#define E_GD 150000
#define E_GG 300000
#define NE (E_DG + E_GD + E_GG)
#define EG (E_DG + E_GG)   // edges into gene nodes
#define NLAYER 2
#define NBG 30             // ceil(NG/1024)
#define NBD 10             // ceil(ND/1024)

typedef __hip_bfloat16 bf16;

__device__ __forceinline__ float bu(unsigned short u) {
    return __uint_as_float(((unsigned)u) << 16);
}
__device__ __forceinline__ float gelu(float v) {
    // jax.nn.gelu default (approximate=True, tanh form)
    const float c = 0.79788456080286536f * (v + 0.044715f * v * v * v);
    return 0.5f * v * (1.0f + tanhf(c));
}

// ---------------------------------------------------------------------------
// Input dtype detection (see r1/r2 notes): flag=1 -> inputs fp32, 0 -> bf16.
__global__ void k_detect(const unsigned short* __restrict__ x, int* __restrict__ flag) {
    int bad = 0;
    for (int i = threadIdx.x; i < 4096; i += 256) {
        const float v = bu(x[i]);
        if (!(fabsf(v) < 1e6f)) bad = 1;
    }
    if (bad) atomicOr(flag, 1);
}

// ---------------------------------------------------------------------------
// Batched conversion of all float inputs -> canonical fp32 ws buffers.
#define NSEG 15
struct CvtDesc {
    const void* src[NSEG];
    float* dst[NSEG];
    int nelem[NSEG];
    int blk0[NSEG];
};

__global__ __launch_bounds__(256) void k_cvt_all(CvtDesc d, const int* __restrict__ flag) {
    const int b = blockIdx.x;
    int s = 0;
    while (s + 1 < NSEG && b >= d.blk0[s + 1]) s++;
    const int i0 = (b - d.blk0[s]) * 1024 + threadIdx.x * 4;
    const int n = d.nelem[s];
    if (i0 >= n) return;
    const bool isf32 = (*flag != 0);
    float* dst = d.dst[s];
    if (i0 + 4 <= n) {
        float4 v;
        if (isf32) {
            v = *(const float4*)((const float*)d.src[s] + i0);
        } else {
            const ushort4 u = *(const ushort4*)((const unsigned short*)d.src[s] + i0);
            v = make_float4(bu(u.x), bu(u.y), bu(u.z), bu(u.w));
        }
        *(float4*)(dst + i0) = v;
    } else {
        for (int j = i0; j < n; j++)
            dst[j] = isf32 ? ((const float*)d.src[s])[j] : bu(((const unsigned short*)d.src[s])[j]);
    }
}

// ---------------------------------------------------------------------------
// CSR build: histogram -> 3-phase parallel scan -> scatter.
__global__ __launch_bounds__(256) void k_hist(
    const int* __restrict__ dst_dg, const int* __restrict__ dst_gg,
    const int* __restrict__ dst_gd,
    int* __restrict__ cnt_g, int* __restrict__ cnt_d) {
    const int i = blockIdx.x * 256 + threadIdx.x;
    if (i < E_DG) atomicAdd(cnt_g + dst_dg[i], 1);
    else if (i < EG) atomicAdd(cnt_g + dst_gg[i - E_DG], 1);
    else if (i < NE) atomicAdd(cnt_d + dst_gd[i - EG], 1);
}

// Phase 1: per-block (1024-elem) sums. Blocks 0..NBG-1 -> gene, NBG.. -> disease.
__global__ __launch_bounds__(256) void k_scan_p1(
    const int* __restrict__ cnt_g, const int* __restrict__ cnt_d,
    int* __restrict__ bsum) {
    const int b = blockIdx.x;
    const int* cnt = (b < NBG) ? cnt_g : cnt_d;
    const int n = (b < NBG) ? NG : ND;
    const int i0 = ((b < NBG) ? b : (b - NBG)) * 1024 + threadIdx.x * 4;
    int s = 0;
#pragma unroll
    for (int j = 0; j < 4; j++)
        if (i0 + j < n) s += cnt[i0 + j];
    __shared__ int red[256];
    red[threadIdx.x] = s;
    __syncthreads();
    for (int d = 128; d > 0; d >>= 1) {
        if (threadIdx.x < d) red[threadIdx.x] += red[threadIdx.x + d];
        __syncthreads();
    }
    if (threadIdx.x == 0) bsum[b] = red[0];
}

// Phase 2: exclusive-scan the 40 block sums (two independent segments).
__global__ void k_scan_p2(int* __restrict__ bsum) {
    if (threadIdx.x == 0) {
        int acc = 0;
        for (int i = 0; i < NBG; i++) { const int v = bsum[i]; bsum[i] = acc; acc += v; }
        acc = 0;
        for (int i = NBG; i < NBG + NBD; i++) { const int v = bsum[i]; bsum[i] = acc; acc += v; }
    }
}

// Phase 3: block-local scan + block offset -> rowptr (n+1) and cursor (=rowptr[i]).
__global__ __launch_bounds__(256) void k_scan_p3(
    const int* __restrict__ cnt_g, const int* __restrict__ cnt_d,
    const int* __restrict__ bsum,
    int* __restrict__ rp_g, int* __restrict__ cur_g,
    int* __restrict__ rp_d, int* __restrict__ cur_d) {
    const int b = blockIdx.x;
    const bool isg = (b < NBG);
    const int* cnt = isg ? cnt_g : cnt_d;
    int* rp = isg ? rp_g : rp_d;
    int* cur = isg ? cur_g : cur_d;
    const int n = isg ? NG : ND;
    const int i0 = (isg ? b : (b - NBG)) * 1024 + threadIdx.x * 4;
    int v[4];
    int t = 0;
#pragma unroll
    for (int j = 0; j < 4; j++) {
        v[j] = (i0 + j < n) ? cnt[i0 + j] : 0;
        t += v[j];
    }
    __shared__ int sdata[256];
    sdata[threadIdx.x] = t;
    __syncthreads();
    for (int d = 1; d < 256; d <<= 1) {
        const int u = (threadIdx.x >= d) ? sdata[threadIdx.x - d] : 0;
        __syncthreads();
        sdata[threadIdx.x] += u;
        __syncthreads();
    }
    int run = bsum[b] + sdata[threadIdx.x] - t;   // exclusive prefix for this thread
#pragma unroll
    for (int j = 0; j < 4; j++) {
        if (i0 + j < n) {
            cur[i0 + j] = run;
            run += v[j];
            rp[i0 + j + 1] = run;
        }
    }
    if (threadIdx.x == 0 && (b == 0 || b == NBG)) rp[0] = 0;
}

// edge record: (src << 2) | edge_type
__global__ __launch_bounds__(256) void k_scatter(
    const int* __restrict__ src_dg, const int* __restrict__ dst_dg,
    const int* __restrict__ src_gg, const int* __restrict__ dst_gg,
    const int* __restrict__ src_gd, const int* __restrict__ dst_gd,
    int* __restrict__ cur_g, int* __restrict__ cur_d,
    int* __restrict__ edges_g, int* __restrict__ edges_d) {
    const int i = blockIdx.x * 256 + threadIdx.x;
    if (i < E_DG) {
        const int pos = atomicAdd(cur_g + dst_dg[i], 1);
        edges_g[pos] = (src_dg[i] << 2) | 0;
    } else if (i < EG) {
        const int j = i - E_DG;
        const int pos = atomicAdd(cur_g + dst_gg[j], 1);
        edges_g[pos] = (src_gg[j] << 2) | 2;
    } else if (i < NE) {
        const int j = i - EG;
        const int pos = atomicAdd(cur_d + dst_gd[j], 1);
        edges_d[pos] = src_gd[j] << 2;
    }
}

// ---------------------------------------------------------------------------
// Fused KQV projection + per-edge-type relation transform (per node type).
// Block = 192 threads, 16 nodes per block.
template <int GENE>
__global__ __launch_bounds__(192) void k_kqv(
    const float* __restrict__ x,
    const float* __restrict__ W,
    const float* __restrict__ bias,
    const float* __restrict__ relA0, const float* __restrict__ relM0,
    const float* __restrict__ relA1, const float* __restrict__ relM1,
    bf16* __restrict__ qtab,
    bf16* __restrict__ k0, bf16* __restrict__ v0,
    bf16* __restrict__ k1, bf16* __restrict__ v1) {
    __shared__ float xs[16 * HD];
    __shared__ float kqv[16 * 384];
    const int tid = threadIdx.x;
    const int node0 = blockIdx.x * 16;

    for (int f4 = tid; f4 < 512; f4 += 192) {
        const int n = f4 >> 5, dp = f4 & 31;
        const float4 v = *(const float4*)(x + (size_t)(node0 + n) * HD + dp * 4);
        *(float4*)(xs + n * HD + dp * 4) = v;
    }
    __syncthreads();

    float acc0[16], acc1[16];
#pragma unroll
    for (int n = 0; n < 16; n++) { acc0[n] = 0.f; acc1[n] = 0.f; }
    const int o0 = tid, o1 = tid + 192;
    for (int d = 0; d < HD; d += 4) {
        float4 xv[16];
#pragma unroll
        for (int n = 0; n < 16; n++) xv[n] = *(const float4*)(xs + n * HD + d);
#pragma unroll
        for (int j = 0; j < 4; j++) {
            const float w0 = W[(d + j) * 384 + o0];
            const float w1 = W[(d + j) * 384 + o1];
#pragma unroll
            for (int n = 0; n < 16; n++) {
                const float xvn = ((const float*)&xv[n])[j];
                acc0[n] = fmaf(xvn, w0, acc0[n]);
                acc1[n] = fmaf(xvn, w1, acc1[n]);
            }
        }
    }
    const float bb0 = bias[o0];
    const float bb1 = bias[o1];
#pragma unroll
    for (int n = 0; n < 16; n++) { acc0[n] += bb0; acc1[n] += bb1; }
#pragma unroll
    for (int n = 0; n < 16; n++) {
        kqv[n * 384 + o0] = acc0[n];
        kqv[n * 384 + o1] = acc1[n];
    }
    if (o0 >= 128) {
#pragma unroll
        for (int n = 0; n < 16; n++)
            qtab[(size_t)(node0 + n) * HD + (o0 - 128)] = __float2bfloat16(acc0[n]);
    }
    if (o1 < 256) {
#pragma unroll
        for (int n = 0; n < 16; n++)
            qtab[(size_t)(node0 + n) * HD + (o1 - 128)] = __float2bfloat16(acc1[n]);
    }
    __syncthreads();

    const int ncols = GENE ? 512 : 256;
    for (int j = tid; j < ncols; j += 192) {
        const int set = j >> 7;       // 0:k.A0 1:v.M0 2:k.A1 3:v.M1
        const int jj = j & 127;
        const int h = jj >> 5, f = jj & 31;
        const int srcoff = (set & 1) ? 256 : 0;
        const float* mat = (set == 0) ? relA0 : (set == 1) ? relM0 : (set == 2) ? relA1 : relM1;
        bf16* outp = (set == 0) ? k0 : (set == 1) ? v0 : (set == 2) ? k1 : v1;
        mat += h * D * D + f;
        float acc[16];
#pragma unroll
        for (int n = 0; n < 16; n++) acc[n] = 0.f;
        for (int dd = 0; dd < D; dd++) {
            const float m = mat[dd * D];
            const int coff = srcoff + h * D + dd;
#pragma unroll
            for (int n = 0; n < 16; n++)
                acc[n] = fmaf(kqv[n * 384 + coff], m, acc[n]);
        }
#pragma unroll
        for (int n = 0; n < 16; n++)
            outp[(size_t)(node0 + n) * HD + jj] = __float2bfloat16(acc[n]);
    }
}

// ---------------------------------------------------------------------------
// Gather-style per-node aggregation: one wave per dst node, online softmax
// over the node's CSR edge list. No global atomics. Writes normalized agg.
// Lane l: head h = l>>4, dims (l&15)*2 .. +1 of that head.
template <int GENE>
__global__ __launch_bounds__(256) void k_node_agg(
    const int* __restrict__ rowptr, const int* __restrict__ edges,
    const bf16* __restrict__ q,
    const bf16* __restrict__ kA, const bf16* __restrict__ vA,   // et0 (gene) / et1 (dis)
    const bf16* __restrict__ kB, const bf16* __restrict__ vB,   // et2 (gene only)
    const float* __restrict__ prel,    // [3][H] layer slice
    float* __restrict__ agg, int nnode) {
    const int node = blockIdx.x * 4 + (threadIdx.x >> 6);
    if (node >= nnode) return;
    const int lane = threadIdx.x & 63;
    const int h = lane >> 4;
    const int off = h * D + (lane & 15) * 2;
    const float scale = 0.17677669529663689f;
    const float pA = prel[(GENE ? 0 : 1) * H + h] * scale;
    const float pB = GENE ? prel[2 * H + h] * scale : 0.f;

    const ushort2 qu = *(const ushort2*)(q + (size_t)node * HD + off);
    const float q0 = bu(qu.x), q1 = bu(qu.y);

    float m = -1e30f, s = 0.f, a0 = 0.f, a1 = 0.f;
    const int e1 = rowptr[node + 1];
    for (int e = rowptr[node]; e < e1; e++) {
        const int rec = edges[e];
        const int src = rec >> 2;
        const bool isB = GENE && ((rec & 3) == 2);
        const bf16* kt = isB ? kB : kA;
        const bf16* vt = isB ? vB : vA;
        const ushort2 ku = *(const ushort2*)(kt + (size_t)src * HD + off);
        float p = q0 * bu(ku.x) + q1 * bu(ku.y);
        p += __shfl_xor(p, 1);
        p += __shfl_xor(p, 2);
        p += __shfl_xor(p, 4);
        p += __shfl_xor(p, 8);
        const float a = p * (isB ? pB : pA);
        const ushort2 vu = *(const ushort2*)(vt + (size_t)src * HD + off);
        const float mn = fmaxf(m, a);
        const float c = __expf(m - mn);    // first iter: exp(-huge)=0
        const float ea = __expf(a - mn);
        s = s * c + ea;
        a0 = a0 * c + ea * bu(vu.x);
        a1 = a1 * c + ea * bu(vu.y);
        m = mn;
    }
    const float inv = (s > 0.f) ? (1.f / s) : 0.f;   // edgeless node -> 0
    *(float2*)(agg + (size_t)node * HD + off) = make_float2(a0 * inv, a1 * inv);
}

// ---------------------------------------------------------------------------
// Update: gelu(agg) @ Wout + bout -> skip-gate mix; write fp32 x (+fp32 out)
template <int LAST>
__global__ __launch_bounds__(128) void k_update(
    const float* __restrict__ agg,
    const float* __restrict__ Wout, const float* __restrict__ bout,
    const float* __restrict__ skip,
    float* __restrict__ x, float* __restrict__ xout) {
    __shared__ float gs[16 * HD];
    const int tid = threadIdx.x;
    const int node0 = blockIdx.x * 16;
    for (int f4 = tid; f4 < 512; f4 += 128) {
        const int n = f4 >> 5, dp = f4 & 31;
        float4 v = *(const float4*)(agg + (size_t)(node0 + n) * HD + dp * 4);
        v.x = gelu(v.x);
        v.y = gelu(v.y);
        v.z = gelu(v.z);
        v.w = gelu(v.w);
        *(float4*)(gs + n * HD + dp * 4) = v;
    }
    __syncthreads();
    float acc[16];
#pragma unroll
    for (int n = 0; n < 16; n++) acc[n] = 0.f;
    const int o = tid;
    for (int d = 0; d < HD; d += 4) {
        float4 xv[16];
#pragma unroll
        for (int n = 0; n < 16; n++) xv[n] = *(const float4*)(gs + n * HD + d);
#pragma unroll
        for (int j = 0; j < 4; j++) {
            const float w = Wout[(d + j) * HD + o];
#pragma unroll
            for (int n = 0; n < 16; n++)
                acc[n] = fmaf(((const float*)&xv[n])[j], w, acc[n]);
        }
    }
    const float bb = bout[o];
    const float g = 1.f / (1.f + expf(-skip[0]));
#pragma unroll
    for (int n = 0; n < 16; n++) {
        const size_t idx = (size_t)(node0 + n) * HD + o;
        const float xn = g * (acc[n] + bb) + (1.f - g) * x[idx];
        x[idx] = xn;
        if (LAST) xout[idx] = xn;
    }
}

// ---------------------------------------------------------------------------
static inline size_t alignup(size_t v) { return (v + 15) & ~(size_t)15; }

extern "C" void kernel_launch(void* const* d_in, const int* in_sizes, int n_in,
                              void* d_out, int out_size, void* d_ws, size_t ws_size,
                              hipStream_t stream) {
    (void)in_sizes; (void)n_in; (void)out_size; (void)ws_size;
    const int* src_dg = (const int*)d_in[2];
    const int* dst_dg = (const int*)d_in[3];
    const int* src_gd = (const int*)d_in[4];
    const int* dst_gd = (const int*)d_in[5];
    const int* src_gg = (const int*)d_in[6];
    const int* dst_gg = (const int*)d_in[7];

    // ---- workspace carve-up ----
    float* ws = (float*)d_ws;
    float* xd   = ws; ws += alignup((size_t)ND * HD);
    float* xg   = ws; ws += alignup((size_t)NG * HD);
    float* aggd = ws; ws += alignup((size_t)ND * HD);
    float* aggg = ws; ws += alignup((size_t)NG * HD);
    int* flag = (int*)ws; ws += 16;
    // CSR
    int* cnt_g  = (int*)ws; ws += alignup(NG);
    int* cnt_d  = (int*)ws; ws += alignup(ND);
    int* rp_g   = (int*)ws; ws += alignup(NG + 1);
    int* rp_d   = (int*)ws; ws += alignup(ND + 1);
    int* cur_g  = (int*)ws; ws += alignup(NG);
    int* cur_d  = (int*)ws; ws += alignup(ND);
    int* bsum   = (int*)ws; ws += alignup(NBG + NBD);
    int* edges_g = (int*)ws; ws += alignup(EG);
    int* edges_d = (int*)ws; ws += alignup(E_GD);
    // canonical fp32 inputs
    float* wkqvd = ws; ws += alignup((size_t)NLAYER * HD * 3 * HD);
    float* bkqvd = ws; ws += alignup((size_t)NLAYER * 3 * HD);
    float* wkqvg = ws; ws += alignup((size_t)NLAYER * HD * 3 * HD);
    float* bkqvg = ws; ws += alignup((size_t)NLAYER * 3 * HD);
    float* woutd = ws; ws += alignup((size_t)NLAYER * HD * HD);
    float* boutd = ws; ws += alignup((size_t)NLAYER * HD);
    float* woutg = ws; ws += alignup((size_t)NLAYER * HD * HD);
    float* boutg = ws; ws += alignup((size_t)NLAYER * HD);
    float* skipd = ws; ws += 16;
    float* skipg = ws; ws += 16;
    float* arelc = ws; ws += alignup((size_t)NLAYER * 3 * H * D * D);
    float* mrelc = ws; ws += alignup((size_t)NLAYER * 3 * H * D * D);
    float* prelc = ws; ws += 16;
    // bf16 q/k/v tables
    bf16* qd  = (bf16*)ws;
    bf16* qg  = qd  + (size_t)ND * HD;
    bf16* kd0 = qg  + (size_t)NG * HD;
    bf16* vd0 = kd0 + (size_t)ND * HD;
    bf16* kg1 = vd0 + (size_t)ND * HD;
    bf16* vg1 = kg1 + (size_t)NG * HD;
    bf16* kg2 = vg1 + (size_t)NG * HD;
    bf16* vg2 = kg2 + (size_t)NG * HD;

    // ---- dtype detect + canonicalize ----
    hipMemsetAsync(flag, 0, 4, stream);
    k_detect<<<1, 256, 0, stream>>>((const unsigned short*)d_in[0], flag);

    CvtDesc cd;
    const int seg_in[NSEG] = {0, 1, 8, 9, 10, 11, 12, 13, 14, 15, 16, 17, 18, 19, 20};
    float* const seg_dst[NSEG] = {xd, xg, wkqvd, bkqvd, wkqvg, bkqvg, woutd, boutd,
                                  woutg, boutg, skipd, skipg, arelc, mrelc, prelc};
    const int seg_n[NSEG] = {ND * HD, NG * HD,
                             NLAYER * HD * 3 * HD, NLAYER * 3 * HD,
                             NLAYER * HD * 3 * HD, NLAYER * 3 * HD,
                             NLAYER * HD * HD, NLAYER * HD,
                             NLAYER * HD * HD, NLAYER * HD,
                             NLAYER, NLAYER,
                             NLAYER * 3 * H * D * D, NLAYER * 3 * H * D * D,
                             NLAYER * 3 * H};
    int nblk = 0;
    for (int s = 0; s < NSEG; s++) {
        cd.src[s] = d_in[seg_in[s]];
        cd.dst[s] = seg_dst[s];
        cd.nelem[s] = seg_n[s];
        cd.blk0[s] = nblk;
        nblk += (seg_n[s] + 1023) / 1024;
    }
    k_cvt_all<<<nblk, 256, 0, stream>>>(cd, flag);

    // ---- CSR build (once; graph is layer-invariant) ----
    hipMemsetAsync(cnt_g, 0, sizeof(int) * NG, stream);
    hipMemsetAsync(cnt_d, 0, sizeof(int) * ND, stream);
    k_hist<<<(NE + 255) / 256, 256, 0, stream>>>(dst_dg, dst_gg, dst_gd, cnt_g, cnt_d);
    k_scan_p1<<<NBG + NBD, 256, 0, stream>>>(cnt_g, cnt_d, bsum);
    k_scan_p2<<<1, 64, 0, stream>>>(bsum);
    k_scan_p3<<<NBG + NBD, 256, 0, stream>>>(cnt_g, cnt_d, bsum, rp_g, cur_g, rp_d, cur_d);
    k_scatter<<<(NE + 255) / 256, 256, 0, stream>>>(
        src_dg, dst_dg, src_gg, dst_gg, src_gd, dst_gd,
        cur_g, cur_d, edges_g, edges_d);

    for (int l = 0; l < NLAYER; l++) {
        const float* arl = arelc + (size_t)l * 3 * H * D * D;
        const float* mrl = mrelc + (size_t)l * 3 * H * D * D;
        k_kqv<0><<<ND / 16, 192, 0, stream>>>(
            xd, wkqvd + (size_t)l * HD * 3 * HD, bkqvd + l * 3 * HD,
            arl + 0 * H * D * D, mrl + 0 * H * D * D, nullptr, nullptr,
            qd, kd0, vd0, nullptr, nullptr);
        k_kqv<1><<<NG / 16, 192, 0, stream>>>(
            xg, wkqvg + (size_t)l * HD * 3 * HD, bkqvg + l * 3 * HD,
            arl + 1 * H * D * D, mrl + 1 * H * D * D,
            arl + 2 * H * D * D, mrl + 2 * H * D * D,
            qg, kg1, vg1, kg2, vg2);
        // gene nodes aggregate et0 (d->g) + et2 (g->g); disease nodes et1 (g->d)
        k_node_agg<1><<<(NG + 3) / 4, 256, 0, stream>>>(
            rp_g, edges_g, qg, kd0, vd0, kg2, vg2, prelc + l * 3 * H, aggg, NG);
        k_node_agg<0><<<(ND + 3) / 4, 256, 0, stream>>>(
            rp_d, edges_d, qd, kg1, vg1, kg1, vg1, prelc + l * 3 * H, aggd, ND);
        if (l == NLAYER - 1) {
            k_update<1><<<ND / 16, 128, 0, stream>>>(
                aggd, woutd + (size_t)l * HD * HD, boutd + l * HD,
                skipd + l, xd, (float*)d_out);
            k_update<1><<<NG / 16, 128, 0, stream>>>(
                aggg, woutg + (size_t)l * HD * HD, boutg + l * HD,
                skipg + l, xg, (float*)d_out + (size_t)ND * HD);
        } else {
            k_update<0><<<ND / 16, 128, 0, stream>>>(
                aggd, woutd + (size_t)l * HD * HD, boutd + l * HD,
                skipd + l, xd, nullptr);
            k_update<0><<<NG / 16, 128, 0, stream>>>(
                aggg, woutg + (size_t)l * HD * HD, boutg + l * HD,
                skipg + l, xg, nullptr);
        }
    }
}

// Round 6
// 588.673 us; speedup vs baseline: 4.6229x; 1.2266x over previous
//
#include <hip/hip_runtime.h>
#include <hip/hip_bf16.h>

#define H 4
#define D 32
#define HD 128
#define ND 10000
#define NG 30000
#define E_DG 150000
#define E_GD 150000
#define E_GG 300000
#define NE (E_DG + E_GD + E_GG)
#define EG (E_DG + E_GG)   // edges into gene nodes
#define NLAYER 2
#define NBG 30             // ceil(NG/1024)
#define NBD 10             // ceil(ND/1024)
#define OCG 640            // gene table cols:   [q|k1|v1|k2|v2]
#define OCD 384            // disease table cols:[q|k0|v0]

typedef __hip_bfloat16 bf16;
typedef __attribute__((ext_vector_type(8))) short short8;
typedef __attribute__((ext_vector_type(4))) float f32x4;

__device__ __forceinline__ float bu(unsigned short u) {
    return __uint_as_float(((unsigned)u) << 16);
}
__device__ __forceinline__ unsigned short f2bu(float f) {
    union { bf16 h; unsigned short u; } c;
    c.h = __float2bfloat16(f);
    return c.u;
}
__device__ __forceinline__ float gelu(float v) {
    const float c = 0.79788456080286536f * (v + 0.044715f * v * v * v);
    return 0.5f * v * (1.0f + tanhf(c));
}

// ---------------------------------------------------------------------------
// Input dtype detection: flag=1 -> inputs fp32, 0 -> bf16.
__global__ void k_detect(const unsigned short* __restrict__ x, int* __restrict__ flag) {
    int bad = 0;
    for (int i = threadIdx.x; i < 4096; i += 256) {
        const float v = bu(x[i]);
        if (!(fabsf(v) < 1e6f)) bad = 1;
    }
    if (bad) atomicOr(flag, 1);
}

// ---------------------------------------------------------------------------
// Batched conversion of all float inputs -> canonical fp32 ws buffers.
#define NSEG 15
struct CvtDesc {
    const void* src[NSEG];
    float* dst[NSEG];
    int nelem[NSEG];
    int blk0[NSEG];
};

__global__ __launch_bounds__(256) void k_cvt_all(CvtDesc d, const int* __restrict__ flag) {
    const int b = blockIdx.x;
    int s = 0;
    while (s + 1 < NSEG && b >= d.blk0[s + 1]) s++;
    const int i0 = (b - d.blk0[s]) * 1024 + threadIdx.x * 4;
    const int n = d.nelem[s];
    if (i0 >= n) return;
    const bool isf32 = (*flag != 0);
    float* dst = d.dst[s];
    if (i0 + 4 <= n) {
        float4 v;
        if (isf32) {
            v = *(const float4*)((const float*)d.src[s] + i0);
        } else {
            const ushort4 u = *(const ushort4*)((const unsigned short*)d.src[s] + i0);
            v = make_float4(bu(u.x), bu(u.y), bu(u.z), bu(u.w));
        }
        *(float4*)(dst + i0) = v;
    } else {
        for (int j = i0; j < n; j++)
            dst[j] = isf32 ? ((const float*)d.src[s])[j] : bu(((const unsigned short*)d.src[s])[j]);
    }
}

// ---------------------------------------------------------------------------
// CSR build: histogram -> 3-phase parallel scan -> scatter.
__global__ __launch_bounds__(256) void k_hist(
    const int* __restrict__ dst_dg, const int* __restrict__ dst_gg,
    const int* __restrict__ dst_gd,
    int* __restrict__ cnt_g, int* __restrict__ cnt_d) {
    const int i = blockIdx.x * 256 + threadIdx.x;
    if (i < E_DG) atomicAdd(cnt_g + dst_dg[i], 1);
    else if (i < EG) atomicAdd(cnt_g + dst_gg[i - E_DG], 1);
    else if (i < NE) atomicAdd(cnt_d + dst_gd[i - EG], 1);
}

__global__ __launch_bounds__(256) void k_scan_p1(
    const int* __restrict__ cnt_g, const int* __restrict__ cnt_d,
    int* __restrict__ bsum) {
    const int b = blockIdx.x;
    const int* cnt = (b < NBG) ? cnt_g : cnt_d;
    const int n = (b < NBG) ? NG : ND;
    const int i0 = ((b < NBG) ? b : (b - NBG)) * 1024 + threadIdx.x * 4;
    int s = 0;
#pragma unroll
    for (int j = 0; j < 4; j++)
        if (i0 + j < n) s += cnt[i0 + j];
    __shared__ int red[256];
    red[threadIdx.x] = s;
    __syncthreads();
    for (int d = 128; d > 0; d >>= 1) {
        if (threadIdx.x < d) red[threadIdx.x] += red[threadIdx.x + d];
        __syncthreads();
    }
    if (threadIdx.x == 0) bsum[b] = red[0];
}

__global__ void k_scan_p2(int* __restrict__ bsum) {
    if (threadIdx.x == 0) {
        int acc = 0;
        for (int i = 0; i < NBG; i++) { const int v = bsum[i]; bsum[i] = acc; acc += v; }
        acc = 0;
        for (int i = NBG; i < NBG + NBD; i++) { const int v = bsum[i]; bsum[i] = acc; acc += v; }
    }
}

__global__ __launch_bounds__(256) void k_scan_p3(
    const int* __restrict__ cnt_g, const int* __restrict__ cnt_d,
    const int* __restrict__ bsum,
    int* __restrict__ rp_g, int* __restrict__ cur_g,
    int* __restrict__ rp_d, int* __restrict__ cur_d) {
    const int b = blockIdx.x;
    const bool isg = (b < NBG);
    const int* cnt = isg ? cnt_g : cnt_d;
    int* rp = isg ? rp_g : rp_d;
    int* cur = isg ? cur_g : cur_d;
    const int n = isg ? NG : ND;
    const int i0 = (isg ? b : (b - NBG)) * 1024 + threadIdx.x * 4;
    int v[4];
    int t = 0;
#pragma unroll
    for (int j = 0; j < 4; j++) {
        v[j] = (i0 + j < n) ? cnt[i0 + j] : 0;
        t += v[j];
    }
    __shared__ int sdata[256];
    sdata[threadIdx.x] = t;
    __syncthreads();
    for (int d = 1; d < 256; d <<= 1) {
        const int u = (threadIdx.x >= d) ? sdata[threadIdx.x - d] : 0;
        __syncthreads();
        sdata[threadIdx.x] += u;
        __syncthreads();
    }
    int run = bsum[b] + sdata[threadIdx.x] - t;
#pragma unroll
    for (int j = 0; j < 4; j++) {
        if (i0 + j < n) {
            cur[i0 + j] = run;
            run += v[j];
            rp[i0 + j + 1] = run;
        }
    }
    if (threadIdx.x == 0 && (b == 0 || b == NBG)) rp[0] = 0;
}

// edge record: (src << 2) | edge_type
__global__ __launch_bounds__(256) void k_scatter(
    const int* __restrict__ src_dg, const int* __restrict__ dst_dg,
    const int* __restrict__ src_gg, const int* __restrict__ dst_gg,
    const int* __restrict__ src_gd, const int* __restrict__ dst_gd,
    int* __restrict__ cur_g, int* __restrict__ cur_d,
    int* __restrict__ edges_g, int* __restrict__ edges_d) {
    const int i = blockIdx.x * 256 + threadIdx.x;
    if (i < E_DG) {
        const int pos = atomicAdd(cur_g + dst_dg[i], 1);
        edges_g[pos] = (src_dg[i] << 2) | 0;
    } else if (i < EG) {
        const int j = i - E_DG;
        const int pos = atomicAdd(cur_g + dst_gg[j], 1);
        edges_g[pos] = (src_gg[j] << 2) | 2;
    } else if (i < NE) {
        const int j = i - EG;
        const int pos = atomicAdd(cur_d + dst_gd[j], 1);
        edges_d[pos] = src_gd[j] << 2;
    }
}

// ---------------------------------------------------------------------------
// Combined-weight precompute: fold per-edge-type relation matrices into the
// KQV projection. W'k_et = Wk . blockdiag(A_et), b'k_et = bk . A_et (fp32),
// then pack bf16 into MFMA-B-friendly layout Wp[kb][col][32].
// Disease cols [q|k0|v0] (OC=384); gene cols [q|k1|v1|k2|v2] (OC=640).
template <int GENE>
__global__ __launch_bounds__(256) void k_combine(
    const float* __restrict__ W,      // [L][128][384] canonical
    const float* __restrict__ bvec,   // [L][384]
    const float* __restrict__ arel,   // [L][3][H][32][32]
    const float* __restrict__ mrel,
    unsigned short* __restrict__ Wp,  // [L][4][OC][32] bf16
    float* __restrict__ bp) {         // [L][OC]
    const int OC = GENE ? OCG : OCD;
    const int idx = blockIdx.x * 256 + threadIdx.x;
    if (idx >= NLAYER * OC * 128) return;
    const int l = idx / (OC * 128);
    const int rem = idx - l * OC * 128;
    const int col = rem >> 7;
    const int d = rem & 127;
    const int g = col >> 7;           // 0=q, 1/3=k, 2/4=v
    const int jj = col & 127;
    const int h = jj >> 5, f = jj & 31;
    const float* Wl = W + (size_t)l * 128 * 384;
    const float* bl = bvec + l * 384;
    float val, bv = 0.f;
    if (g == 0) {
        val = Wl[d * 384 + 128 + jj];
        bv = bl[128 + jj];
    } else {
        const int et = GENE ? ((g <= 2) ? 1 : 2) : 0;
        const bool isk = (g & 1);
        const float* mat = (isk ? arel : mrel) + (((size_t)(l * 3 + et) * H + h) << 10) + f;
        const int sb = isk ? 0 : 256;
        val = 0.f;
        for (int dd = 0; dd < 32; dd++)
            val += Wl[d * 384 + sb + h * 32 + dd] * mat[dd * 32];
        if (d == 0)
            for (int dd = 0; dd < 32; dd++)
                bv += bl[sb + h * 32 + dd] * mat[dd * 32];
    }
    Wp[(size_t)l * 4 * OC * 32 + ((size_t)(d >> 5) * OC + col) * 32 + (d & 31)] = f2bu(val);
    if (d == 0) bp[l * OC + col] = bv;
}

// ---------------------------------------------------------------------------
// fp32 -> bf16 cast (x tables for MFMA A operand)
__global__ __launch_bounds__(256) void k_f2b(
    const float* __restrict__ in, unsigned short* __restrict__ out, int n4) {
    const int i = blockIdx.x * 256 + threadIdx.x;
    if (i < n4) {
        const float4 v = ((const float4*)in)[i];
        ushort4 u;
        u.x = f2bu(v.x); u.y = f2bu(v.y); u.z = f2bu(v.z); u.w = f2bu(v.w);
        ((ushort4*)out)[i] = u;
    }
}

// ---------------------------------------------------------------------------
// MFMA GEMM: out[N][OC] (bf16) = xb[N][128] @ Wp + bias. 4 waves/block, each
// wave does a 16x64 tile via 4 accumulators, K=128 in 4 steps of 32.
// A-frag: lane holds xb[node0 + (lane&15)][kb*32 + (lane>>4)*8 + 0..7].
// B packed as Wp[kb][col][32] so the lane's 8-k fragment is one 16B load.
__global__ __launch_bounds__(256) void k_gemm(
    const unsigned short* __restrict__ xb, const unsigned short* __restrict__ Wp,
    const float* __restrict__ bias, unsigned short* __restrict__ out,
    int mtiles, int OC) {
    const int ntiles = OC >> 6;
    const int w = blockIdx.x * 4 + (threadIdx.x >> 6);
    const int mt = w / ntiles, nt = w - mt * ntiles;
    if (mt >= mtiles) return;
    const int lane = threadIdx.x & 63;
    const int r = lane & 15, q4 = lane >> 4;
    const int node0 = mt << 4, col0 = nt << 6;
    f32x4 acc0 = {0.f, 0.f, 0.f, 0.f};
    f32x4 acc1 = acc0, acc2 = acc0, acc3 = acc0;
#pragma unroll
    for (int kb = 0; kb < 4; kb++) {
        const short8 a = *(const short8*)(xb + (size_t)(node0 + r) * 128 + kb * 32 + q4 * 8);
        const unsigned short* wb = Wp + ((size_t)kb * OC + col0 + r) * 32 + q4 * 8;
        const short8 b0 = *(const short8*)(wb);
        const short8 b1 = *(const short8*)(wb + 512);
        const short8 b2 = *(const short8*)(wb + 1024);
        const short8 b3 = *(const short8*)(wb + 1536);
        acc0 = __builtin_amdgcn_mfma_f32_16x16x32_bf16(a, b0, acc0, 0, 0, 0);
        acc1 = __builtin_amdgcn_mfma_f32_16x16x32_bf16(a, b1, acc1, 0, 0, 0);
        acc2 = __builtin_amdgcn_mfma_f32_16x16x32_bf16(a, b2, acc2, 0, 0, 0);
        acc3 = __builtin_amdgcn_mfma_f32_16x16x32_bf16(a, b3, acc3, 0, 0, 0);
    }
    const f32x4 accs[4] = {acc0, acc1, acc2, acc3};
#pragma unroll
    for (int t = 0; t < 4; t++) {
        const int col = col0 + t * 16 + r;
        const float bb = bias[col];
#pragma unroll
        for (int reg = 0; reg < 4; reg++)
            out[(size_t)(node0 + q4 * 4 + reg) * OC + col] = f2bu(accs[t][reg] + bb);
    }
}

// ---------------------------------------------------------------------------
// Gather-style per-node aggregation over interleaved tables.
// q at tabq[node*sq + off]; k at tab[src*s + off], v at +128 cols.
template <int GENE>
__global__ __launch_bounds__(256) void k_node_agg(
    const int* __restrict__ rowptr, const int* __restrict__ edges,
    const unsigned short* __restrict__ tabq, int sq,
    const unsigned short* __restrict__ tabA, int sA,
    const unsigned short* __restrict__ tabB, int sB,
    const float* __restrict__ prel, float* __restrict__ agg, int nnode) {
    const int node = blockIdx.x * 4 + (threadIdx.x >> 6);
    if (node >= nnode) return;
    const int lane = threadIdx.x & 63;
    const int h = lane >> 4;
    const int off = h * D + (lane & 15) * 2;
    const float scale = 0.17677669529663689f;
    const float pA = prel[(GENE ? 0 : 1) * H + h] * scale;
    const float pB = GENE ? prel[2 * H + h] * scale : 0.f;

    const ushort2 qu = *(const ushort2*)(tabq + (size_t)node * sq + off);
    const float q0 = bu(qu.x), q1 = bu(qu.y);

    float m = -1e30f, s = 0.f, a0 = 0.f, a1 = 0.f;
    const int e1 = rowptr[node + 1];
    for (int e = rowptr[node]; e < e1; e++) {
        const int rec = edges[e];
        const int src = rec >> 2;
        const bool isB = GENE && ((rec & 3) == 2);
        const unsigned short* kt = (isB ? tabB : tabA) + (size_t)src * (isB ? sB : sA) + off;
        const ushort2 ku = *(const ushort2*)kt;
        const ushort2 vu = *(const ushort2*)(kt + 128);
        float p = q0 * bu(ku.x) + q1 * bu(ku.y);
        p += __shfl_xor(p, 1);
        p += __shfl_xor(p, 2);
        p += __shfl_xor(p, 4);
        p += __shfl_xor(p, 8);
        const float a = p * (isB ? pB : pA);
        const float mn = fmaxf(m, a);
        const float c = __expf(m - mn);
        const float ea = __expf(a - mn);
        s = s * c + ea;
        a0 = a0 * c + ea * bu(vu.x);
        a1 = a1 * c + ea * bu(vu.y);
        m = mn;
    }
    const float inv = (s > 0.f) ? (1.f / s) : 0.f;
    *(float2*)(agg + (size_t)node * HD + off) = make_float2(a0 * inv, a1 * inv);
}

// ---------------------------------------------------------------------------
// Update: gelu(agg) @ Wout + bout -> skip-gate mix; write fp32 x (+fp32 out)
template <int LAST>
__global__ __launch_bounds__(128) void k_update(
    const float* __restrict__ agg,
    const float* __restrict__ Wout, const float* __restrict__ bout,
    const float* __restrict__ skip,
    float* __restrict__ x, float* __restrict__ xout) {
    __shared__ float gs[16 * HD];
    const int tid = threadIdx.x;
    const int node0 = blockIdx.x * 16;
    for (int f4 = tid; f4 < 512; f4 += 128) {
        const int n = f4 >> 5, dp = f4 & 31;
        float4 v = *(const float4*)(agg + (size_t)(node0 + n) * HD + dp * 4);
        v.x = gelu(v.x);
        v.y = gelu(v.y);
        v.z = gelu(v.z);
        v.w = gelu(v.w);
        *(float4*)(gs + n * HD + dp * 4) = v;
    }
    __syncthreads();
    float acc[16];
#pragma unroll
    for (int n = 0; n < 16; n++) acc[n] = 0.f;
    const int o = tid;
    for (int d = 0; d < HD; d += 4) {
        float4 xv[16];
#pragma unroll
        for (int n = 0; n < 16; n++) xv[n] = *(const float4*)(gs + n * HD + d);
#pragma unroll
        for (int j = 0; j < 4; j++) {
            const float w = Wout[(d + j) * HD + o];
#pragma unroll
            for (int n = 0; n < 16; n++)
                acc[n] = fmaf(((const float*)&xv[n])[j], w, acc[n]);
        }
    }
    const float bb = bout[o];
    const float g = 1.f / (1.f + expf(-skip[0]));
#pragma unroll
    for (int n = 0; n < 16; n++) {
        const size_t idx = (size_t)(node0 + n) * HD + o;
        const float xn = g * (acc[n] + bb) + (1.f - g) * x[idx];
        x[idx] = xn;
        if (LAST) xout[idx] = xn;
    }
}

// ---------------------------------------------------------------------------
static inline size_t alignup(size_t v) { return (v + 15) & ~(size_t)15; }

extern "C" void kernel_launch(void* const* d_in, const int* in_sizes, int n_in,
                              void* d_out, int out_size, void* d_ws, size_t ws_size,
                              hipStream_t stream) {
    (void)in_sizes; (void)n_in; (void)out_size; (void)ws_size;
    const int* src_dg = (const int*)d_in[2];
    const int* dst_dg = (const int*)d_in[3];
    const int* src_gd = (const int*)d_in[4];
    const int* dst_gd = (const int*)d_in[5];
    const int* src_gg = (const int*)d_in[6];
    const int* dst_gg = (const int*)d_in[7];

    // ---- workspace carve-up ----
    float* ws = (float*)d_ws;
    float* xd   = ws; ws += alignup((size_t)ND * HD);
    float* xg   = ws; ws += alignup((size_t)NG * HD);
    float* aggd = ws; ws += alignup((size_t)ND * HD);
    float* aggg = ws; ws += alignup((size_t)NG * HD);
    int* flag = (int*)ws; ws += 16;
    // CSR
    int* cnt_g  = (int*)ws; ws += alignup(NG);
    int* cnt_d  = (int*)ws; ws += alignup(ND);
    int* rp_g   = (int*)ws; ws += alignup(NG + 1);
    int* rp_d   = (int*)ws; ws += alignup(ND + 1);
    int* cur_g  = (int*)ws; ws += alignup(NG);
    int* cur_d  = (int*)ws; ws += alignup(ND);
    int* bsum   = (int*)ws; ws += alignup(NBG + NBD);
    int* edges_g = (int*)ws; ws += alignup(EG);
    int* edges_d = (int*)ws; ws += alignup(E_GD);
    // canonical fp32 inputs
    float* wkqvd = ws; ws += alignup((size_t)NLAYER * HD * 3 * HD);
    float* bkqvd = ws; ws += alignup((size_t)NLAYER * 3 * HD);
    float* wkqvg = ws; ws += alignup((size_t)NLAYER * HD * 3 * HD);
    float* bkqvg = ws; ws += alignup((size_t)NLAYER * 3 * HD);
    float* woutd = ws; ws += alignup((size_t)NLAYER * HD * HD);
    float* boutd = ws; ws += alignup((size_t)NLAYER * HD);
    float* woutg = ws; ws += alignup((size_t)NLAYER * HD * HD);
    float* boutg = ws; ws += alignup((size_t)NLAYER * HD);
    float* skipd = ws; ws += 16;
    float* skipg = ws; ws += 16;
    float* arelc = ws; ws += alignup((size_t)NLAYER * 3 * H * D * D);
    float* mrelc = ws; ws += alignup((size_t)NLAYER * 3 * H * D * D);
    float* prelc = ws; ws += 16;
    // combined bias (fp32)
    float* bp_d = ws; ws += alignup((size_t)NLAYER * OCD);
    float* bp_g = ws; ws += alignup((size_t)NLAYER * OCG);
    // bf16 regions
    unsigned short* Wp_d = (unsigned short*)ws; ws += alignup((size_t)NLAYER * 4 * OCD * 32 / 2);
    unsigned short* Wp_g = (unsigned short*)ws; ws += alignup((size_t)NLAYER * 4 * OCG * 32 / 2);
    unsigned short* xbd = (unsigned short*)ws; ws += alignup((size_t)ND * HD / 2);
    unsigned short* xbg = (unsigned short*)ws; ws += alignup((size_t)NG * HD / 2);
    unsigned short* tab_d = (unsigned short*)ws; ws += alignup((size_t)ND * OCD / 2);
    unsigned short* tab_g = (unsigned short*)ws; ws += alignup((size_t)NG * OCG / 2);

    // ---- dtype detect + canonicalize ----
    hipMemsetAsync(flag, 0, 4, stream);
    k_detect<<<1, 256, 0, stream>>>((const unsigned short*)d_in[0], flag);

    CvtDesc cd;
    const int seg_in[NSEG] = {0, 1, 8, 9, 10, 11, 12, 13, 14, 15, 16, 17, 18, 19, 20};
    float* const seg_dst[NSEG] = {xd, xg, wkqvd, bkqvd, wkqvg, bkqvg, woutd, boutd,
                                  woutg, boutg, skipd, skipg, arelc, mrelc, prelc};
    const int seg_n[NSEG] = {ND * HD, NG * HD,
                             NLAYER * HD * 3 * HD, NLAYER * 3 * HD,
                             NLAYER * HD * 3 * HD, NLAYER * 3 * HD,
                             NLAYER * HD * HD, NLAYER * HD,
                             NLAYER * HD * HD, NLAYER * HD,
                             NLAYER, NLAYER,
                             NLAYER * 3 * H * D * D, NLAYER * 3 * H * D * D,
                             NLAYER * 3 * H};
    int nblk = 0;
    for (int s = 0; s < NSEG; s++) {
        cd.src[s] = d_in[seg_in[s]];
        cd.dst[s] = seg_dst[s];
        cd.nelem[s] = seg_n[s];
        cd.blk0[s] = nblk;
        nblk += (seg_n[s] + 1023) / 1024;
    }
    k_cvt_all<<<nblk, 256, 0, stream>>>(cd, flag);

    // ---- combined weights (once) ----
    k_combine<0><<<(NLAYER * OCD * 128 + 255) / 256, 256, 0, stream>>>(
        wkqvd, bkqvd, arelc, mrelc, Wp_d, bp_d);
    k_combine<1><<<(NLAYER * OCG * 128 + 255) / 256, 256, 0, stream>>>(
        wkqvg, bkqvg, arelc, mrelc, Wp_g, bp_g);

    // ---- CSR build (once; graph is layer-invariant) ----
    hipMemsetAsync(cnt_g, 0, sizeof(int) * NG, stream);
    hipMemsetAsync(cnt_d, 0, sizeof(int) * ND, stream);
    k_hist<<<(NE + 255) / 256, 256, 0, stream>>>(dst_dg, dst_gg, dst_gd, cnt_g, cnt_d);
    k_scan_p1<<<NBG + NBD, 256, 0, stream>>>(cnt_g, cnt_d, bsum);
    k_scan_p2<<<1, 64, 0, stream>>>(bsum);
    k_scan_p3<<<NBG + NBD, 256, 0, stream>>>(cnt_g, cnt_d, bsum, rp_g, cur_g, rp_d, cur_d);
    k_scatter<<<(NE + 255) / 256, 256, 0, stream>>>(
        src_dg, dst_dg, src_gg, dst_gg, src_gd, dst_gd,
        cur_g, cur_d, edges_g, edges_d);

    for (int l = 0; l < NLAYER; l++) {
        k_f2b<<<(ND * 32 + 255) / 256, 256, 0, stream>>>(xd, xbd, ND * 32);
        k_f2b<<<(NG * 32 + 255) / 256, 256, 0, stream>>>(xg, xbg, NG * 32);
        k_gemm<<<(625 * (OCD / 64) + 3) / 4, 256, 0, stream>>>(
            xbd, Wp_d + (size_t)l * 4 * OCD * 32, bp_d + l * OCD, tab_d, 625, OCD);
        k_gemm<<<(1875 * (OCG / 64) + 3) / 4, 256, 0, stream>>>(
            xbg, Wp_g + (size_t)l * 4 * OCG * 32, bp_g + l * OCG, tab_g, 1875, OCG);
        // gene dst: et0 k/v in tab_d cols 128/256; et2 k/v in tab_g cols 384/512
        k_node_agg<1><<<(NG + 3) / 4, 256, 0, stream>>>(
            rp_g, edges_g, tab_g, OCG, tab_d + 128, OCD, tab_g + 384, OCG,
            prelc + l * 3 * H, aggg, NG);
        // disease dst: et1 k/v in tab_g cols 128/256
        k_node_agg<0><<<(ND + 3) / 4, 256, 0, stream>>>(
            rp_d, edges_d, tab_d, OCD, tab_g + 128, OCG, nullptr, 0,
            prelc + l * 3 * H, aggd, ND);
        if (l == NLAYER - 1) {
            k_update<1><<<ND / 16, 128, 0, stream>>>(
                aggd, woutd + (size_t)l * HD * HD, boutd + l * HD,
                skipd + l, xd, (float*)d_out);
            k_update<1><<<NG / 16, 128, 0, stream>>>(
                aggg, woutg + (size_t)l * HD * HD, boutg + l * HD,
                skipg + l, xg, (float*)d_out + (size_t)ND * HD);
        } else {
            k_update<0><<<ND / 16, 128, 0, stream>>>(
                aggd, woutd + (size_t)l * HD * HD, boutd + l * HD,
                skipd + l, xd, nullptr);
            k_update<0><<<NG / 16, 128, 0, stream>>>(
                aggg, woutg + (size_t)l * HD * HD, boutg + l * HD,
                skipg + l, xg, nullptr);
        }
    }
}

// Round 7
// 464.335 us; speedup vs baseline: 5.8608x; 1.2678x over previous
//
#include <hip/hip_runtime.h>
#include <hip/hip_bf16.h>

#define H 4
#define D 32
#define HD 128
#define ND 10000
#define NG 30000
#define E_DG 150000
#define E_GD 150000
#define E_GG 300000
#define NE (E_DG + E_GD + E_GG)
#define EG (E_DG + E_GG)   // edges into gene nodes
#define NLAYER 2
#define NBG 30             // ceil(NG/1024)
#define NBD 10             // ceil(ND/1024)
#define OCG 640            // gene table cols:   [q|k1|v1|k2|v2]
#define OCD 384            // disease table cols:[q|k0|v0]

typedef __hip_bfloat16 bf16;
typedef __attribute__((ext_vector_type(8))) short short8;
typedef __attribute__((ext_vector_type(8))) unsigned short u16x8;
typedef __attribute__((ext_vector_type(4))) float f32x4;

__device__ __forceinline__ float bu(unsigned short u) {
    return __uint_as_float(((unsigned)u) << 16);
}
__device__ __forceinline__ unsigned short f2bu(float f) {
    union { bf16 h; unsigned short u; } c;
    c.h = __float2bfloat16(f);
    return c.u;
}
__device__ __forceinline__ float gelu(float v) {
    const float c = 0.79788456080286536f * (v + 0.044715f * v * v * v);
    return 0.5f * v * (1.0f + tanhf(c));
}

// ---------------------------------------------------------------------------
// Input dtype detection: flag=1 -> inputs fp32, 0 -> bf16.
__global__ void k_detect(const unsigned short* __restrict__ x, int* __restrict__ flag) {
    int bad = 0;
    for (int i = threadIdx.x; i < 4096; i += 256) {
        const float v = bu(x[i]);
        if (!(fabsf(v) < 1e6f)) bad = 1;
    }
    if (bad) atomicOr(flag, 1);
}

// ---------------------------------------------------------------------------
// Batched conversion of all float inputs -> canonical fp32 ws buffers.
#define NSEG 15
struct CvtDesc {
    const void* src[NSEG];
    float* dst[NSEG];
    int nelem[NSEG];
    int blk0[NSEG];
};

__global__ __launch_bounds__(256) void k_cvt_all(CvtDesc d, const int* __restrict__ flag) {
    const int b = blockIdx.x;
    int s = 0;
    while (s + 1 < NSEG && b >= d.blk0[s + 1]) s++;
    const int i0 = (b - d.blk0[s]) * 1024 + threadIdx.x * 4;
    const int n = d.nelem[s];
    if (i0 >= n) return;
    const bool isf32 = (*flag != 0);
    float* dst = d.dst[s];
    if (i0 + 4 <= n) {
        float4 v;
        if (isf32) {
            v = *(const float4*)((const float*)d.src[s] + i0);
        } else {
            const ushort4 u = *(const ushort4*)((const unsigned short*)d.src[s] + i0);
            v = make_float4(bu(u.x), bu(u.y), bu(u.z), bu(u.w));
        }
        *(float4*)(dst + i0) = v;
    } else {
        for (int j = i0; j < n; j++)
            dst[j] = isf32 ? ((const float*)d.src[s])[j] : bu(((const unsigned short*)d.src[s])[j]);
    }
}

// ---------------------------------------------------------------------------
// CSR build: histogram -> 3-phase parallel scan -> scatter.
__global__ __launch_bounds__(256) void k_hist(
    const int* __restrict__ dst_dg, const int* __restrict__ dst_gg,
    const int* __restrict__ dst_gd,
    int* __restrict__ cnt_g, int* __restrict__ cnt_d) {
    const int i = blockIdx.x * 256 + threadIdx.x;
    if (i < E_DG) atomicAdd(cnt_g + dst_dg[i], 1);
    else if (i < EG) atomicAdd(cnt_g + dst_gg[i - E_DG], 1);
    else if (i < NE) atomicAdd(cnt_d + dst_gd[i - EG], 1);
}

__global__ __launch_bounds__(256) void k_scan_p1(
    const int* __restrict__ cnt_g, const int* __restrict__ cnt_d,
    int* __restrict__ bsum) {
    const int b = blockIdx.x;
    const int* cnt = (b < NBG) ? cnt_g : cnt_d;
    const int n = (b < NBG) ? NG : ND;
    const int i0 = ((b < NBG) ? b : (b - NBG)) * 1024 + threadIdx.x * 4;
    int s = 0;
#pragma unroll
    for (int j = 0; j < 4; j++)
        if (i0 + j < n) s += cnt[i0 + j];
    __shared__ int red[256];
    red[threadIdx.x] = s;
    __syncthreads();
    for (int d = 128; d > 0; d >>= 1) {
        if (threadIdx.x < d) red[threadIdx.x] += red[threadIdx.x + d];
        __syncthreads();
    }
    if (threadIdx.x == 0) bsum[b] = red[0];
}

__global__ void k_scan_p2(int* __restrict__ bsum) {
    if (threadIdx.x == 0) {
        int acc = 0;
        for (int i = 0; i < NBG; i++) { const int v = bsum[i]; bsum[i] = acc; acc += v; }
        acc = 0;
        for (int i = NBG; i < NBG + NBD; i++) { const int v = bsum[i]; bsum[i] = acc; acc += v; }
    }
}

__global__ __launch_bounds__(256) void k_scan_p3(
    const int* __restrict__ cnt_g, const int* __restrict__ cnt_d,
    const int* __restrict__ bsum,
    int* __restrict__ rp_g, int* __restrict__ cur_g,
    int* __restrict__ rp_d, int* __restrict__ cur_d) {
    const int b = blockIdx.x;
    const bool isg = (b < NBG);
    const int* cnt = isg ? cnt_g : cnt_d;
    int* rp = isg ? rp_g : rp_d;
    int* cur = isg ? cur_g : cur_d;
    const int n = isg ? NG : ND;
    const int i0 = (isg ? b : (b - NBG)) * 1024 + threadIdx.x * 4;
    int v[4];
    int t = 0;
#pragma unroll
    for (int j = 0; j < 4; j++) {
        v[j] = (i0 + j < n) ? cnt[i0 + j] : 0;
        t += v[j];
    }
    __shared__ int sdata[256];
    sdata[threadIdx.x] = t;
    __syncthreads();
    for (int d = 1; d < 256; d <<= 1) {
        const int u = (threadIdx.x >= d) ? sdata[threadIdx.x - d] : 0;
        __syncthreads();
        sdata[threadIdx.x] += u;
        __syncthreads();
    }
    int run = bsum[b] + sdata[threadIdx.x] - t;
#pragma unroll
    for (int j = 0; j < 4; j++) {
        if (i0 + j < n) {
            cur[i0 + j] = run;
            run += v[j];
            rp[i0 + j + 1] = run;
        }
    }
    if (threadIdx.x == 0 && (b == 0 || b == NBG)) rp[0] = 0;
}

// edge record: (src << 2) | edge_type  (et: 0=d->g, 1=g->d, 2=g->g)
__global__ __launch_bounds__(256) void k_scatter(
    const int* __restrict__ src_dg, const int* __restrict__ dst_dg,
    const int* __restrict__ src_gg, const int* __restrict__ dst_gg,
    const int* __restrict__ src_gd, const int* __restrict__ dst_gd,
    int* __restrict__ cur_g, int* __restrict__ cur_d,
    int* __restrict__ edges_g, int* __restrict__ edges_d) {
    const int i = blockIdx.x * 256 + threadIdx.x;
    if (i < E_DG) {
        const int pos = atomicAdd(cur_g + dst_dg[i], 1);
        edges_g[pos] = (src_dg[i] << 2) | 0;
    } else if (i < EG) {
        const int j = i - E_DG;
        const int pos = atomicAdd(cur_g + dst_gg[j], 1);
        edges_g[pos] = (src_gg[j] << 2) | 2;
    } else if (i < NE) {
        const int j = i - EG;
        const int pos = atomicAdd(cur_d + dst_gd[j], 1);
        edges_d[pos] = (src_gd[j] << 2) | 1;
    }
}

// ---------------------------------------------------------------------------
// Combined-weight precompute (see r5): fold relation matrices into KQV weights.
template <int GENE>
__global__ __launch_bounds__(256) void k_combine(
    const float* __restrict__ W,      // [L][128][384] canonical
    const float* __restrict__ bvec,   // [L][384]
    const float* __restrict__ arel,   // [L][3][H][32][32]
    const float* __restrict__ mrel,
    unsigned short* __restrict__ Wp,  // [L][4][OC][32] bf16
    float* __restrict__ bp) {         // [L][OC]
    const int OC = GENE ? OCG : OCD;
    const int idx = blockIdx.x * 256 + threadIdx.x;
    if (idx >= NLAYER * OC * 128) return;
    const int l = idx / (OC * 128);
    const int rem = idx - l * OC * 128;
    const int col = rem >> 7;
    const int d = rem & 127;
    const int g = col >> 7;           // 0=q, 1/3=k, 2/4=v
    const int jj = col & 127;
    const int h = jj >> 5, f = jj & 31;
    const float* Wl = W + (size_t)l * 128 * 384;
    const float* bl = bvec + l * 384;
    float val, bv = 0.f;
    if (g == 0) {
        val = Wl[d * 384 + 128 + jj];
        bv = bl[128 + jj];
    } else {
        const int et = GENE ? ((g <= 2) ? 1 : 2) : 0;
        const bool isk = (g & 1);
        const float* mat = (isk ? arel : mrel) + (((size_t)(l * 3 + et) * H + h) << 10) + f;
        const int sb = isk ? 0 : 256;
        val = 0.f;
        for (int dd = 0; dd < 32; dd++)
            val += Wl[d * 384 + sb + h * 32 + dd] * mat[dd * 32];
        if (d == 0)
            for (int dd = 0; dd < 32; dd++)
                bv += bl[sb + h * 32 + dd] * mat[dd * 32];
    }
    Wp[(size_t)l * 4 * OC * 32 + ((size_t)(d >> 5) * OC + col) * 32 + (d & 31)] = f2bu(val);
    if (d == 0) bp[l * OC + col] = bv;
}

// ---------------------------------------------------------------------------
// fp32 -> bf16 cast
__global__ __launch_bounds__(256) void k_f2b(
    const float* __restrict__ in, unsigned short* __restrict__ out, int n4) {
    const int i = blockIdx.x * 256 + threadIdx.x;
    if (i < n4) {
        const float4 v = ((const float4*)in)[i];
        ushort4 u;
        u.x = f2bu(v.x); u.y = f2bu(v.y); u.z = f2bu(v.z); u.w = f2bu(v.w);
        ((ushort4*)out)[i] = u;
    }
}

// ---------------------------------------------------------------------------
// Merged MFMA GEMM for both node types (see r5 layout notes).
// waves 0..3749: disease (625 mtiles x 6 ntiles); 3750..: gene (1875 x 10).
__global__ __launch_bounds__(256) void k_gemm2(
    const unsigned short* __restrict__ xbd, const unsigned short* __restrict__ Wpd,
    const float* __restrict__ bpd, unsigned short* __restrict__ outd,
    const unsigned short* __restrict__ xbg, const unsigned short* __restrict__ Wpg,
    const float* __restrict__ bpg, unsigned short* __restrict__ outg) {
    int w = blockIdx.x * 4 + (threadIdx.x >> 6);
    const unsigned short *xb, *Wp;
    const float* bias;
    unsigned short* out;
    int mt, nt, OC;
    if (w < 3750) {
        xb = xbd; Wp = Wpd; bias = bpd; out = outd; OC = OCD;
        mt = w / 6; nt = w - mt * 6;
    } else {
        w -= 3750;
        xb = xbg; Wp = Wpg; bias = bpg; out = outg; OC = OCG;
        mt = w / 10; nt = w - mt * 10;
    }
    const int lane = threadIdx.x & 63;
    const int r = lane & 15, q4 = lane >> 4;
    const int node0 = mt << 4, col0 = nt << 6;
    f32x4 acc0 = {0.f, 0.f, 0.f, 0.f};
    f32x4 acc1 = acc0, acc2 = acc0, acc3 = acc0;
#pragma unroll
    for (int kb = 0; kb < 4; kb++) {
        const short8 a = *(const short8*)(xb + (size_t)(node0 + r) * 128 + kb * 32 + q4 * 8);
        const unsigned short* wb = Wp + ((size_t)kb * OC + col0 + r) * 32 + q4 * 8;
        const short8 b0 = *(const short8*)(wb);
        const short8 b1 = *(const short8*)(wb + 512);
        const short8 b2 = *(const short8*)(wb + 1024);
        const short8 b3 = *(const short8*)(wb + 1536);
        acc0 = __builtin_amdgcn_mfma_f32_16x16x32_bf16(a, b0, acc0, 0, 0, 0);
        acc1 = __builtin_amdgcn_mfma_f32_16x16x32_bf16(a, b1, acc1, 0, 0, 0);
        acc2 = __builtin_amdgcn_mfma_f32_16x16x32_bf16(a, b2, acc2, 0, 0, 0);
        acc3 = __builtin_amdgcn_mfma_f32_16x16x32_bf16(a, b3, acc3, 0, 0, 0);
    }
    const f32x4 accs[4] = {acc0, acc1, acc2, acc3};
#pragma unroll
    for (int t = 0; t < 4; t++) {
        const int col = col0 + t * 16 + r;
        const float bb = bias[col];
#pragma unroll
        for (int reg = 0; reg < 4; reg++)
            out[(size_t)(node0 + q4 * 4 + reg) * OC + col] = f2bu(accs[t][reg] + bb);
    }
}

// ---------------------------------------------------------------------------
// Unified gather aggregation: one wave per dst node (gene waves 0..NG-1,
// disease waves NG..NG+ND-1). 4 slots x 16 lanes; each slot runs an
// independent online-softmax chain over every 4th edge; merged at the end
// (associative). Lane sub covers elements sub*8..sub*8+7 (head = sub>>2).
// Log2-domain softmax (log2e folded into prel scale). k at table row +0,
// v at +128 cols. Software prefetch: rec two-ahead, k/v one-ahead.
__global__ __launch_bounds__(256) void k_agg(
    const int* __restrict__ rp_g, const int* __restrict__ edges_g,
    const int* __restrict__ rp_d, const int* __restrict__ edges_d,
    const unsigned short* __restrict__ tab_d, const unsigned short* __restrict__ tab_g,
    const float* __restrict__ prel,   // [3][H] layer slice
    float* __restrict__ agg) {        // [NG+ND][128], gene rows first
    const int wid = blockIdx.x * 4 + (threadIdx.x >> 6);
    const int lane = threadIdx.x & 63;
    const int slot = lane >> 4, sub = lane & 15;
    const int h = sub >> 2;

    int node;
    const int *rp, *edges;
    const unsigned short* tq;
    int sq;
    float* aggrow;
    if (wid < NG) {
        node = wid; rp = rp_g; edges = edges_g; tq = tab_g; sq = OCG;
        aggrow = agg + (size_t)node * HD;
    } else {
        node = wid - NG; rp = rp_d; edges = edges_d; tq = tab_d; sq = OCD;
        aggrow = agg + (size_t)(NG + node) * HD;
    }

    // q fragment (8 elems) -> fp32
    const u16x8 q8 = *(const u16x8*)(tq + (size_t)node * sq + sub * 8);
    float qf[8];
#pragma unroll
    for (int i = 0; i < 8; i++) qf[i] = bu(q8[i]);

    const float pscale = 0.17677669529663689f * 1.4426950408889634f;  // scale*log2e
    const float pet0 = prel[0 * H + h] * pscale;
    const float pet1 = prel[1 * H + h] * pscale;
    const float pet2 = prel[2 * H + h] * pscale;

    // k/v base table per edge type (et0: tab_d+128/OCD; et1: tab_g+128/OCG; et2: tab_g+384/OCG)
    float m = -1e30f, s = 0.f;
    float acc[8];
#pragma unroll
    for (int i = 0; i < 8; i++) acc[i] = 0.f;

    const int r0 = rp[node], r1 = rp[node + 1];
    int e = r0 + slot;
    int rec0 = (e < r1) ? edges[e] : 0;
    int rec1 = (e + 4 < r1) ? edges[e + 4] : 0;

    // stage-0 k/v load
    u16x8 k0, v0;
    {
        const int src = rec0 >> 2, et = rec0 & 3;
        const unsigned short* base = (et == 0) ? (tab_d + 128) : (et == 1) ? (tab_g + 128) : (tab_g + 384);
        const int stride = (et == 0) ? OCD : OCG;
        const unsigned short* p = base + (size_t)src * stride + sub * 8;
        k0 = *(const u16x8*)p;
        v0 = *(const u16x8*)(p + 128);
    }

    while (e < r1) {
        // prefetch next k/v (from rec1) and rec two ahead
        const int rec2 = (e + 8 < r1) ? edges[e + 8] : 0;
        u16x8 k1, v1;
        {
            const int src = rec1 >> 2, et = rec1 & 3;
            const unsigned short* base = (et == 0) ? (tab_d + 128) : (et == 1) ? (tab_g + 128) : (tab_g + 384);
            const int stride = (et == 0) ? OCD : OCG;
            const unsigned short* p = base + (size_t)src * stride + sub * 8;
            k1 = *(const u16x8*)p;
            v1 = *(const u16x8*)(p + 128);
        }
        // compute current edge
        float p = 0.f;
#pragma unroll
        for (int i = 0; i < 8; i++) p = fmaf(qf[i], bu(k0[i]), p);
        p += __shfl_xor(p, 1);
        p += __shfl_xor(p, 2);
        const int et = rec0 & 3;
        const float pa = (et == 0) ? pet0 : (et == 1) ? pet1 : pet2;
        const float a = p * pa;
        const float mn = fmaxf(m, a);
        const float c = exp2f(m - mn);
        const float ea = exp2f(a - mn);
        s = s * c + ea;
#pragma unroll
        for (int i = 0; i < 8; i++) acc[i] = fmaf(acc[i], c, ea * bu(v0[i]));
        m = mn;
        // shift pipeline
        rec0 = rec1; rec1 = rec2; k0 = k1; v0 = v1;
        e += 4;
    }

    // merge the 4 slot-chains (associative online-softmax merge)
#pragma unroll
    for (int mask = 16; mask <= 32; mask <<= 1) {
        const float m2 = __shfl_xor(m, mask);
        const float s2 = __shfl_xor(s, mask);
        const float M = fmaxf(m, m2);
        const float c1 = exp2f(m - M);
        const float c2 = exp2f(m2 - M);
        s = s * c1 + s2 * c2;
#pragma unroll
        for (int i = 0; i < 8; i++) {
            const float o = __shfl_xor(acc[i], mask);
            acc[i] = acc[i] * c1 + o * c2;
        }
        m = M;
    }

    const float inv = (s > 0.f) ? (1.f / s) : 0.f;
    if (slot == 0) {
        float4 o0 = make_float4(acc[0] * inv, acc[1] * inv, acc[2] * inv, acc[3] * inv);
        float4 o1 = make_float4(acc[4] * inv, acc[5] * inv, acc[6] * inv, acc[7] * inv);
        *(float4*)(aggrow + sub * 8) = o0;
        *(float4*)(aggrow + sub * 8 + 4) = o1;
    }
}

// ---------------------------------------------------------------------------
// Merged update for both node types: gelu(agg) @ Wout + bout -> skip mix.
// Writes fp32 x, bf16 xb (next layer's GEMM input), and (last) fp32 d_out.
__global__ __launch_bounds__(128) void k_update2(
    const float* __restrict__ agg,   // [NG+ND][128], gene first
    const float* __restrict__ Woutg, const float* __restrict__ boutg,
    const float* __restrict__ skipg, float* __restrict__ xg, unsigned short* __restrict__ xbg,
    const float* __restrict__ Woutd, const float* __restrict__ boutd,
    const float* __restrict__ skipd, float* __restrict__ xd, unsigned short* __restrict__ xbd,
    int last, float* __restrict__ dout) {
    const int b = blockIdx.x;
    const bool gene = (b < NG / 16);
    const int node0 = (gene ? b : (b - NG / 16)) * 16;
    const float* ag = agg + (gene ? (size_t)0 : (size_t)NG * HD) + (size_t)node0 * HD;
    const float* Wout = gene ? Woutg : Woutd;
    const float* bout = gene ? boutg : boutd;
    const float* skip = gene ? skipg : skipd;
    float* x = (gene ? xg : xd) + (size_t)node0 * HD;
    unsigned short* xb = (gene ? xbg : xbd) + (size_t)node0 * HD;
    float* xout = last ? (dout + (gene ? (size_t)ND * HD : 0) + (size_t)node0 * HD) : nullptr;

    __shared__ float gs[16 * HD];
    const int tid = threadIdx.x;
    for (int f4 = tid; f4 < 512; f4 += 128) {
        const int n = f4 >> 5, dp = f4 & 31;
        float4 v = *(const float4*)(ag + n * HD + dp * 4);
        v.x = gelu(v.x);
        v.y = gelu(v.y);
        v.z = gelu(v.z);
        v.w = gelu(v.w);
        *(float4*)(gs + n * HD + dp * 4) = v;
    }
    __syncthreads();
    float acc[16];
#pragma unroll
    for (int n = 0; n < 16; n++) acc[n] = 0.f;
    const int o = tid;
    for (int d = 0; d < HD; d += 4) {
        float4 xv[16];
#pragma unroll
        for (int n = 0; n < 16; n++) xv[n] = *(const float4*)(gs + n * HD + d);
#pragma unroll
        for (int j = 0; j < 4; j++) {
            const float w = Wout[(d + j) * HD + o];
#pragma unroll
            for (int n = 0; n < 16; n++)
                acc[n] = fmaf(((const float*)&xv[n])[j], w, acc[n]);
        }
    }
    const float bb = bout[o];
    const float g = 1.f / (1.f + expf(-skip[0]));
#pragma unroll
    for (int n = 0; n < 16; n++) {
        const int idx = n * HD + o;
        const float xn = g * (acc[n] + bb) + (1.f - g) * x[idx];
        x[idx] = xn;
        xb[idx] = f2bu(xn);
        if (xout) xout[idx] = xn;
    }
}

// ---------------------------------------------------------------------------
static inline size_t alignup(size_t v) { return (v + 15) & ~(size_t)15; }

extern "C" void kernel_launch(void* const* d_in, const int* in_sizes, int n_in,
                              void* d_out, int out_size, void* d_ws, size_t ws_size,
                              hipStream_t stream) {
    (void)in_sizes; (void)n_in; (void)out_size; (void)ws_size;
    const int* src_dg = (const int*)d_in[2];
    const int* dst_dg = (const int*)d_in[3];
    const int* src_gd = (const int*)d_in[4];
    const int* dst_gd = (const int*)d_in[5];
    const int* src_gg = (const int*)d_in[6];
    const int* dst_gg = (const int*)d_in[7];

    // ---- workspace carve-up ----
    float* ws = (float*)d_ws;
    float* xd   = ws; ws += alignup((size_t)ND * HD);   // contiguous with xg for one f2b
    float* xg   = ws; ws += alignup((size_t)NG * HD);
    float* agg  = ws; ws += alignup((size_t)(NG + ND) * HD);
    int* flag = (int*)ws; ws += 16;
    // CSR
    int* cnt_g  = (int*)ws; ws += alignup(NG);
    int* cnt_d  = (int*)ws; ws += alignup(ND);
    int* rp_g   = (int*)ws; ws += alignup(NG + 1);
    int* rp_d   = (int*)ws; ws += alignup(ND + 1);
    int* cur_g  = (int*)ws; ws += alignup(NG);
    int* cur_d  = (int*)ws; ws += alignup(ND);
    int* bsum   = (int*)ws; ws += alignup(NBG + NBD);
    int* edges_g = (int*)ws; ws += alignup(EG);
    int* edges_d = (int*)ws; ws += alignup(E_GD);
    // canonical fp32 inputs
    float* wkqvd = ws; ws += alignup((size_t)NLAYER * HD * 3 * HD);
    float* bkqvd = ws; ws += alignup((size_t)NLAYER * 3 * HD);
    float* wkqvg = ws; ws += alignup((size_t)NLAYER * HD * 3 * HD);
    float* bkqvg = ws; ws += alignup((size_t)NLAYER * 3 * HD);
    float* woutd = ws; ws += alignup((size_t)NLAYER * HD * HD);
    float* boutd = ws; ws += alignup((size_t)NLAYER * HD);
    float* woutg = ws; ws += alignup((size_t)NLAYER * HD * HD);
    float* boutg = ws; ws += alignup((size_t)NLAYER * HD);
    float* skipd = ws; ws += 16;
    float* skipg = ws; ws += 16;
    float* arelc = ws; ws += alignup((size_t)NLAYER * 3 * H * D * D);
    float* mrelc = ws; ws += alignup((size_t)NLAYER * 3 * H * D * D);
    float* prelc = ws; ws += 16;
    // combined bias (fp32)
    float* bp_d = ws; ws += alignup((size_t)NLAYER * OCD);
    float* bp_g = ws; ws += alignup((size_t)NLAYER * OCG);
    // bf16 regions
    unsigned short* Wp_d = (unsigned short*)ws; ws += alignup((size_t)NLAYER * 4 * OCD * 32 / 2);
    unsigned short* Wp_g = (unsigned short*)ws; ws += alignup((size_t)NLAYER * 4 * OCG * 32 / 2);
    unsigned short* xbd = (unsigned short*)ws; ws += alignup((size_t)ND * HD / 2);  // contiguous with xbg
    unsigned short* xbg = (unsigned short*)ws; ws += alignup((size_t)NG * HD / 2);
    unsigned short* tab_d = (unsigned short*)ws; ws += alignup((size_t)ND * OCD / 2);
    unsigned short* tab_g = (unsigned short*)ws; ws += alignup((size_t)NG * OCG / 2);

    // ---- dtype detect + canonicalize ----
    hipMemsetAsync(flag, 0, 4, stream);
    k_detect<<<1, 256, 0, stream>>>((const unsigned short*)d_in[0], flag);

    CvtDesc cd;
    const int seg_in[NSEG] = {0, 1, 8, 9, 10, 11, 12, 13, 14, 15, 16, 17, 18, 19, 20};
    float* const seg_dst[NSEG] = {xd, xg, wkqvd, bkqvd, wkqvg, bkqvg, woutd, boutd,
                                  woutg, boutg, skipd, skipg, arelc, mrelc, prelc};
    const int seg_n[NSEG] = {ND * HD, NG * HD,
                             NLAYER * HD * 3 * HD, NLAYER * 3 * HD,
                             NLAYER * HD * 3 * HD, NLAYER * 3 * HD,
                             NLAYER * HD * HD, NLAYER * HD,
                             NLAYER * HD * HD, NLAYER * HD,
                             NLAYER, NLAYER,
                             NLAYER * 3 * H * D * D, NLAYER * 3 * H * D * D,
                             NLAYER * 3 * H};
    int nblk = 0;
    for (int s = 0; s < NSEG; s++) {
        cd.src[s] = d_in[seg_in[s]];
        cd.dst[s] = seg_dst[s];
        cd.nelem[s] = seg_n[s];
        cd.blk0[s] = nblk;
        nblk += (seg_n[s] + 1023) / 1024;
    }
    k_cvt_all<<<nblk, 256, 0, stream>>>(cd, flag);

    // ---- combined weights (once) ----
    k_combine<0><<<(NLAYER * OCD * 128 + 255) / 256, 256, 0, stream>>>(
        wkqvd, bkqvd, arelc, mrelc, Wp_d, bp_d);
    k_combine<1><<<(NLAYER * OCG * 128 + 255) / 256, 256, 0, stream>>>(
        wkqvg, bkqvg, arelc, mrelc, Wp_g, bp_g);

    // ---- CSR build (once; graph is layer-invariant) ----
    hipMemsetAsync(cnt_g, 0, sizeof(int) * NG, stream);
    hipMemsetAsync(cnt_d, 0, sizeof(int) * ND, stream);
    k_hist<<<(NE + 255) / 256, 256, 0, stream>>>(dst_dg, dst_gg, dst_gd, cnt_g, cnt_d);
    k_scan_p1<<<NBG + NBD, 256, 0, stream>>>(cnt_g, cnt_d, bsum);
    k_scan_p2<<<1, 64, 0, stream>>>(bsum);
    k_scan_p3<<<NBG + NBD, 256, 0, stream>>>(cnt_g, cnt_d, bsum, rp_g, cur_g, rp_d, cur_d);
    k_scatter<<<(NE + 255) / 256, 256, 0, stream>>>(
        src_dg, dst_dg, src_gg, dst_gg, src_gd, dst_gd,
        cur_g, cur_d, edges_g, edges_d);

    // layer-0 bf16 x (xd/xg and xbd/xbg are contiguous -> one dispatch)
    k_f2b<<<((ND + NG) * 32 + 255) / 256, 256, 0, stream>>>(xd, xbd, (ND + NG) * 32);

    for (int l = 0; l < NLAYER; l++) {
        k_gemm2<<<5625, 256, 0, stream>>>(
            xbd, Wp_d + (size_t)l * 4 * OCD * 32, bp_d + l * OCD, tab_d,
            xbg, Wp_g + (size_t)l * 4 * OCG * 32, bp_g + l * OCG, tab_g);
        k_agg<<<(NG + ND) / 4, 256, 0, stream>>>(
            rp_g, edges_g, rp_d, edges_d, tab_d, tab_g, prelc + l * 3 * H, agg);
        k_update2<<<(NG + ND) / 16, 128, 0, stream>>>(
            agg,
            woutg + (size_t)l * HD * HD, boutg + l * HD, skipg + l, xg, xbg,
            woutd + (size_t)l * HD * HD, boutd + l * HD, skipd + l, xd, xbd,
            (l == NLAYER - 1) ? 1 : 0, (float*)d_out);
    }
}

// Round 8
// 426.424 us; speedup vs baseline: 6.3819x; 1.0889x over previous
//
#include <hip/hip_runtime.h>
#include <hip/hip_bf16.h>

#define H 4
#define D 32
#define HD 128
#define ND 10000
#define NG 30000
#define E_DG 150000
#define E_GD 150000
#define E_GG 300000
#define NE (E_DG + E_GD + E_GG)
#define EG (E_DG + E_GG)   // edges into gene nodes
#define NLAYER 2
#define NBG 30             // ceil(NG/1024)
#define NBD 10             // ceil(ND/1024)
#define OCG 640            // gene table cols:   [q|k1|v1|k2|v2]
#define OCD 384            // disease table cols:[q|k0|v0]

typedef __hip_bfloat16 bf16;
typedef __attribute__((ext_vector_type(8))) short short8;
typedef __attribute__((ext_vector_type(8))) unsigned short u16x8;
typedef __attribute__((ext_vector_type(4))) float f32x4;

__device__ __forceinline__ float bu(unsigned short u) {
    return __uint_as_float(((unsigned)u) << 16);
}
__device__ __forceinline__ unsigned short f2bu(float f) {
    union { bf16 h; unsigned short u; } c;
    c.h = __float2bfloat16(f);
    return c.u;
}
__device__ __forceinline__ float gelu(float v) {
    const float c = 0.79788456080286536f * (v + 0.044715f * v * v * v);
    return 0.5f * v * (1.0f + tanhf(c));
}

// ---------------------------------------------------------------------------
// Input dtype detection: flag=1 -> inputs fp32, 0 -> bf16.
__global__ void k_detect(const unsigned short* __restrict__ x, int* __restrict__ flag) {
    int bad = 0;
    for (int i = threadIdx.x; i < 4096; i += 256) {
        const float v = bu(x[i]);
        if (!(fabsf(v) < 1e6f)) bad = 1;
    }
    if (bad) atomicOr(flag, 1);
}

// ---------------------------------------------------------------------------
// Batched conversion of all float inputs -> canonical fp32 ws buffers.
#define NSEG 15
struct CvtDesc {
    const void* src[NSEG];
    float* dst[NSEG];
    int nelem[NSEG];
    int blk0[NSEG];
};

__global__ __launch_bounds__(256) void k_cvt_all(CvtDesc d, const int* __restrict__ flag) {
    const int b = blockIdx.x;
    int s = 0;
    while (s + 1 < NSEG && b >= d.blk0[s + 1]) s++;
    const int i0 = (b - d.blk0[s]) * 1024 + threadIdx.x * 4;
    const int n = d.nelem[s];
    if (i0 >= n) return;
    const bool isf32 = (*flag != 0);
    float* dst = d.dst[s];
    if (i0 + 4 <= n) {
        float4 v;
        if (isf32) {
            v = *(const float4*)((const float*)d.src[s] + i0);
        } else {
            const ushort4 u = *(const ushort4*)((const unsigned short*)d.src[s] + i0);
            v = make_float4(bu(u.x), bu(u.y), bu(u.z), bu(u.w));
        }
        *(float4*)(dst + i0) = v;
    } else {
        for (int j = i0; j < n; j++)
            dst[j] = isf32 ? ((const float*)d.src[s])[j] : bu(((const unsigned short*)d.src[s])[j]);
    }
}

// ---------------------------------------------------------------------------
// CSR build: histogram -> 3-phase parallel scan -> scatter.
__global__ __launch_bounds__(256) void k_hist(
    const int* __restrict__ dst_dg, const int* __restrict__ dst_gg,
    const int* __restrict__ dst_gd,
    int* __restrict__ cnt_g, int* __restrict__ cnt_d) {
    const int i = blockIdx.x * 256 + threadIdx.x;
    if (i < E_DG) atomicAdd(cnt_g + dst_dg[i], 1);
    else if (i < EG) atomicAdd(cnt_g + dst_gg[i - E_DG], 1);
    else if (i < NE) atomicAdd(cnt_d + dst_gd[i - EG], 1);
}

__global__ __launch_bounds__(256) void k_scan_p1(
    const int* __restrict__ cnt_g, const int* __restrict__ cnt_d,
    int* __restrict__ bsum) {
    const int b = blockIdx.x;
    const int* cnt = (b < NBG) ? cnt_g : cnt_d;
    const int n = (b < NBG) ? NG : ND;
    const int i0 = ((b < NBG) ? b : (b - NBG)) * 1024 + threadIdx.x * 4;
    int s = 0;
#pragma unroll
    for (int j = 0; j < 4; j++)
        if (i0 + j < n) s += cnt[i0 + j];
    __shared__ int red[256];
    red[threadIdx.x] = s;
    __syncthreads();
    for (int d = 128; d > 0; d >>= 1) {
        if (threadIdx.x < d) red[threadIdx.x] += red[threadIdx.x + d];
        __syncthreads();
    }
    if (threadIdx.x == 0) bsum[b] = red[0];
}

__global__ void k_scan_p2(int* __restrict__ bsum) {
    if (threadIdx.x == 0) {
        int acc = 0;
        for (int i = 0; i < NBG; i++) { const int v = bsum[i]; bsum[i] = acc; acc += v; }
        acc = 0;
        for (int i = NBG; i < NBG + NBD; i++) { const int v = bsum[i]; bsum[i] = acc; acc += v; }
    }
}

__global__ __launch_bounds__(256) void k_scan_p3(
    const int* __restrict__ cnt_g, const int* __restrict__ cnt_d,
    const int* __restrict__ bsum,
    int* __restrict__ rp_g, int* __restrict__ cur_g,
    int* __restrict__ rp_d, int* __restrict__ cur_d) {
    const int b = blockIdx.x;
    const bool isg = (b < NBG);
    const int* cnt = isg ? cnt_g : cnt_d;
    int* rp = isg ? rp_g : rp_d;
    int* cur = isg ? cur_g : cur_d;
    const int n = isg ? NG : ND;
    const int i0 = (isg ? b : (b - NBG)) * 1024 + threadIdx.x * 4;
    int v[4];
    int t = 0;
#pragma unroll
    for (int j = 0; j < 4; j++) {
        v[j] = (i0 + j < n) ? cnt[i0 + j] : 0;
        t += v[j];
    }
    __shared__ int sdata[256];
    sdata[threadIdx.x] = t;
    __syncthreads();
    for (int d = 1; d < 256; d <<= 1) {
        const int u = (threadIdx.x >= d) ? sdata[threadIdx.x - d] : 0;
        __syncthreads();
        sdata[threadIdx.x] += u;
        __syncthreads();
    }
    int run = bsum[b] + sdata[threadIdx.x] - t;
#pragma unroll
    for (int j = 0; j < 4; j++) {
        if (i0 + j < n) {
            cur[i0 + j] = run;
            run += v[j];
            rp[i0 + j + 1] = run;
        }
    }
    if (threadIdx.x == 0 && (b == 0 || b == NBG)) rp[0] = 0;
}

// edge record: (src << 2) | edge_type  (et: 0=d->g, 1=g->d, 2=g->g)
__global__ __launch_bounds__(256) void k_scatter(
    const int* __restrict__ src_dg, const int* __restrict__ dst_dg,
    const int* __restrict__ src_gg, const int* __restrict__ dst_gg,
    const int* __restrict__ src_gd, const int* __restrict__ dst_gd,
    int* __restrict__ cur_g, int* __restrict__ cur_d,
    int* __restrict__ edges_g, int* __restrict__ edges_d) {
    const int i = blockIdx.x * 256 + threadIdx.x;
    if (i < E_DG) {
        const int pos = atomicAdd(cur_g + dst_dg[i], 1);
        edges_g[pos] = (src_dg[i] << 2) | 0;
    } else if (i < EG) {
        const int j = i - E_DG;
        const int pos = atomicAdd(cur_g + dst_gg[j], 1);
        edges_g[pos] = (src_gg[j] << 2) | 2;
    } else if (i < NE) {
        const int j = i - EG;
        const int pos = atomicAdd(cur_d + dst_gd[j], 1);
        edges_d[pos] = (src_gd[j] << 2) | 1;
    }
}

// ---------------------------------------------------------------------------
// Combined-weight precompute (see r5): fold relation matrices into KQV weights.
template <int GENE>
__global__ __launch_bounds__(256) void k_combine(
    const float* __restrict__ W,      // [L][128][384] canonical
    const float* __restrict__ bvec,   // [L][384]
    const float* __restrict__ arel,   // [L][3][H][32][32]
    const float* __restrict__ mrel,
    unsigned short* __restrict__ Wp,  // [L][4][OC][32] bf16
    float* __restrict__ bp) {         // [L][OC]
    const int OC = GENE ? OCG : OCD;
    const int idx = blockIdx.x * 256 + threadIdx.x;
    if (idx >= NLAYER * OC * 128) return;
    const int l = idx / (OC * 128);
    const int rem = idx - l * OC * 128;
    const int col = rem >> 7;
    const int d = rem & 127;
    const int g = col >> 7;           // 0=q, 1/3=k, 2/4=v
    const int jj = col & 127;
    const int h = jj >> 5, f = jj & 31;
    const float* Wl = W + (size_t)l * 128 * 384;
    const float* bl = bvec + l * 384;
    float val, bv = 0.f;
    if (g == 0) {
        val = Wl[d * 384 + 128 + jj];
        bv = bl[128 + jj];
    } else {
        const int et = GENE ? ((g <= 2) ? 1 : 2) : 0;
        const bool isk = (g & 1);
        const float* mat = (isk ? arel : mrel) + (((size_t)(l * 3 + et) * H + h) << 10) + f;
        const int sb = isk ? 0 : 256;
        val = 0.f;
        for (int dd = 0; dd < 32; dd++)
            val += Wl[d * 384 + sb + h * 32 + dd] * mat[dd * 32];
        if (d == 0)
            for (int dd = 0; dd < 32; dd++)
                bv += bl[sb + h * 32 + dd] * mat[dd * 32];
    }
    Wp[(size_t)l * 4 * OC * 32 + ((size_t)(d >> 5) * OC + col) * 32 + (d & 31)] = f2bu(val);
    if (d == 0) bp[l * OC + col] = bv;
}

// ---------------------------------------------------------------------------
// Pack Wout (fp32 [L][128][128]) into MFMA-B layout [L][4][128][32] bf16.
__global__ __launch_bounds__(256) void k_packw(
    const float* __restrict__ woutd, const float* __restrict__ woutg,
    unsigned short* __restrict__ Wpod, unsigned short* __restrict__ Wpog) {
    const int idx = blockIdx.x * 256 + threadIdx.x;
    if (idx >= 2 * NLAYER * 128 * 128) return;
    const int type = idx >= NLAYER * 128 * 128;
    int rem = idx - type * NLAYER * 128 * 128;
    const int l = rem / (128 * 128);
    rem -= l * 128 * 128;
    const int d = rem >> 7, col = rem & 127;
    const float* w = (type ? woutg : woutd) + (size_t)l * 128 * 128 + d * 128 + col;
    unsigned short* out = (type ? Wpog : Wpod) +
        ((size_t)l * 4 + (d >> 5)) * 128 * 32 + col * 32 + (d & 31);
    *out = f2bu(*w);
}

// ---------------------------------------------------------------------------
// fp32 -> bf16 cast
__global__ __launch_bounds__(256) void k_f2b(
    const float* __restrict__ in, unsigned short* __restrict__ out, int n4) {
    const int i = blockIdx.x * 256 + threadIdx.x;
    if (i < n4) {
        const float4 v = ((const float4*)in)[i];
        ushort4 u;
        u.x = f2bu(v.x); u.y = f2bu(v.y); u.z = f2bu(v.z); u.w = f2bu(v.w);
        ((ushort4*)out)[i] = u;
    }
}

// ---------------------------------------------------------------------------
// Merged MFMA GEMM for both node types (see r5 layout notes).
// waves 0..3749: disease (625 mtiles x 6 ntiles); 3750..: gene (1875 x 10).
__global__ __launch_bounds__(256) void k_gemm2(
    const unsigned short* __restrict__ xbd, const unsigned short* __restrict__ Wpd,
    const float* __restrict__ bpd, unsigned short* __restrict__ outd,
    const unsigned short* __restrict__ xbg, const unsigned short* __restrict__ Wpg,
    const float* __restrict__ bpg, unsigned short* __restrict__ outg) {
    int w = blockIdx.x * 4 + (threadIdx.x >> 6);
    const unsigned short *xb, *Wp;
    const float* bias;
    unsigned short* out;
    int mt, nt, OC;
    if (w < 3750) {
        xb = xbd; Wp = Wpd; bias = bpd; out = outd; OC = OCD;
        mt = w / 6; nt = w - mt * 6;
    } else {
        w -= 3750;
        xb = xbg; Wp = Wpg; bias = bpg; out = outg; OC = OCG;
        mt = w / 10; nt = w - mt * 10;
    }
    const int lane = threadIdx.x & 63;
    const int r = lane & 15, q4 = lane >> 4;
    const int node0 = mt << 4, col0 = nt << 6;
    f32x4 acc0 = {0.f, 0.f, 0.f, 0.f};
    f32x4 acc1 = acc0, acc2 = acc0, acc3 = acc0;
#pragma unroll
    for (int kb = 0; kb < 4; kb++) {
        const short8 a = *(const short8*)(xb + (size_t)(node0 + r) * 128 + kb * 32 + q4 * 8);
        const unsigned short* wb = Wp + ((size_t)kb * OC + col0 + r) * 32 + q4 * 8;
        const short8 b0 = *(const short8*)(wb);
        const short8 b1 = *(const short8*)(wb + 512);
        const short8 b2 = *(const short8*)(wb + 1024);
        const short8 b3 = *(const short8*)(wb + 1536);
        acc0 = __builtin_amdgcn_mfma_f32_16x16x32_bf16(a, b0, acc0, 0, 0, 0);
        acc1 = __builtin_amdgcn_mfma_f32_16x16x32_bf16(a, b1, acc1, 0, 0, 0);
        acc2 = __builtin_amdgcn_mfma_f32_16x16x32_bf16(a, b2, acc2, 0, 0, 0);
        acc3 = __builtin_amdgcn_mfma_f32_16x16x32_bf16(a, b3, acc3, 0, 0, 0);
    }
    const f32x4 accs[4] = {acc0, acc1, acc2, acc3};
#pragma unroll
    for (int t = 0; t < 4; t++) {
        const int col = col0 + t * 16 + r;
        const float bb = bias[col];
#pragma unroll
        for (int reg = 0; reg < 4; reg++)
            out[(size_t)(node0 + q4 * 4 + reg) * OC + col] = f2bu(accs[t][reg] + bb);
    }
}

// ---------------------------------------------------------------------------
// Unified gather aggregation, 2 edges per slot per iteration (8 edges/wave-iter).
// One wave per dst node (gene waves 0..NG-1, disease NG..NG+ND-1). 4 slots x 16
// lanes; each slot runs an independent online-softmax chain over every 4th edge,
// two at a time; merged at the end. Output: gelu(agg) bf16, row-major
// [ND+NG][128] with DISEASE rows first (matches x / d_out ordering).
__global__ __launch_bounds__(256) void k_agg(
    const int* __restrict__ rp_g, const int* __restrict__ edges_g,
    const int* __restrict__ rp_d, const int* __restrict__ edges_d,
    const unsigned short* __restrict__ tab_d, const unsigned short* __restrict__ tab_g,
    const float* __restrict__ prel,   // [3][H] layer slice
    unsigned short* __restrict__ gagg) {
    const int wid = blockIdx.x * 4 + (threadIdx.x >> 6);
    const int lane = threadIdx.x & 63;
    const int slot = lane >> 4, sub = lane & 15;
    const int h = sub >> 2;

    int node, row;
    const int *rp, *edges;
    const unsigned short* tq;
    int sq;
    if (wid < NG) {
        node = wid; rp = rp_g; edges = edges_g; tq = tab_g; sq = OCG;
        row = ND + node;
    } else {
        node = wid - NG; rp = rp_d; edges = edges_d; tq = tab_d; sq = OCD;
        row = node;
    }

    const u16x8 q8 = *(const u16x8*)(tq + (size_t)node * sq + sub * 8);
    float qf[8];
#pragma unroll
    for (int i = 0; i < 8; i++) qf[i] = bu(q8[i]);

    const float pscale = 0.17677669529663689f * 1.4426950408889634f;  // scale*log2e
    const float pet0 = prel[0 * H + h] * pscale;
    const float pet1 = prel[1 * H + h] * pscale;
    const float pet2 = prel[2 * H + h] * pscale;

    float m = -1e30f, s = 0.f;
    float acc[8];
#pragma unroll
    for (int i = 0; i < 8; i++) acc[i] = 0.f;

    const int r0 = rp[node], r1 = rp[node + 1];
    int e = r0 + slot;

    auto kvload = [&](int rec, u16x8& k, u16x8& v) {
        const int src = rec >> 2, et = rec & 3;
        const unsigned short* base = (et == 0) ? (tab_d + 128) : (et == 1) ? (tab_g + 128) : (tab_g + 384);
        const int stride = (et == 0) ? OCD : OCG;
        const unsigned short* p = base + (size_t)src * stride + sub * 8;
        k = *(const u16x8*)p;
        v = *(const u16x8*)(p + 128);
    };

    int recA0 = (e < r1) ? edges[e] : 0;
    int recB0 = (e + 4 < r1) ? edges[e + 4] : 0;
    u16x8 kA0, vA0, kB0, vB0;
    kvload(recA0, kA0, vA0);
    kvload(recB0, kB0, vB0);
    int recA1 = (e + 8 < r1) ? edges[e + 8] : 0;
    int recB1 = (e + 12 < r1) ? edges[e + 12] : 0;

    while (e < r1) {
        const int recA2 = (e + 16 < r1) ? edges[e + 16] : 0;
        const int recB2 = (e + 20 < r1) ? edges[e + 20] : 0;
        u16x8 kA1, vA1, kB1, vB1;
        kvload(recA1, kA1, vA1);
        kvload(recB1, kB1, vB1);

        float pA = 0.f, pB = 0.f;
#pragma unroll
        for (int i = 0; i < 8; i++) {
            pA = fmaf(qf[i], bu(kA0[i]), pA);
            pB = fmaf(qf[i], bu(kB0[i]), pB);
        }
        pA += __shfl_xor(pA, 1);
        pB += __shfl_xor(pB, 1);
        pA += __shfl_xor(pA, 2);
        pB += __shfl_xor(pB, 2);
        const int etA = recA0 & 3, etB = recB0 & 3;
        const float aA = pA * ((etA == 0) ? pet0 : (etA == 1) ? pet1 : pet2);
        float aB = pB * ((etB == 0) ? pet0 : (etB == 1) ? pet1 : pet2);
        aB = (e + 4 < r1) ? aB : -1e30f;   // mask tail edge
        const float mn = fmaxf(m, fmaxf(aA, aB));
        const float c = exp2f(m - mn);
        const float eaA = exp2f(aA - mn);
        const float eaB = exp2f(aB - mn);
        s = s * c + eaA + eaB;
#pragma unroll
        for (int i = 0; i < 8; i++)
            acc[i] = fmaf(eaB, bu(vB0[i]), fmaf(eaA, bu(vA0[i]), acc[i] * c));
        m = mn;
        recA0 = recA1; recB0 = recB1; recA1 = recA2; recB1 = recB2;
        kA0 = kA1; vA0 = vA1; kB0 = kB1; vB0 = vB1;
        e += 8;
    }

    // merge the 4 slot-chains (associative online-softmax merge)
#pragma unroll
    for (int mask = 16; mask <= 32; mask <<= 1) {
        const float m2 = __shfl_xor(m, mask);
        const float s2 = __shfl_xor(s, mask);
        const float M = fmaxf(m, m2);
        const float c1 = exp2f(m - M);
        const float c2 = exp2f(m2 - M);
        s = s * c1 + s2 * c2;
#pragma unroll
        for (int i = 0; i < 8; i++) {
            const float o = __shfl_xor(acc[i], mask);
            acc[i] = acc[i] * c1 + o * c2;
        }
        m = M;
    }

    const float inv = (s > 0.f) ? (1.f / s) : 0.f;
    if (slot == 0) {
        u16x8 o;
#pragma unroll
        for (int i = 0; i < 8; i++) o[i] = f2bu(gelu(acc[i] * inv));
        *(u16x8*)(gagg + (size_t)row * HD + sub * 8) = o;
    }
}

// ---------------------------------------------------------------------------
// MFMA update: o = gagg(bf16,gelu'd) @ Wout + bout; x = g*o + (1-g)*x.
// Writes fp32 x, bf16 xb, and (last) fp32 d_out. Rows: disease 0..ND-1, gene on.
__global__ __launch_bounds__(256) void k_upd(
    const unsigned short* __restrict__ gagg,
    const unsigned short* __restrict__ Wpod, const float* __restrict__ boutd,
    const float* __restrict__ skipd,
    const unsigned short* __restrict__ Wpog, const float* __restrict__ boutg,
    const float* __restrict__ skipg,
    float* __restrict__ xall, unsigned short* __restrict__ xball,
    int last, float* __restrict__ dout) {
    const int w = blockIdx.x * 4 + (threadIdx.x >> 6);
    const int mt = w >> 1, nt = w & 1;
    const int node0 = mt << 4;
    const bool gene = (node0 >= ND);
    const unsigned short* Wp = gene ? Wpog : Wpod;
    const float* bias = gene ? boutg : boutd;
    const float g = 1.f / (1.f + expf(-(gene ? skipg[0] : skipd[0])));
    const int lane = threadIdx.x & 63;
    const int r = lane & 15, q4 = lane >> 4;
    const int col0 = nt << 6;
    f32x4 acc0 = {0.f, 0.f, 0.f, 0.f};
    f32x4 acc1 = acc0, acc2 = acc0, acc3 = acc0;
#pragma unroll
    for (int kb = 0; kb < 4; kb++) {
        const short8 a = *(const short8*)(gagg + (size_t)(node0 + r) * 128 + kb * 32 + q4 * 8);
        const unsigned short* wb = Wp + ((size_t)kb * 128 + col0 + r) * 32 + q4 * 8;
        const short8 b0 = *(const short8*)(wb);
        const short8 b1 = *(const short8*)(wb + 512);
        const short8 b2 = *(const short8*)(wb + 1024);
        const short8 b3 = *(const short8*)(wb + 1536);
        acc0 = __builtin_amdgcn_mfma_f32_16x16x32_bf16(a, b0, acc0, 0, 0, 0);
        acc1 = __builtin_amdgcn_mfma_f32_16x16x32_bf16(a, b1, acc1, 0, 0, 0);
        acc2 = __builtin_amdgcn_mfma_f32_16x16x32_bf16(a, b2, acc2, 0, 0, 0);
        acc3 = __builtin_amdgcn_mfma_f32_16x16x32_bf16(a, b3, acc3, 0, 0, 0);
    }
    const f32x4 accs[4] = {acc0, acc1, acc2, acc3};
#pragma unroll
    for (int t = 0; t < 4; t++) {
        const int col = col0 + t * 16 + r;
        const float bb = bias[col];
#pragma unroll
        for (int reg = 0; reg < 4; reg++) {
            const size_t idx = (size_t)(node0 + q4 * 4 + reg) * 128 + col;
            const float xn = g * (accs[t][reg] + bb) + (1.f - g) * xall[idx];
            xall[idx] = xn;
            xball[idx] = f2bu(xn);
            if (last) dout[idx] = xn;
        }
    }
}

// ---------------------------------------------------------------------------
static inline size_t alignup(size_t v) { return (v + 15) & ~(size_t)15; }

extern "C" void kernel_launch(void* const* d_in, const int* in_sizes, int n_in,
                              void* d_out, int out_size, void* d_ws, size_t ws_size,
                              hipStream_t stream) {
    (void)in_sizes; (void)n_in; (void)out_size; (void)ws_size;
    const int* src_dg = (const int*)d_in[2];
    const int* dst_dg = (const int*)d_in[3];
    const int* src_gd = (const int*)d_in[4];
    const int* dst_gd = (const int*)d_in[5];
    const int* src_gg = (const int*)d_in[6];
    const int* dst_gg = (const int*)d_in[7];

    // ---- workspace carve-up ----
    float* ws = (float*)d_ws;
    float* xd   = ws; ws += alignup((size_t)ND * HD);   // xall: disease rows then gene
    float* xg   = ws; ws += alignup((size_t)NG * HD);
    int* flag = (int*)ws; ws += 16;
    // CSR
    int* cnt_g  = (int*)ws; ws += alignup(NG);
    int* cnt_d  = (int*)ws; ws += alignup(ND);
    int* rp_g   = (int*)ws; ws += alignup(NG + 1);
    int* rp_d   = (int*)ws; ws += alignup(ND + 1);
    int* cur_g  = (int*)ws; ws += alignup(NG);
    int* cur_d  = (int*)ws; ws += alignup(ND);
    int* bsum   = (int*)ws; ws += alignup(NBG + NBD);
    int* edges_g = (int*)ws; ws += alignup(EG);
    int* edges_d = (int*)ws; ws += alignup(E_GD);
    // canonical fp32 inputs
    float* wkqvd = ws; ws += alignup((size_t)NLAYER * HD * 3 * HD);
    float* bkqvd = ws; ws += alignup((size_t)NLAYER * 3 * HD);
    float* wkqvg = ws; ws += alignup((size_t)NLAYER * HD * 3 * HD);
    float* bkqvg = ws; ws += alignup((size_t)NLAYER * 3 * HD);
    float* woutd = ws; ws += alignup((size_t)NLAYER * HD * HD);
    float* boutd = ws; ws += alignup((size_t)NLAYER * HD);
    float* woutg = ws; ws += alignup((size_t)NLAYER * HD * HD);
    float* boutg = ws; ws += alignup((size_t)NLAYER * HD);
    float* skipd = ws; ws += 16;
    float* skipg = ws; ws += 16;
    float* arelc = ws; ws += alignup((size_t)NLAYER * 3 * H * D * D);
    float* mrelc = ws; ws += alignup((size_t)NLAYER * 3 * H * D * D);
    float* prelc = ws; ws += 16;
    // combined bias (fp32)
    float* bp_d = ws; ws += alignup((size_t)NLAYER * OCD);
    float* bp_g = ws; ws += alignup((size_t)NLAYER * OCG);
    // bf16 regions
    unsigned short* Wp_d = (unsigned short*)ws; ws += alignup((size_t)NLAYER * 4 * OCD * 32 / 2);
    unsigned short* Wp_g = (unsigned short*)ws; ws += alignup((size_t)NLAYER * 4 * OCG * 32 / 2);
    unsigned short* Wpod = (unsigned short*)ws; ws += alignup((size_t)NLAYER * 4 * 128 * 32 / 2);
    unsigned short* Wpog = (unsigned short*)ws; ws += alignup((size_t)NLAYER * 4 * 128 * 32 / 2);
    unsigned short* xbd = (unsigned short*)ws; ws += alignup((size_t)ND * HD / 2);  // xball
    unsigned short* xbg = (unsigned short*)ws; ws += alignup((size_t)NG * HD / 2);
    unsigned short* gagg = (unsigned short*)ws; ws += alignup((size_t)(ND + NG) * HD / 2);
    unsigned short* tab_d = (unsigned short*)ws; ws += alignup((size_t)ND * OCD / 2);
    unsigned short* tab_g = (unsigned short*)ws; ws += alignup((size_t)NG * OCG / 2);

    // ---- dtype detect + canonicalize ----
    hipMemsetAsync(flag, 0, 4, stream);
    k_detect<<<1, 256, 0, stream>>>((const unsigned short*)d_in[0], flag);

    CvtDesc cd;
    const int seg_in[NSEG] = {0, 1, 8, 9, 10, 11, 12, 13, 14, 15, 16, 17, 18, 19, 20};
    float* const seg_dst[NSEG] = {xd, xg, wkqvd, bkqvd, wkqvg, bkqvg, woutd, boutd,
                                  woutg, boutg, skipd, skipg, arelc, mrelc, prelc};
    const int seg_n[NSEG] = {ND * HD, NG * HD,
                             NLAYER * HD * 3 * HD, NLAYER * 3 * HD,
                             NLAYER * HD * 3 * HD, NLAYER * 3 * HD,
                             NLAYER * HD * HD, NLAYER * HD,
                             NLAYER * HD * HD, NLAYER * HD,
                             NLAYER, NLAYER,
                             NLAYER * 3 * H * D * D, NLAYER * 3 * H * D * D,
                             NLAYER * 3 * H};
    int nblk = 0;
    for (int s = 0; s < NSEG; s++) {
        cd.src[s] = d_in[seg_in[s]];
        cd.dst[s] = seg_dst[s];
        cd.nelem[s] = seg_n[s];
        cd.blk0[s] = nblk;
        nblk += (seg_n[s] + 1023) / 1024;
    }
    k_cvt_all<<<nblk, 256, 0, stream>>>(cd, flag);

    // ---- combined/packed weights (once) ----
    k_combine<0><<<(NLAYER * OCD * 128 + 255) / 256, 256, 0, stream>>>(
        wkqvd, bkqvd, arelc, mrelc, Wp_d, bp_d);
    k_combine<1><<<(NLAYER * OCG * 128 + 255) / 256, 256, 0, stream>>>(
        wkqvg, bkqvg, arelc, mrelc, Wp_g, bp_g);
    k_packw<<<(2 * NLAYER * 128 * 128 + 255) / 256, 256, 0, stream>>>(
        woutd, woutg, Wpod, Wpog);

    // ---- CSR build (once; graph is layer-invariant) ----
    hipMemsetAsync(cnt_g, 0, sizeof(int) * (NG + ND), stream);   // cnt_g+cnt_d contiguous
    k_hist<<<(NE + 255) / 256, 256, 0, stream>>>(dst_dg, dst_gg, dst_gd, cnt_g, cnt_d);
    k_scan_p1<<<NBG + NBD, 256, 0, stream>>>(cnt_g, cnt_d, bsum);
    k_scan_p2<<<1, 64, 0, stream>>>(bsum);
    k_scan_p3<<<NBG + NBD, 256, 0, stream>>>(cnt_g, cnt_d, bsum, rp_g, cur_g, rp_d, cur_d);
    k_scatter<<<(NE + 255) / 256, 256, 0, stream>>>(
        src_dg, dst_dg, src_gg, dst_gg, src_gd, dst_gd,
        cur_g, cur_d, edges_g, edges_d);

    // layer-0 bf16 x (xd/xg and xbd/xbg contiguous -> one dispatch)
    k_f2b<<<((ND + NG) * 32 + 255) / 256, 256, 0, stream>>>(xd, xbd, (ND + NG) * 32);

    for (int l = 0; l < NLAYER; l++) {
        k_gemm2<<<5625, 256, 0, stream>>>(
            xbd, Wp_d + (size_t)l * 4 * OCD * 32, bp_d + l * OCD, tab_d,
            xbg, Wp_g + (size_t)l * 4 * OCG * 32, bp_g + l * OCG, tab_g);
        k_agg<<<(NG + ND) / 4, 256, 0, stream>>>(
            rp_g, edges_g, rp_d, edges_d, tab_d, tab_g, prelc + l * 3 * H, gagg);
        k_upd<<<((ND + NG) / 16 * 2 + 3) / 4, 256, 0, stream>>>(
            gagg,
            Wpod + (size_t)l * 4 * 128 * 32, boutd + l * HD, skipd + l,
            Wpog + (size_t)l * 4 * 128 * 32, boutg + l * HD, skipg + l,
            xd, xbd, (l == NLAYER - 1) ? 1 : 0, (float*)d_out);
    }
}

// Round 10
// 395.339 us; speedup vs baseline: 6.8837x; 1.0786x over previous
//
#include <hip/hip_runtime.h>
#include <hip/hip_bf16.h>

#define H 4
#define D 32
#define HD 128
#define ND 10000
#define NG 30000
#define E_DG 150000
#define E_GD 150000
#define E_GG 300000
#define NE (E_DG + E_GD + E_GG)
#define EG (E_DG + E_GG)   // edges into gene nodes
#define NLAYER 2
#define NBG 30             // ceil(NG/1024)
#define NBD 10             // ceil(ND/1024)
#define OCG 640            // gene table cols:   [q|k1|v1|k2|v2]
#define OCD 384            // disease table cols:[q|k0|v0]
#define GOFF ((size_t)ND * OCD)   // gene rows offset in unified table
#define GOFF_X ((size_t)ND * HD)  // gene rows offset in x tables

typedef _Float16 f16;
typedef __attribute__((ext_vector_type(2))) _Float16 f16x2;
typedef __attribute__((ext_vector_type(4))) _Float16 f16x4;
typedef __attribute__((ext_vector_type(8))) _Float16 f16x8;
typedef __attribute__((ext_vector_type(4))) float f32x4;

__device__ __forceinline__ float bu(unsigned short u) {
    return __uint_as_float(((unsigned)u) << 16);
}
__device__ __forceinline__ float gelu(float v) {
    const float c = 0.79788456080286536f * (v + 0.044715f * v * v * v);
    return 0.5f * v * (1.0f + tanhf(c));
}

// ---------------------------------------------------------------------------
// Input dtype detection: flag=1 -> inputs fp32, 0 -> bf16. Self-initializing.
__global__ void k_detect(const unsigned short* __restrict__ x, int* __restrict__ flag) {
    __shared__ int sbad;
    if (threadIdx.x == 0) sbad = 0;
    __syncthreads();
    int bad = 0;
    for (int i = threadIdx.x; i < 4096; i += 256) {
        const float v = bu(x[i]);
        if (!(fabsf(v) < 1e6f)) bad = 1;
    }
    if (bad) sbad = 1;     // benign race
    __syncthreads();
    if (threadIdx.x == 0) flag[0] = sbad;
}

// ---------------------------------------------------------------------------
// Batched conversion of all float inputs -> canonical fp32 (+optional f16).
#define NSEG 15
struct CvtDesc {
    const void* src[NSEG];
    float* dst[NSEG];
    f16* dst16[NSEG];     // non-null: also write f16 copy
    int nelem[NSEG];
    int blk0[NSEG];
};

__global__ __launch_bounds__(256) void k_cvt_all(CvtDesc d, const int* __restrict__ flag) {
    const int b = blockIdx.x;
    int s = 0;
    while (s + 1 < NSEG && b >= d.blk0[s + 1]) s++;
    const int i0 = (b - d.blk0[s]) * 1024 + threadIdx.x * 4;
    const int n = d.nelem[s];
    if (i0 >= n) return;
    const bool isf32 = (*flag != 0);
    float* dst = d.dst[s];
    f16* d16 = d.dst16[s];
    if (i0 + 4 <= n) {
        float4 v;
        if (isf32) {
            v = *(const float4*)((const float*)d.src[s] + i0);
        } else {
            const ushort4 u = *(const ushort4*)((const unsigned short*)d.src[s] + i0);
            v = make_float4(bu(u.x), bu(u.y), bu(u.z), bu(u.w));
        }
        *(float4*)(dst + i0) = v;
        if (d16) {
            f16x4 h = {(f16)v.x, (f16)v.y, (f16)v.z, (f16)v.w};
            *(f16x4*)(d16 + i0) = h;
        }
    } else {
        for (int j = i0; j < n; j++) {
            const float v = isf32 ? ((const float*)d.src[s])[j]
                                  : bu(((const unsigned short*)d.src[s])[j]);
            dst[j] = v;
            if (d16) d16[j] = (f16)v;
        }
    }
}

// ---------------------------------------------------------------------------
// CSR build: histogram -> 3-phase parallel scan -> scatter.
__global__ __launch_bounds__(256) void k_hist(
    const int* __restrict__ dst_dg, const int* __restrict__ dst_gg,
    const int* __restrict__ dst_gd,
    int* __restrict__ cnt_g, int* __restrict__ cnt_d) {
    const int i = blockIdx.x * 256 + threadIdx.x;
    if (i < E_DG) atomicAdd(cnt_g + dst_dg[i], 1);
    else if (i < EG) atomicAdd(cnt_g + dst_gg[i - E_DG], 1);
    else if (i < NE) atomicAdd(cnt_d + dst_gd[i - EG], 1);
}

__global__ __launch_bounds__(256) void k_scan_p1(
    const int* __restrict__ cnt_g, const int* __restrict__ cnt_d,
    int* __restrict__ bsum) {
    const int b = blockIdx.x;
    const int* cnt = (b < NBG) ? cnt_g : cnt_d;
    const int n = (b < NBG) ? NG : ND;
    const int i0 = ((b < NBG) ? b : (b - NBG)) * 1024 + threadIdx.x * 4;
    int s = 0;
#pragma unroll
    for (int j = 0; j < 4; j++)
        if (i0 + j < n) s += cnt[i0 + j];
    __shared__ int red[256];
    red[threadIdx.x] = s;
    __syncthreads();
    for (int d = 128; d > 0; d >>= 1) {
        if (threadIdx.x < d) red[threadIdx.x] += red[threadIdx.x + d];
        __syncthreads();
    }
    if (threadIdx.x == 0) bsum[b] = red[0];
}

__global__ void k_scan_p2(int* __restrict__ bsum) {
    if (threadIdx.x == 0) {
        int acc = 0;
        for (int i = 0; i < NBG; i++) { const int v = bsum[i]; bsum[i] = acc; acc += v; }
        acc = 0;
        for (int i = NBG; i < NBG + NBD; i++) { const int v = bsum[i]; bsum[i] = acc; acc += v; }
    }
}

__global__ __launch_bounds__(256) void k_scan_p3(
    const int* __restrict__ cnt_g, const int* __restrict__ cnt_d,
    const int* __restrict__ bsum,
    int* __restrict__ rp_g, int* __restrict__ cur_g,
    int* __restrict__ rp_d, int* __restrict__ cur_d) {
    const int b = blockIdx.x;
    const bool isg = (b < NBG);
    const int* cnt = isg ? cnt_g : cnt_d;
    int* rp = isg ? rp_g : rp_d;
    int* cur = isg ? cur_g : cur_d;
    const int n = isg ? NG : ND;
    const int i0 = (isg ? b : (b - NBG)) * 1024 + threadIdx.x * 4;
    int v[4];
    int t = 0;
#pragma unroll
    for (int j = 0; j < 4; j++) {
        v[j] = (i0 + j < n) ? cnt[i0 + j] : 0;
        t += v[j];
    }
    __shared__ int sdata[256];
    sdata[threadIdx.x] = t;
    __syncthreads();
    for (int d = 1; d < 256; d <<= 1) {
        const int u = (threadIdx.x >= d) ? sdata[threadIdx.x - d] : 0;
        __syncthreads();
        sdata[threadIdx.x] += u;
        __syncthreads();
    }
    int run = bsum[b] + sdata[threadIdx.x] - t;
#pragma unroll
    for (int j = 0; j < 4; j++) {
        if (i0 + j < n) {
            cur[i0 + j] = run;
            run += v[j];
            rp[i0 + j + 1] = run;
        }
    }
    if (threadIdx.x == 0 && (b == 0 || b == NBG)) rp[0] = 0;
}

// edge record = element offset of the src's k-row in the UNIFIED table.
// v is always at +128 elements. (prel/scale folded into k weights.)
__global__ __launch_bounds__(256) void k_scatter(
    const int* __restrict__ src_dg, const int* __restrict__ dst_dg,
    const int* __restrict__ src_gg, const int* __restrict__ dst_gg,
    const int* __restrict__ src_gd, const int* __restrict__ dst_gd,
    int* __restrict__ cur_g, int* __restrict__ cur_d,
    int* __restrict__ edges_g, int* __restrict__ edges_d) {
    const int i = blockIdx.x * 256 + threadIdx.x;
    if (i < E_DG) {
        const int pos = atomicAdd(cur_g + dst_dg[i], 1);
        edges_g[pos] = src_dg[i] * OCD + 128;                     // et0: d->g
    } else if (i < EG) {
        const int j = i - E_DG;
        const int pos = atomicAdd(cur_g + dst_gg[j], 1);
        edges_g[pos] = (int)GOFF + src_gg[j] * OCG + 384;         // et2: g->g
    } else if (i < NE) {
        const int j = i - EG;
        const int pos = atomicAdd(cur_d + dst_gd[j], 1);
        edges_d[pos] = (int)GOFF + src_gd[j] * OCG + 128;         // et1: g->d
    }
}

// ---------------------------------------------------------------------------
// Fused prep: combined KQV weights (relation matrices + prel*scale*log2e
// folded in, f16 MFMA-B packing) + Wout packing.
__device__ __forceinline__ void combine_one(
    int idx, int GENE,
    const float* __restrict__ W, const float* __restrict__ bvec,
    const float* __restrict__ arel, const float* __restrict__ mrel,
    const float* __restrict__ prel,
    f16* __restrict__ Wp, float* __restrict__ bp) {
    const int OC = GENE ? OCG : OCD;
    const int l = idx / (OC * 128);
    const int rem = idx - l * OC * 128;
    const int col = rem >> 7;
    const int d = rem & 127;
    const int g = col >> 7;           // 0=q, 1/3=k, 2/4=v
    const int jj = col & 127;
    const int h = jj >> 5, f = jj & 31;
    const float* Wl = W + (size_t)l * 128 * 384;
    const float* bl = bvec + l * 384;
    float val, bv = 0.f;
    if (g == 0) {
        val = Wl[d * 384 + 128 + jj];
        bv = bl[128 + jj];
    } else {
        const int et = GENE ? ((g <= 2) ? 1 : 2) : 0;
        const bool isk = (g & 1);
        const float* mat = (isk ? arel : mrel) + (((size_t)(l * 3 + et) * H + h) << 10) + f;
        const int sb = isk ? 0 : 256;
        val = 0.f;
        for (int dd = 0; dd < 32; dd++)
            val += Wl[d * 384 + sb + h * 32 + dd] * mat[dd * 32];
        if (d == 0)
            for (int dd = 0; dd < 32; dd++)
                bv += bl[sb + h * 32 + dd] * mat[dd * 32];
        if (isk) {
            const float sc = prel[(l * 3 + et) * H + h] *
                             (0.17677669529663689f * 1.4426950408889634f);
            val *= sc;
            bv *= sc;
        }
    }
    Wp[(size_t)l * 4 * OC * 32 + ((size_t)(d >> 5) * OC + col) * 32 + (d & 31)] = (f16)val;
    if (d == 0) bp[l * OC + col] = bv;
}

__global__ __launch_bounds__(256) void k_prep(
    const float* __restrict__ wkqvd, const float* __restrict__ bkqvd,
    const float* __restrict__ wkqvg, const float* __restrict__ bkqvg,
    const float* __restrict__ arel, const float* __restrict__ mrel,
    const float* __restrict__ prel,
    f16* __restrict__ Wp_d, float* __restrict__ bp_d,
    f16* __restrict__ Wp_g, float* __restrict__ bp_g,
    const float* __restrict__ woutd, const float* __restrict__ woutg,
    f16* __restrict__ Wpod, f16* __restrict__ Wpog) {
    int idx = blockIdx.x * 256 + threadIdx.x;
    const int nd = NLAYER * OCD * 128;
    const int ng = NLAYER * OCG * 128;
    const int np = 2 * NLAYER * 128 * 128;
    if (idx < nd) {
        combine_one(idx, 0, wkqvd, bkqvd, arel, mrel, prel, Wp_d, bp_d);
    } else if ((idx -= nd) < ng) {
        combine_one(idx, 1, wkqvg, bkqvg, arel, mrel, prel, Wp_g, bp_g);
    } else if ((idx -= ng) < np) {
        const int type = idx >= NLAYER * 128 * 128;
        int rem = idx - type * NLAYER * 128 * 128;
        const int l = rem / (128 * 128);
        rem -= l * 128 * 128;
        const int d = rem >> 7, col = rem & 127;
        const float* w = (type ? woutg : woutd) + (size_t)l * 128 * 128 + d * 128 + col;
        f16* out = (type ? Wpog : Wpod) +
            ((size_t)l * 4 + (d >> 5)) * 128 * 32 + col * 32 + (d & 31);
        *out = (f16)*w;
    }
}

// ---------------------------------------------------------------------------
// Merged f16 MFMA GEMM for both node types. Block's 4 waves share one B-tile
// (same nt, consecutive mt) for L1 reuse of the 16KB B operand.
__global__ __launch_bounds__(256) void k_gemm2(
    const f16* __restrict__ xball, const f16* __restrict__ Wpd,
    const float* __restrict__ bpd, const f16* __restrict__ Wpg,
    const float* __restrict__ bpg, f16* __restrict__ tab) {
    int w = blockIdx.x * 4 + (threadIdx.x >> 6);
    const f16 *xb, *Wp;
    const float* bias;
    f16* out;
    int mt, nt, OC;
    if (w < 3750) {                 // disease: 625 mtiles x 6 ntiles
        xb = xball; Wp = Wpd; bias = bpd; out = tab; OC = OCD;
        nt = w / 625; mt = w - nt * 625;
    } else {                        // gene: 1875 mtiles x 10 ntiles
        w -= 3750;
        xb = xball + GOFF_X; Wp = Wpg; bias = bpg; out = tab + GOFF; OC = OCG;
        nt = w / 1875; mt = w - nt * 1875;
    }
    const int lane = threadIdx.x & 63;
    const int r = lane & 15, q4 = lane >> 4;
    const int node0 = mt << 4, col0 = nt << 6;
    f32x4 acc0 = {0.f, 0.f, 0.f, 0.f};
    f32x4 acc1 = acc0, acc2 = acc0, acc3 = acc0;
#pragma unroll
    for (int kb = 0; kb < 4; kb++) {
        const f16x8 a = *(const f16x8*)(xb + (size_t)(node0 + r) * 128 + kb * 32 + q4 * 8);
        const f16* wb = Wp + ((size_t)kb * OC + col0 + r) * 32 + q4 * 8;
        const f16x8 b0 = *(const f16x8*)(wb);
        const f16x8 b1 = *(const f16x8*)(wb + 512);
        const f16x8 b2 = *(const f16x8*)(wb + 1024);
        const f16x8 b3 = *(const f16x8*)(wb + 1536);
        acc0 = __builtin_amdgcn_mfma_f32_16x16x32_f16(a, b0, acc0, 0, 0, 0);
        acc1 = __builtin_amdgcn_mfma_f32_16x16x32_f16(a, b1, acc1, 0, 0, 0);
        acc2 = __builtin_amdgcn_mfma_f32_16x16x32_f16(a, b2, acc2, 0, 0, 0);
        acc3 = __builtin_amdgcn_mfma_f32_16x16x32_f16(a, b3, acc3, 0, 0, 0);
    }
    const f32x4 accs[4] = {acc0, acc1, acc2, acc3};
#pragma unroll
    for (int t = 0; t < 4; t++) {
        const int col = col0 + t * 16 + r;
        const float bb = bias[col];
#pragma unroll
        for (int reg = 0; reg < 4; reg++)
            out[(size_t)(node0 + q4 * 4 + reg) * OC + col] = (f16)(accs[t][reg] + bb);
    }
}

// ---------------------------------------------------------------------------
// Unified gather aggregation, f16 tables + v_dot2 + direct-offset edge recs.
// One wave per dst node; 4 slots x 16 lanes; 2 independent edges per slot per
// iteration (8/wave-iter); associative merge at the end. Emits gelu(agg) f16
// in MFMA-A layout, DISEASE rows first.
__global__ __launch_bounds__(256) void k_agg(
    const int* __restrict__ rp_g, const int* __restrict__ edges_g,
    const int* __restrict__ rp_d, const int* __restrict__ edges_d,
    const f16* __restrict__ tab, f16* __restrict__ gagg) {
    const int wid = blockIdx.x * 4 + (threadIdx.x >> 6);
    const int lane = threadIdx.x & 63;
    const int slot = lane >> 4, sub = lane & 15;

    int node, row;
    const int *rp, *edges;
    size_t qoff;
    if (wid < NG) {
        node = wid; rp = rp_g; edges = edges_g;
        qoff = GOFF + (size_t)node * OCG;
        row = ND + node;
    } else {
        node = wid - NG; rp = rp_d; edges = edges_d;
        qoff = (size_t)node * OCD;
        row = node;
    }

    union U { f16x8 v; f16x2 p[4]; };
    U q;
    q.v = *(const f16x8*)(tab + qoff + sub * 8);

    float m = -1e30f, s = 0.f;
    float acc[8];
#pragma unroll
    for (int i = 0; i < 8; i++) acc[i] = 0.f;

    const int r0 = rp[node], r1 = rp[node + 1];
    int e = r0 + slot;

    auto kvload = [&](int rec, U& k, U& v) {
        const f16* p = tab + (size_t)rec + sub * 8;
        k.v = *(const f16x8*)p;
        v.v = *(const f16x8*)(p + 128);
    };

    int recA0 = (e < r1) ? edges[e] : 0;
    int recB0 = (e + 4 < r1) ? edges[e + 4] : 0;
    U kA0, vA0, kB0, vB0;
    kvload(recA0, kA0, vA0);
    kvload(recB0, kB0, vB0);
    int recA1 = (e + 8 < r1) ? edges[e + 8] : 0;
    int recB1 = (e + 12 < r1) ? edges[e + 12] : 0;

    while (e < r1) {
        const int recA2 = (e + 16 < r1) ? edges[e + 16] : 0;
        const int recB2 = (e + 20 < r1) ? edges[e + 20] : 0;
        U kA1, vA1, kB1, vB1;
        kvload(recA1, kA1, vA1);
        kvload(recB1, kB1, vB1);

        // q.k dot via packed f16 dot2 (prel*scale*log2e already in k)
        float pA = __builtin_amdgcn_fdot2(q.p[0], kA0.p[0], 0.f, false);
        float pB = __builtin_amdgcn_fdot2(q.p[0], kB0.p[0], 0.f, false);
        pA = __builtin_amdgcn_fdot2(q.p[1], kA0.p[1], pA, false);
        pB = __builtin_amdgcn_fdot2(q.p[1], kB0.p[1], pB, false);
        pA = __builtin_amdgcn_fdot2(q.p[2], kA0.p[2], pA, false);
        pB = __builtin_amdgcn_fdot2(q.p[2], kB0.p[2], pB, false);
        pA = __builtin_amdgcn_fdot2(q.p[3], kA0.p[3], pA, false);
        pB = __builtin_amdgcn_fdot2(q.p[3], kB0.p[3], pB, false);
        pA += __shfl_xor(pA, 1);
        pB += __shfl_xor(pB, 1);
        pA += __shfl_xor(pA, 2);
        pB += __shfl_xor(pB, 2);
        const float aA = pA;
        const float aB = (e + 4 < r1) ? pB : -1e30f;   // mask tail edge
        const float mn = fmaxf(m, fmaxf(aA, aB));
        const float c = exp2f(m - mn);
        const float eaA = exp2f(aA - mn);
        const float eaB = exp2f(aB - mn);
        s = s * c + eaA + eaB;
#pragma unroll
        for (int i = 0; i < 8; i++)
            acc[i] = fmaf(eaB, (float)vB0.v[i], fmaf(eaA, (float)vA0.v[i], acc[i] * c));
        m = mn;
        recA0 = recA1; recB0 = recB1; recA1 = recA2; recB1 = recB2;
        kA0 = kA1; vA0 = vA1; kB0 = kB1; vB0 = vB1;
        e += 8;
    }

    // merge the 4 slot-chains (associative online-softmax merge)
#pragma unroll
    for (int mask = 16; mask <= 32; mask <<= 1) {
        const float m2 = __shfl_xor(m, mask);
        const float s2 = __shfl_xor(s, mask);
        const float M = fmaxf(m, m2);
        const float c1 = exp2f(m - M);
        const float c2 = exp2f(m2 - M);
        s = s * c1 + s2 * c2;
#pragma unroll
        for (int i = 0; i < 8; i++) {
            const float o = __shfl_xor(acc[i], mask);
            acc[i] = acc[i] * c1 + o * c2;
        }
        m = M;
    }

    const float inv = (s > 0.f) ? (1.f / s) : 0.f;
    if (slot == 0) {
        f16x8 o;
#pragma unroll
        for (int i = 0; i < 8; i++) o[i] = (f16)gelu(acc[i] * inv);
        *(f16x8*)(gagg + (size_t)row * HD + sub * 8) = o;
    }
}

// ---------------------------------------------------------------------------
// MFMA update: o = gagg @ Wout + bout; x = g*o + (1-g)*x. Writes fp32 x,
// f16 xb, (last) fp32 d_out. Block's 4 waves share one B-tile.
__global__ __launch_bounds__(256) void k_upd(
    const f16* __restrict__ gagg,
    const f16* __restrict__ Wpod, const float* __restrict__ boutd,
    const float* __restrict__ skipd,
    const f16* __restrict__ Wpog, const float* __restrict__ boutg,
    const float* __restrict__ skipg,
    float* __restrict__ xall, f16* __restrict__ xball,
    int last, float* __restrict__ dout) {
    const int w = blockIdx.x * 4 + (threadIdx.x >> 6);
    const int nt = w / 2500, mt = w - nt * 2500;   // 2500 mtiles x 2 ntiles
    const int node0 = mt << 4;
    const bool gene = (node0 >= ND);
    const f16* Wp = gene ? Wpog : Wpod;
    const float* bias = gene ? boutg : boutd;
    const float g = 1.f / (1.f + expf(-(gene ? skipg[0] : skipd[0])));
    const int lane = threadIdx.x & 63;
    const int r = lane & 15, q4 = lane >> 4;
    const int col0 = nt << 6;
    f32x4 acc0 = {0.f, 0.f, 0.f, 0.f};
    f32x4 acc1 = acc0, acc2 = acc0, acc3 = acc0;
#pragma unroll
    for (int kb = 0; kb < 4; kb++) {
        const f16x8 a = *(const f16x8*)(gagg + (size_t)(node0 + r) * 128 + kb * 32 + q4 * 8);
        const f16* wb = Wp + ((size_t)kb * 128 + col0 + r) * 32 + q4 * 8;
        const f16x8 b0 = *(const f16x8*)(wb);
        const f16x8 b1 = *(const f16x8*)(wb + 512);
        const f16x8 b2 = *(const f16x8*)(wb + 1024);
        const f16x8 b3 = *(const f16x8*)(wb + 1536);
        acc0 = __builtin_amdgcn_mfma_f32_16x16x32_f16(a, b0, acc0, 0, 0, 0);
        acc1 = __builtin_amdgcn_mfma_f32_16x16x32_f16(a, b1, acc1, 0, 0, 0);
        acc2 = __builtin_amdgcn_mfma_f32_16x16x32_f16(a, b2, acc2, 0, 0, 0);
        acc3 = __builtin_amdgcn_mfma_f32_16x16x32_f16(a, b3, acc3, 0, 0, 0);
    }
    const f32x4 accs[4] = {acc0, acc1, acc2, acc3};
#pragma unroll
    for (int t = 0; t < 4; t++) {
        const int col = col0 + t * 16 + r;
        const float bb = bias[col];
#pragma unroll
        for (int reg = 0; reg < 4; reg++) {
            const size_t idx = (size_t)(node0 + q4 * 4 + reg) * 128 + col;
            const float xn = g * (accs[t][reg] + bb) + (1.f - g) * xall[idx];
            xall[idx] = xn;
            xball[idx] = (f16)xn;
            if (last) dout[idx] = xn;
        }
    }
}

// ---------------------------------------------------------------------------
static inline size_t alignup(size_t v) { return (v + 15) & ~(size_t)15; }

extern "C" void kernel_launch(void* const* d_in, const int* in_sizes, int n_in,
                              void* d_out, int out_size, void* d_ws, size_t ws_size,
                              hipStream_t stream) {
    (void)in_sizes; (void)n_in; (void)out_size; (void)ws_size;
    const int* src_dg = (const int*)d_in[2];
    const int* dst_dg = (const int*)d_in[3];
    const int* src_gd = (const int*)d_in[4];
    const int* dst_gd = (const int*)d_in[5];
    const int* src_gg = (const int*)d_in[6];
    const int* dst_gg = (const int*)d_in[7];

    // ---- workspace carve-up ----
    float* ws = (float*)d_ws;
    float* xd   = ws; ws += alignup((size_t)ND * HD);   // xall: disease rows then gene
    float* xg   = ws; ws += alignup((size_t)NG * HD);
    int* flag = (int*)ws; ws += 16;
    // CSR
    int* cnt_g  = (int*)ws; ws += alignup(NG);
    int* cnt_d  = (int*)ws; ws += alignup(ND);
    int* rp_g   = (int*)ws; ws += alignup(NG + 1);
    int* rp_d   = (int*)ws; ws += alignup(ND + 1);
    int* cur_g  = (int*)ws; ws += alignup(NG);
    int* cur_d  = (int*)ws; ws += alignup(ND);
    int* bsum   = (int*)ws; ws += alignup(NBG + NBD);
    int* edges_g = (int*)ws; ws += alignup(EG);
    int* edges_d = (int*)ws; ws += alignup(E_GD);
    // canonical fp32 inputs
    float* wkqvd = ws; ws += alignup((size_t)NLAYER * HD * 3 * HD);
    float* bkqvd = ws; ws += alignup((size_t)NLAYER * 3 * HD);
    float* wkqvg = ws; ws += alignup((size_t)NLAYER * HD * 3 * HD);
    float* bkqvg = ws; ws += alignup((size_t)NLAYER * 3 * HD);
    float* woutd = ws; ws += alignup((size_t)NLAYER * HD * HD);
    float* boutd = ws; ws += alignup((size_t)NLAYER * HD);
    float* woutg = ws; ws += alignup((size_t)NLAYER * HD * HD);
    float* boutg = ws; ws += alignup((size_t)NLAYER * HD);
    float* skipd = ws; ws += 16;
    float* skipg = ws; ws += 16;
    float* arelc = ws; ws += alignup((size_t)NLAYER * 3 * H * D * D);
    float* mrelc = ws; ws += alignup((size_t)NLAYER * 3 * H * D * D);
    float* prelc = ws; ws += 32;
    // combined bias (fp32)
    float* bp_d = ws; ws += alignup((size_t)NLAYER * OCD);
    float* bp_g = ws; ws += alignup((size_t)NLAYER * OCG);
    // f16 regions
    f16* Wp_d = (f16*)ws; ws += alignup((size_t)NLAYER * 4 * OCD * 32 / 2);
    f16* Wp_g = (f16*)ws; ws += alignup((size_t)NLAYER * 4 * OCG * 32 / 2);
    f16* Wpod = (f16*)ws; ws += alignup((size_t)NLAYER * 4 * 128 * 32 / 2);
    f16* Wpog = (f16*)ws; ws += alignup((size_t)NLAYER * 4 * 128 * 32 / 2);
    f16* xball = (f16*)ws; ws += alignup((size_t)(ND + NG) * HD / 2);
    f16* gagg  = (f16*)ws; ws += alignup((size_t)(ND + NG) * HD / 2);
    f16* tab   = (f16*)ws; ws += alignup(((size_t)ND * OCD + (size_t)NG * OCG) / 2);

    // ---- dtype detect + canonicalize (also emits f16 x) ----
    k_detect<<<1, 256, 0, stream>>>((const unsigned short*)d_in[0], flag);

    CvtDesc cd;
    const int seg_in[NSEG] = {0, 1, 8, 9, 10, 11, 12, 13, 14, 15, 16, 17, 18, 19, 20};
    float* const seg_dst[NSEG] = {xd, xg, wkqvd, bkqvd, wkqvg, bkqvg, woutd, boutd,
                                  woutg, boutg, skipd, skipg, arelc, mrelc, prelc};
    const int seg_n[NSEG] = {ND * HD, NG * HD,
                             NLAYER * HD * 3 * HD, NLAYER * 3 * HD,
                             NLAYER * HD * 3 * HD, NLAYER * 3 * HD,
                             NLAYER * HD * HD, NLAYER * HD,
                             NLAYER * HD * HD, NLAYER * HD,
                             NLAYER, NLAYER,
                             NLAYER * 3 * H * D * D, NLAYER * 3 * H * D * D,
                             NLAYER * 3 * H};
    int nblk = 0;
    for (int s = 0; s < NSEG; s++) {
        cd.src[s] = d_in[seg_in[s]];
        cd.dst[s] = seg_dst[s];
        cd.dst16[s] = (s == 0) ? xball : (s == 1) ? (xball + (size_t)ND * HD) : nullptr;
        cd.nelem[s] = seg_n[s];
        cd.blk0[s] = nblk;
        nblk += (seg_n[s] + 1023) / 1024;
    }
    k_cvt_all<<<nblk, 256, 0, stream>>>(cd, flag);

    // ---- combined/packed weights (once) ----
    k_prep<<<1280, 256, 0, stream>>>(
        wkqvd, bkqvd, wkqvg, bkqvg, arelc, mrelc, prelc,
        Wp_d, bp_d, Wp_g, bp_g, woutd, woutg, Wpod, Wpog);

    // ---- CSR build (once; graph is layer-invariant) ----
    hipError_t e0 = hipMemsetAsync(cnt_g, 0, sizeof(int) * (NG + ND), stream);
    (void)e0;   // cnt_g+cnt_d contiguous
    k_hist<<<(NE + 255) / 256, 256, 0, stream>>>(dst_dg, dst_gg, dst_gd, cnt_g, cnt_d);
    k_scan_p1<<<NBG + NBD, 256, 0, stream>>>(cnt_g, cnt_d, bsum);
    k_scan_p2<<<1, 64, 0, stream>>>(bsum);
    k_scan_p3<<<NBG + NBD, 256, 0, stream>>>(cnt_g, cnt_d, bsum, rp_g, cur_g, rp_d, cur_d);
    k_scatter<<<(NE + 255) / 256, 256, 0, stream>>>(
        src_dg, dst_dg, src_gg, dst_gg, src_gd, dst_gd,
        cur_g, cur_d, edges_g, edges_d);

    for (int l = 0; l < NLAYER; l++) {
        k_gemm2<<<5625, 256, 0, stream>>>(
            xball, Wp_d + (size_t)l * 4 * OCD * 32, bp_d + l * OCD,
            Wp_g + (size_t)l * 4 * OCG * 32, bp_g + l * OCG, tab);
        k_agg<<<(NG + ND) / 4, 256, 0, stream>>>(
            rp_g, edges_g, rp_d, edges_d, tab, gagg);
        k_upd<<<1250, 256, 0, stream>>>(
            gagg,
            Wpod + (size_t)l * 4 * 128 * 32, boutd + l * HD, skipd + l,
            Wpog + (size_t)l * 4 * 128 * 32, boutg + l * HD, skipg + l,
            xd, xball, (l == NLAYER - 1) ? 1 : 0, (float*)d_out);
    }
}

// Round 11
// 372.878 us; speedup vs baseline: 7.2983x; 1.0602x over previous
//
#include <hip/hip_runtime.h>
#include <hip/hip_bf16.h>

#define H 4
#define D 32
#define HD 128
#define ND 10000
#define NG 30000
#define E_DG 150000
#define E_GD 150000
#define E_GG 300000
#define NE (E_DG + E_GD + E_GG)
#define EG (E_DG + E_GG)   // edges into gene nodes
#define NLAYER 2
#define NBG 30             // ceil(NG/1024)
#define NBD 10             // ceil(ND/1024)
#define OCG 640            // gene table cols:   [q|k1|v1|k2|v2]
#define OCD 384            // disease table cols:[q|k0|v0]
#define GOFF ((size_t)ND * OCD)   // gene rows offset in unified table
#define NSCAT 2344         // scatter blocks
#define NGEMM 5625         // gemm0 blocks (22500 wave-tiles / 4)

typedef _Float16 f16;
typedef __attribute__((ext_vector_type(2))) _Float16 f16x2;
typedef __attribute__((ext_vector_type(8))) _Float16 f16x8;
typedef __attribute__((ext_vector_type(8))) unsigned short u16x8;
typedef __attribute__((ext_vector_type(4))) float f32x4;

__device__ __forceinline__ float bu(unsigned short u) {
    return __uint_as_float(((unsigned)u) << 16);
}
// raw input load with dtype branch (isf32 wave-uniform)
__device__ __forceinline__ float ldraw(const void* p, size_t i, bool isf32) {
    return isf32 ? ((const float*)p)[i] : bu(((const unsigned short*)p)[i]);
}
__device__ __forceinline__ float gelu(float v) {
    const float c = 0.79788456080286536f * (v + 0.044715f * v * v * v);
    return 0.5f * v * (1.0f + tanhf(c));
}

// ---------------------------------------------------------------------------
// Combined-weight fold (rel matrices + prel*scale*log2e into K), raw inputs.
__device__ __forceinline__ void combine_one(
    int idx, int GENE, bool isf32,
    const void* W, const void* bvec,
    const void* arel, const void* mrel, const void* prel,
    f16* __restrict__ Wp, float* __restrict__ bp) {
    const int OC = GENE ? OCG : OCD;
    const int l = idx / (OC * 128);
    const int rem = idx - l * OC * 128;
    const int col = rem >> 7;
    const int d = rem & 127;
    const int g = col >> 7;           // 0=q, 1/3=k, 2/4=v
    const int jj = col & 127;
    const int h = jj >> 5, f = jj & 31;
    const size_t wbase = (size_t)l * 128 * 384;
    const size_t bbase = (size_t)l * 384;
    float val, bv = 0.f;
    if (g == 0) {
        val = ldraw(W, wbase + d * 384 + 128 + jj, isf32);
        bv = ldraw(bvec, bbase + 128 + jj, isf32);
    } else {
        const int et = GENE ? ((g <= 2) ? 1 : 2) : 0;
        const bool isk = (g & 1);
        const void* mat = isk ? arel : mrel;
        const size_t mbase = (((size_t)(l * 3 + et) * H + h) << 10) + f;
        const int sb = isk ? 0 : 256;
        val = 0.f;
        for (int dd = 0; dd < 32; dd++)
            val += ldraw(W, wbase + d * 384 + sb + h * 32 + dd, isf32) *
                   ldraw(mat, mbase + dd * 32, isf32);
        if (d == 0)
            for (int dd = 0; dd < 32; dd++)
                bv += ldraw(bvec, bbase + sb + h * 32 + dd, isf32) *
                      ldraw(mat, mbase + dd * 32, isf32);
        if (isk) {
            const float sc = ldraw(prel, (size_t)(l * 3 + et) * H + h, isf32) *
                             (0.17677669529663689f * 1.4426950408889634f);
            val *= sc;
            bv *= sc;
        }
    }
    Wp[(size_t)l * 4 * OC * 32 + ((size_t)(d >> 5) * OC + col) * 32 + (d & 31)] = (f16)val;
    if (d == 0) bp[l * OC + col] = bv;
}

// ---------------------------------------------------------------------------
// Mega-prep: self-detect dtype, fold+pack all weights, zero cnt/ready,
// convert bout, compute sigmoid(skip) gates, publish flag.
// blocks [0,1280): combine/pack; block 1280: misc; blocks 1281..1320: zero cnt.
__global__ __launch_bounds__(256) void k_prep0(
    const void* x0,
    const void* wkqvd_r, const void* bkqvd_r,
    const void* wkqvg_r, const void* bkqvg_r,
    const void* arel_r, const void* mrel_r, const void* prel_r,
    const void* woutd_r, const void* woutg_r,
    const void* boutd_r, const void* boutg_r,
    const void* skipd_r, const void* skipg_r,
    f16* __restrict__ Wp_d, float* __restrict__ bp_d,
    f16* __restrict__ Wp_g, float* __restrict__ bp_g,
    f16* __restrict__ Wpod, f16* __restrict__ Wpog,
    float* __restrict__ boutc_d, float* __restrict__ boutc_g,
    float* __restrict__ gates, int* __restrict__ flag,
    int* __restrict__ cnt, int* __restrict__ ready) {
    const int tid = threadIdx.x;
    // per-block dtype detect from x0's first 1024 halves
    __shared__ int sbad;
    if (tid == 0) sbad = 0;
    __syncthreads();
    {
        const unsigned short* xs = (const unsigned short*)x0;
        int bad = 0;
        for (int i = tid; i < 1024; i += 256)
            if (!(fabsf(bu(xs[i])) < 1e6f)) bad = 1;
        if (bad) sbad = 1;   // benign race
    }
    __syncthreads();
    const bool isf32 = (sbad != 0);

    const int b = blockIdx.x;
    if (b < 1280) {
        int idx = b * 256 + tid;
        const int nd = NLAYER * OCD * 128;
        const int ng = NLAYER * OCG * 128;
        const int np = 2 * NLAYER * 128 * 128;
        if (idx < nd) {
            combine_one(idx, 0, isf32, wkqvd_r, bkqvd_r, arel_r, mrel_r, prel_r, Wp_d, bp_d);
        } else if ((idx -= nd) < ng) {
            combine_one(idx, 1, isf32, wkqvg_r, bkqvg_r, arel_r, mrel_r, prel_r, Wp_g, bp_g);
        } else if ((idx -= ng) < np) {
            const int type = idx >= NLAYER * 128 * 128;
            int rem = idx - type * NLAYER * 128 * 128;
            const int l = rem / (128 * 128);
            rem -= l * 128 * 128;
            const int d = rem >> 7, col = rem & 127;
            const float w = ldraw(type ? woutg_r : woutd_r,
                                  (size_t)l * 128 * 128 + d * 128 + col, isf32);
            f16* out = (type ? Wpog : Wpod) +
                ((size_t)l * 4 + (d >> 5)) * 128 * 32 + col * 32 + (d & 31);
            *out = (f16)w;
        }
    } else if (b == 1280) {
        if (tid < NBG + NBD) ready[tid] = 0;
        if (tid == 0) {
            flag[0] = isf32 ? 1 : 0;
            gates[0] = 1.f / (1.f + expf(-ldraw(skipd_r, 0, isf32)));
            gates[1] = 1.f / (1.f + expf(-ldraw(skipg_r, 0, isf32)));
            gates[2] = 1.f / (1.f + expf(-ldraw(skipd_r, 1, isf32)));
            gates[3] = 1.f / (1.f + expf(-ldraw(skipg_r, 1, isf32)));
        }
        for (int i = tid; i < NLAYER * 128; i += 256) {
            boutc_d[i] = ldraw(boutd_r, i, isf32);
            boutc_g[i] = ldraw(boutg_r, i, isf32);
        }
    } else {
        const int base = (b - 1281) * 1000;   // zero cnt[0..39999] (cnt_g||cnt_d)
        for (int i = tid; i < 1000; i += 256) cnt[base + i] = 0;
    }
}

// ---------------------------------------------------------------------------
// histogram of destinations
__global__ __launch_bounds__(256) void k_hist(
    const int* __restrict__ dst_dg, const int* __restrict__ dst_gg,
    const int* __restrict__ dst_gd,
    int* __restrict__ cnt_g, int* __restrict__ cnt_d) {
    const int i = blockIdx.x * 256 + threadIdx.x;
    if (i < E_DG) atomicAdd(cnt_g + dst_dg[i], 1);
    else if (i < EG) atomicAdd(cnt_g + dst_gg[i - E_DG], 1);
    else if (i < NE) atomicAdd(cnt_d + dst_gd[i - EG], 1);
}

// ---------------------------------------------------------------------------
// Single-dispatch scan via decoupled lookback. 40 blocks (<=256 CUs, all
// co-resident). Block sum is packed into the ready word (S+1), so the atomic
// payload itself carries the data - no separate fence needed.
__global__ __launch_bounds__(256) void k_scan(
    const int* __restrict__ cnt_g, const int* __restrict__ cnt_d,
    int* __restrict__ ready,
    int* __restrict__ rp_g, int* __restrict__ cur_g,
    int* __restrict__ rp_d, int* __restrict__ cur_d) {
    const int b = blockIdx.x;
    const int tid = threadIdx.x;
    const bool isg = (b < NBG);
    const int* cnt = isg ? cnt_g : cnt_d;
    int* rp = isg ? rp_g : rp_d;
    int* cur = isg ? cur_g : cur_d;
    const int n = isg ? NG : ND;
    const int lb = isg ? b : (b - NBG);
    const int i0 = lb * 1024 + tid * 4;
    int v[4];
    int t = 0;
#pragma unroll
    for (int j = 0; j < 4; j++) {
        v[j] = (i0 + j < n) ? cnt[i0 + j] : 0;
        t += v[j];
    }
    __shared__ int sdata[256];
    __shared__ int red2[256];
    __shared__ int s_off;
    sdata[tid] = t;
    __syncthreads();
    for (int d = 1; d < 256; d <<= 1) {
        const int u = (tid >= d) ? sdata[tid - d] : 0;
        __syncthreads();
        sdata[tid] += u;
        __syncthreads();
    }
    const int total = sdata[255];
    if (tid == 0) atomicExch(&ready[b], total + 1);   // publish before spinning
    // lookback: spin on same-segment predecessors in parallel
    const int p0 = isg ? 0 : NBG;
    const int npred = b - p0;
    int part = 0;
    for (int i = tid; i < npred; i += 256) {
        int vv;
        do { vv = atomicAdd(&ready[p0 + i], 0); } while (vv == 0);
        part += vv - 1;
    }
    red2[tid] = part;
    __syncthreads();
    for (int d = 128; d > 0; d >>= 1) {
        if (tid < d) red2[tid] += red2[tid + d];
        __syncthreads();
    }
    if (tid == 0) s_off = red2[0];
    __syncthreads();
    int run = s_off + sdata[tid] - t;   // exclusive prefix for this thread
#pragma unroll
    for (int j = 0; j < 4; j++) {
        if (i0 + j < n) {
            cur[i0 + j] = run;
            run += v[j];
            rp[i0 + j + 1] = run;
        }
    }
    if (tid == 0 && lb == 0) rp[0] = 0;
}

// ---------------------------------------------------------------------------
// Fused scatter (blocks [0,NSCAT)) + layer-0 KQV GEMM (blocks [NSCAT,..)).
// Edge record = element offset of src's k-row in the unified table (v at +128).
// GEMM reads RAW x inputs (dtype branch), writes f16 tab. 4 waves share B-tile.
__global__ __launch_bounds__(256) void k_scatter_gemm0(
    const int* __restrict__ src_dg, const int* __restrict__ dst_dg,
    const int* __restrict__ src_gg, const int* __restrict__ dst_gg,
    const int* __restrict__ src_gd, const int* __restrict__ dst_gd,
    int* __restrict__ cur_g, int* __restrict__ cur_d,
    int* __restrict__ edges_g, int* __restrict__ edges_d,
    const void* xd_r, const void* xg_r, const int* __restrict__ flag,
    const f16* __restrict__ Wpd, const float* __restrict__ bpd,
    const f16* __restrict__ Wpg, const float* __restrict__ bpg,
    f16* __restrict__ tab) {
    if (blockIdx.x < NSCAT) {
        const int i = blockIdx.x * 256 + threadIdx.x;
        if (i < E_DG) {
            const int pos = atomicAdd(cur_g + dst_dg[i], 1);
            edges_g[pos] = src_dg[i] * OCD + 128;                 // et0: d->g
        } else if (i < EG) {
            const int j = i - E_DG;
            const int pos = atomicAdd(cur_g + dst_gg[j], 1);
            edges_g[pos] = (int)GOFF + src_gg[j] * OCG + 384;     // et2: g->g
        } else if (i < NE) {
            const int j = i - EG;
            const int pos = atomicAdd(cur_d + dst_gd[j], 1);
            edges_d[pos] = (int)GOFF + src_gd[j] * OCG + 128;     // et1: g->d
        }
        return;
    }
    const bool isf32 = (*flag != 0);
    int w = (blockIdx.x - NSCAT) * 4 + (threadIdx.x >> 6);
    const void* xr;
    const f16* Wp;
    const float* bias;
    f16* out;
    int mt, nt, OC;
    if (w < 3750) {                 // disease: 625 mtiles x 6 ntiles
        xr = xd_r; Wp = Wpd; bias = bpd; out = tab; OC = OCD;
        nt = w / 625; mt = w - nt * 625;
    } else {                        // gene: 1875 mtiles x 10 ntiles
        w -= 3750;
        xr = xg_r; Wp = Wpg; bias = bpg; out = tab + GOFF; OC = OCG;
        nt = w / 1875; mt = w - nt * 1875;
    }
    const int lane = threadIdx.x & 63;
    const int r = lane & 15, q4 = lane >> 4;
    const int node0 = mt << 4, col0 = nt << 6;
    f32x4 acc0 = {0.f, 0.f, 0.f, 0.f};
    f32x4 acc1 = acc0, acc2 = acc0, acc3 = acc0;
#pragma unroll
    for (int kb = 0; kb < 4; kb++) {
        f16x8 a;
        const size_t base = (size_t)(node0 + r) * 128 + kb * 32 + q4 * 8;
        if (isf32) {
            const float* xp = (const float*)xr + base;
            const float4 u0 = *(const float4*)xp;
            const float4 u1 = *(const float4*)(xp + 4);
            a[0] = (f16)u0.x; a[1] = (f16)u0.y; a[2] = (f16)u0.z; a[3] = (f16)u0.w;
            a[4] = (f16)u1.x; a[5] = (f16)u1.y; a[6] = (f16)u1.z; a[7] = (f16)u1.w;
        } else {
            const u16x8 u = *(const u16x8*)((const unsigned short*)xr + base);
#pragma unroll
            for (int i = 0; i < 8; i++) a[i] = (f16)bu(u[i]);
        }
        const f16* wb = Wp + ((size_t)kb * OC + col0 + r) * 32 + q4 * 8;
        const f16x8 b0 = *(const f16x8*)(wb);
        const f16x8 b1 = *(const f16x8*)(wb + 512);
        const f16x8 b2 = *(const f16x8*)(wb + 1024);
        const f16x8 b3 = *(const f16x8*)(wb + 1536);
        acc0 = __builtin_amdgcn_mfma_f32_16x16x32_f16(a, b0, acc0, 0, 0, 0);
        acc1 = __builtin_amdgcn_mfma_f32_16x16x32_f16(a, b1, acc1, 0, 0, 0);
        acc2 = __builtin_amdgcn_mfma_f32_16x16x32_f16(a, b2, acc2, 0, 0, 0);
        acc3 = __builtin_amdgcn_mfma_f32_16x16x32_f16(a, b3, acc3, 0, 0, 0);
    }
    const f32x4 accs[4] = {acc0, acc1, acc2, acc3};
#pragma unroll
    for (int t = 0; t < 4; t++) {
        const int col = col0 + t * 16 + r;
        const float bb = bias[col];
#pragma unroll
        for (int reg = 0; reg < 4; reg++)
            out[(size_t)(node0 + q4 * 4 + reg) * OC + col] = (f16)(accs[t][reg] + bb);
    }
}

// ---------------------------------------------------------------------------
// Unified gather aggregation (unchanged from r10): f16 tables + v_dot2 +
// direct-offset edge recs; 4 slots x 2 edges/iter; gelu'd f16 output.
__global__ __launch_bounds__(256) void k_agg(
    const int* __restrict__ rp_g, const int* __restrict__ edges_g,
    const int* __restrict__ rp_d, const int* __restrict__ edges_d,
    const f16* __restrict__ tab, f16* __restrict__ gagg) {
    const int wid = blockIdx.x * 4 + (threadIdx.x >> 6);
    const int lane = threadIdx.x & 63;
    const int slot = lane >> 4, sub = lane & 15;

    int node, row;
    const int *rp, *edges;
    size_t qoff;
    if (wid < NG) {
        node = wid; rp = rp_g; edges = edges_g;
        qoff = GOFF + (size_t)node * OCG;
        row = ND + node;
    } else {
        node = wid - NG; rp = rp_d; edges = edges_d;
        qoff = (size_t)node * OCD;
        row = node;
    }

    union U { f16x8 v; f16x2 p[4]; };
    U q;
    q.v = *(const f16x8*)(tab + qoff + sub * 8);

    float m = -1e30f, s = 0.f;
    float acc[8];
#pragma unroll
    for (int i = 0; i < 8; i++) acc[i] = 0.f;

    const int r0 = rp[node], r1 = rp[node + 1];
    int e = r0 + slot;

    auto kvload = [&](int rec, U& k, U& v) {
        const f16* p = tab + (size_t)rec + sub * 8;
        k.v = *(const f16x8*)p;
        v.v = *(const f16x8*)(p + 128);
    };

    int recA0 = (e < r1) ? edges[e] : 0;
    int recB0 = (e + 4 < r1) ? edges[e + 4] : 0;
    U kA0, vA0, kB0, vB0;
    kvload(recA0, kA0, vA0);
    kvload(recB0, kB0, vB0);
    int recA1 = (e + 8 < r1) ? edges[e + 8] : 0;
    int recB1 = (e + 12 < r1) ? edges[e + 12] : 0;

    while (e < r1) {
        const int recA2 = (e + 16 < r1) ? edges[e + 16] : 0;
        const int recB2 = (e + 20 < r1) ? edges[e + 20] : 0;
        U kA1, vA1, kB1, vB1;
        kvload(recA1, kA1, vA1);
        kvload(recB1, kB1, vB1);

        float pA = __builtin_amdgcn_fdot2(q.p[0], kA0.p[0], 0.f, false);
        float pB = __builtin_amdgcn_fdot2(q.p[0], kB0.p[0], 0.f, false);
        pA = __builtin_amdgcn_fdot2(q.p[1], kA0.p[1], pA, false);
        pB = __builtin_amdgcn_fdot2(q.p[1], kB0.p[1], pB, false);
        pA = __builtin_amdgcn_fdot2(q.p[2], kA0.p[2], pA, false);
        pB = __builtin_amdgcn_fdot2(q.p[2], kB0.p[2], pB, false);
        pA = __builtin_amdgcn_fdot2(q.p[3], kA0.p[3], pA, false);
        pB = __builtin_amdgcn_fdot2(q.p[3], kB0.p[3], pB, false);
        pA += __shfl_xor(pA, 1);
        pB += __shfl_xor(pB, 1);
        pA += __shfl_xor(pA, 2);
        pB += __shfl_xor(pB, 2);
        const float aA = pA;
        const float aB = (e + 4 < r1) ? pB : -1e30f;
        const float mn = fmaxf(m, fmaxf(aA, aB));
        const float c = exp2f(m - mn);
        const float eaA = exp2f(aA - mn);
        const float eaB = exp2f(aB - mn);
        s = s * c + eaA + eaB;
#pragma unroll
        for (int i = 0; i < 8; i++)
            acc[i] = fmaf(eaB, (float)vB0.v[i], fmaf(eaA, (float)vA0.v[i], acc[i] * c));
        m = mn;
        recA0 = recA1; recB0 = recB1; recA1 = recA2; recB1 = recB2;
        kA0 = kA1; vA0 = vA1; kB0 = kB1; vB0 = vB1;
        e += 8;
    }

#pragma unroll
    for (int mask = 16; mask <= 32; mask <<= 1) {
        const float m2 = __shfl_xor(m, mask);
        const float s2 = __shfl_xor(s, mask);
        const float M = fmaxf(m, m2);
        const float c1 = exp2f(m - M);
        const float c2 = exp2f(m2 - M);
        s = s * c1 + s2 * c2;
#pragma unroll
        for (int i = 0; i < 8; i++) {
            const float o = __shfl_xor(acc[i], mask);
            acc[i] = acc[i] * c1 + o * c2;
        }
        m = M;
    }

    const float inv = (s > 0.f) ? (1.f / s) : 0.f;
    if (slot == 0) {
        f16x8 o;
#pragma unroll
        for (int i = 0; i < 8; i++) o[i] = (f16)gelu(acc[i] * inv);
        *(f16x8*)(gagg + (size_t)row * HD + sub * 8) = o;
    }
}

// ---------------------------------------------------------------------------
// Fused layer-0 update + layer-1 KQV GEMM. Block = 32 nodes (2 mtiles).
// Phase 1 (4 waves = 4 upd tiles): x1 = g*(gagg@Wout0+b)+(1-g)*x_raw -> LDS
// (f16) + global xball. Phase 2: layer-1 table GEMM with A from LDS.
__global__ __launch_bounds__(256) void k_updgemm(
    const f16* __restrict__ gagg,
    const f16* __restrict__ Wpod0, const f16* __restrict__ Wpog0,
    const float* __restrict__ boutc_d0, const float* __restrict__ boutc_g0,
    const float* __restrict__ gates,   // [0]=d0 [1]=g0
    const void* xd_r, const void* xg_r, const int* __restrict__ flag,
    f16* __restrict__ xball,
    const f16* __restrict__ Wpd1, const float* __restrict__ bpd1,
    const f16* __restrict__ Wpg1, const float* __restrict__ bpg1,
    f16* __restrict__ tab) {
    __shared__ f16 xls[32 * 128];
    const bool isf32 = (*flag != 0);
    const int tid = threadIdx.x;
    const int wv = tid >> 6, lane = tid & 63;
    const int r = lane & 15, q4 = lane >> 4;

    // ---- phase 1: update ----
    {
        const int mtl = wv >> 1, nt = wv & 1;
        const int mtile = blockIdx.x * 2 + mtl;
        const int node0 = mtile * 16;
        const bool gene = (node0 >= ND);
        const f16* Wp = gene ? Wpog0 : Wpod0;
        const float* bias = gene ? boutc_g0 : boutc_d0;
        const float g = gates[gene ? 1 : 0];
        const int col0 = nt << 6;
        f32x4 acc0 = {0.f, 0.f, 0.f, 0.f};
        f32x4 acc1 = acc0, acc2 = acc0, acc3 = acc0;
#pragma unroll
        for (int kb = 0; kb < 4; kb++) {
            const f16x8 a = *(const f16x8*)(gagg + (size_t)(node0 + r) * 128 + kb * 32 + q4 * 8);
            const f16* wb = Wp + ((size_t)kb * 128 + col0 + r) * 32 + q4 * 8;
            const f16x8 b0 = *(const f16x8*)(wb);
            const f16x8 b1 = *(const f16x8*)(wb + 512);
            const f16x8 b2 = *(const f16x8*)(wb + 1024);
            const f16x8 b3 = *(const f16x8*)(wb + 1536);
            acc0 = __builtin_amdgcn_mfma_f32_16x16x32_f16(a, b0, acc0, 0, 0, 0);
            acc1 = __builtin_amdgcn_mfma_f32_16x16x32_f16(a, b1, acc1, 0, 0, 0);
            acc2 = __builtin_amdgcn_mfma_f32_16x16x32_f16(a, b2, acc2, 0, 0, 0);
            acc3 = __builtin_amdgcn_mfma_f32_16x16x32_f16(a, b3, acc3, 0, 0, 0);
        }
        const f32x4 accs[4] = {acc0, acc1, acc2, acc3};
        const void* xr = gene ? xg_r : xd_r;
        const int lrow0 = node0 - (gene ? ND : 0);
#pragma unroll
        for (int t = 0; t < 4; t++) {
            const int col = col0 + t * 16 + r;
            const float bb = bias[col];
#pragma unroll
            for (int reg = 0; reg < 4; reg++) {
                const int rr = q4 * 4 + reg;
                const float xo = ldraw(xr, (size_t)(lrow0 + rr) * 128 + col, isf32);
                const float xn = g * (accs[t][reg] + bb) + (1.f - g) * xo;
                xls[(mtl * 16 + rr) * 128 + col] = (f16)xn;
                xball[(size_t)(node0 + rr) * 128 + col] = (f16)xn;
            }
        }
    }
    __syncthreads();

    // ---- phase 2: layer-1 KQV GEMM from LDS ----
    const int mt0 = blockIdx.x * 2;
    const int n0 = ((mt0 * 16) >= ND) ? 10 : 6;
    const int n1 = (((mt0 + 1) * 16) >= ND) ? 10 : 6;
    for (int it = wv; it < n0 + n1; it += 4) {
        const int mtl = (it < n0) ? 0 : 1;
        const int ntl = (it < n0) ? it : (it - n0);
        const int node0 = (mt0 + mtl) * 16;
        const bool gene = (node0 >= ND);
        const int OC = gene ? OCG : OCD;
        const f16* Wp = gene ? Wpg1 : Wpd1;
        const float* bias = gene ? bpg1 : bpd1;
        f16* out = gene ? (tab + GOFF) : tab;
        const int trow0 = node0 - (gene ? ND : 0);
        const int col0 = ntl << 6;
        f32x4 acc0 = {0.f, 0.f, 0.f, 0.f};
        f32x4 acc1 = acc0, acc2 = acc0, acc3 = acc0;
#pragma unroll
        for (int kb = 0; kb < 4; kb++) {
            const f16x8 a = *(const f16x8*)(xls + (mtl * 16 + r) * 128 + kb * 32 + q4 * 8);
            const f16* wb = Wp + ((size_t)kb * OC + col0 + r) * 32 + q4 * 8;
            const f16x8 b0 = *(const f16x8*)(wb);
            const f16x8 b1 = *(const f16x8*)(wb + 512);
            const f16x8 b2 = *(const f16x8*)(wb + 1024);
            const f16x8 b3 = *(const f16x8*)(wb + 1536);
            acc0 = __builtin_amdgcn_mfma_f32_16x16x32_f16(a, b0, acc0, 0, 0, 0);
            acc1 = __builtin_amdgcn_mfma_f32_16x16x32_f16(a, b1, acc1, 0, 0, 0);
            acc2 = __builtin_amdgcn_mfma_f32_16x16x32_f16(a, b2, acc2, 0, 0, 0);
            acc3 = __builtin_amdgcn_mfma_f32_16x16x32_f16(a, b3, acc3, 0, 0, 0);
        }
        const f32x4 accs[4] = {acc0, acc1, acc2, acc3};
#pragma unroll
        for (int t = 0; t < 4; t++) {
            const int col = col0 + t * 16 + r;
            const float bb = bias[col];
#pragma unroll
            for (int reg = 0; reg < 4; reg++)
                out[(size_t)(trow0 + q4 * 4 + reg) * OC + col] = (f16)(accs[t][reg] + bb);
        }
    }
}

// ---------------------------------------------------------------------------
// Final update (layer 1): o = gagg @ Wout1 + b; dout = g*o + (1-g)*x1 (f16).
__global__ __launch_bounds__(256) void k_upd1(
    const f16* __restrict__ gagg,
    const f16* __restrict__ Wpod1, const f16* __restrict__ Wpog1,
    const float* __restrict__ boutc_d1, const float* __restrict__ boutc_g1,
    const float* __restrict__ gates,   // [0]=d1 [1]=g1 (pre-offset)
    const f16* __restrict__ xball, float* __restrict__ dout) {
    const int w = blockIdx.x * 4 + (threadIdx.x >> 6);
    const int nt = w / 2500, mt = w - nt * 2500;
    const int node0 = mt << 4;
    const bool gene = (node0 >= ND);
    const f16* Wp = gene ? Wpog1 : Wpod1;
    const float* bias = gene ? boutc_g1 : boutc_d1;
    const float g = gates[gene ? 1 : 0];
    const int lane = threadIdx.x & 63;
    const int r = lane & 15, q4 = lane >> 4;
    const int col0 = nt << 6;
    f32x4 acc0 = {0.f, 0.f, 0.f, 0.f};
    f32x4 acc1 = acc0, acc2 = acc0, acc3 = acc0;
#pragma unroll
    for (int kb = 0; kb < 4; kb++) {
        const f16x8 a = *(const f16x8*)(gagg + (size_t)(node0 + r) * 128 + kb * 32 + q4 * 8);
        const f16* wb = Wp + ((size_t)kb * 128 + col0 + r) * 32 + q4 * 8;
        const f16x8 b0 = *(const f16x8*)(wb);
        const f16x8 b1 = *(const f16x8*)(wb + 512);
        const f16x8 b2 = *(const f16x8*)(wb + 1024);
        const f16x8 b3 = *(const f16x8*)(wb + 1536);
        acc0 = __builtin_amdgcn_mfma_f32_16x16x32_f16(a, b0, acc0, 0, 0, 0);
        acc1 = __builtin_amdgcn_mfma_f32_16x16x32_f16(a, b1, acc1, 0, 0, 0);
        acc2 = __builtin_amdgcn_mfma_f32_16x16x32_f16(a, b2, acc2, 0, 0, 0);
        acc3 = __builtin_amdgcn_mfma_f32_16x16x32_f16(a, b3, acc3, 0, 0, 0);
    }
    const f32x4 accs[4] = {acc0, acc1, acc2, acc3};
#pragma unroll
    for (int t = 0; t < 4; t++) {
        const int col = col0 + t * 16 + r;
        const float bb = bias[col];
#pragma unroll
        for (int reg = 0; reg < 4; reg++) {
            const size_t idx = (size_t)(node0 + q4 * 4 + reg) * 128 + col;
            dout[idx] = g * (accs[t][reg] + bb) + (1.f - g) * (float)xball[idx];
        }
    }
}

// ---------------------------------------------------------------------------
static inline size_t alignup(size_t v) { return (v + 15) & ~(size_t)15; }

extern "C" void kernel_launch(void* const* d_in, const int* in_sizes, int n_in,
                              void* d_out, int out_size, void* d_ws, size_t ws_size,
                              hipStream_t stream) {
    (void)in_sizes; (void)n_in; (void)out_size; (void)ws_size;
    const int* src_dg = (const int*)d_in[2];
    const int* dst_dg = (const int*)d_in[3];
    const int* src_gd = (const int*)d_in[4];
    const int* dst_gd = (const int*)d_in[5];
    const int* src_gg = (const int*)d_in[6];
    const int* dst_gg = (const int*)d_in[7];

    // ---- workspace carve-up ----
    float* ws = (float*)d_ws;
    int* flag = (int*)ws; ws += 16;
    int* cnt_g  = (int*)ws; ws += alignup(NG);   // cnt_g||cnt_d contiguous (30000%16==0)
    int* cnt_d  = (int*)ws; ws += alignup(ND);
    int* rp_g   = (int*)ws; ws += alignup(NG + 1);
    int* rp_d   = (int*)ws; ws += alignup(ND + 1);
    int* cur_g  = (int*)ws; ws += alignup(NG);
    int* cur_d  = (int*)ws; ws += alignup(ND);
    int* ready  = (int*)ws; ws += 64;
    int* edges_g = (int*)ws; ws += alignup(EG);
    int* edges_d = (int*)ws; ws += alignup(E_GD);
    float* bp_d = ws; ws += alignup((size_t)NLAYER * OCD);
    float* bp_g = ws; ws += alignup((size_t)NLAYER * OCG);
    float* boutc_d = ws; ws += alignup((size_t)NLAYER * 128);
    float* boutc_g = ws; ws += alignup((size_t)NLAYER * 128);
    float* gates = ws; ws += 16;
    f16* Wp_d = (f16*)ws; ws += alignup((size_t)NLAYER * 4 * OCD * 32 / 2);
    f16* Wp_g = (f16*)ws; ws += alignup((size_t)NLAYER * 4 * OCG * 32 / 2);
    f16* Wpod = (f16*)ws; ws += alignup((size_t)NLAYER * 4 * 128 * 32 / 2);
    f16* Wpog = (f16*)ws; ws += alignup((size_t)NLAYER * 4 * 128 * 32 / 2);
    f16* xball = (f16*)ws; ws += alignup((size_t)(ND + NG) * HD / 2);
    f16* gagg  = (f16*)ws; ws += alignup((size_t)(ND + NG) * HD / 2);
    f16* tab   = (f16*)ws; ws += alignup(((size_t)ND * OCD + (size_t)NG * OCG) / 2);

    // 1) mega-prep: detect + weight fold/pack + zero cnt/ready + bout/gates
    k_prep0<<<1321, 256, 0, stream>>>(
        d_in[0],
        d_in[8], d_in[9], d_in[10], d_in[11],
        d_in[18], d_in[19], d_in[20],
        d_in[12], d_in[14], d_in[13], d_in[15], d_in[16], d_in[17],
        Wp_d, bp_d, Wp_g, bp_g, Wpod, Wpog, boutc_d, boutc_g,
        gates, flag, cnt_g, ready);
    // 2) histogram
    k_hist<<<NSCAT, 256, 0, stream>>>(dst_dg, dst_gg, dst_gd, cnt_g, cnt_d);
    // 3) single-dispatch lookback scan
    k_scan<<<NBG + NBD, 256, 0, stream>>>(cnt_g, cnt_d, ready, rp_g, cur_g, rp_d, cur_d);
    // 4) scatter + layer-0 KQV GEMM (raw x input)
    k_scatter_gemm0<<<NSCAT + NGEMM, 256, 0, stream>>>(
        src_dg, dst_dg, src_gg, dst_gg, src_gd, dst_gd,
        cur_g, cur_d, edges_g, edges_d,
        d_in[0], d_in[1], flag,
        Wp_d, bp_d, Wp_g, bp_g, tab);
    // 5) layer-0 aggregation
    k_agg<<<(NG + ND) / 4, 256, 0, stream>>>(rp_g, edges_g, rp_d, edges_d, tab, gagg);
    // 6) layer-0 update fused with layer-1 KQV GEMM
    k_updgemm<<<(ND + NG) / 32, 256, 0, stream>>>(
        gagg, Wpod, Wpog, boutc_d, boutc_g, gates,
        d_in[0], d_in[1], flag, xball,
        Wp_d + (size_t)4 * OCD * 32, bp_d + OCD,
        Wp_g + (size_t)4 * OCG * 32, bp_g + OCG, tab);
    // 7) layer-1 aggregation
    k_agg<<<(NG + ND) / 4, 256, 0, stream>>>(rp_g, edges_g, rp_d, edges_d, tab, gagg);
    // 8) final update -> d_out (fp32)
    k_upd1<<<(ND + NG) / 32, 256, 0, stream>>>(
        gagg, Wpod + (size_t)4 * 128 * 32, Wpog + (size_t)4 * 128 * 32,
        boutc_d + 128, boutc_g + 128, gates + 2, xball, (float*)d_out);
}

// Round 12
// 362.149 us; speedup vs baseline: 7.5146x; 1.0296x over previous
//
#include <hip/hip_runtime.h>
#include <hip/hip_bf16.h>

#define H 4
#define D 32
#define HD 128
#define ND 10000
#define NG 30000
#define E_DG 150000
#define E_GD 150000
#define E_GG 300000
#define NE (E_DG + E_GD + E_GG)
#define EG (E_DG + E_GG)   // edges into gene nodes
#define NLAYER 2
#define NBG 30             // ceil(NG/1024)
#define NBD 10             // ceil(ND/1024)
#define OCG 640            // gene table cols:   [q|k1|v1|k2|v2]
#define OCD 384            // disease table cols:[q|k0|v0]
#define GOFF ((size_t)ND * OCD)   // gene rows offset in unified table
#define NSCAT 2344         // scatter blocks
#define NGEMM0 1250        // gemm0 blocks (2 mtiles each)
#define XLSTRIDE 136       // LDS A-row stride in f16 (mod-32-words = 4 -> 2x/bank-quad)

typedef _Float16 f16;
typedef __attribute__((ext_vector_type(2))) _Float16 f16x2;
typedef __attribute__((ext_vector_type(8))) _Float16 f16x8;
typedef __attribute__((ext_vector_type(8))) unsigned short u16x8;
typedef __attribute__((ext_vector_type(4))) float f32x4;

__device__ __forceinline__ float bu(unsigned short u) {
    return __uint_as_float(((unsigned)u) << 16);
}
// raw input load with dtype branch (isf32 wave-uniform)
__device__ __forceinline__ float ldraw(const void* p, size_t i, bool isf32) {
    return isf32 ? ((const float*)p)[i] : bu(((const unsigned short*)p)[i]);
}
__device__ __forceinline__ float gelu(float v) {
    const float c = 0.79788456080286536f * (v + 0.044715f * v * v * v);
    return 0.5f * v * (1.0f + tanhf(c));
}

// ---------------------------------------------------------------------------
// Combined-weight fold (rel matrices + prel*scale*log2e into K), raw inputs.
__device__ __forceinline__ void combine_one(
    int idx, int GENE, bool isf32,
    const void* W, const void* bvec,
    const void* arel, const void* mrel, const void* prel,
    f16* __restrict__ Wp, float* __restrict__ bp) {
    const int OC = GENE ? OCG : OCD;
    const int l = idx / (OC * 128);
    const int rem = idx - l * OC * 128;
    const int col = rem >> 7;
    const int d = rem & 127;
    const int g = col >> 7;           // 0=q, 1/3=k, 2/4=v
    const int jj = col & 127;
    const int h = jj >> 5, f = jj & 31;
    const size_t wbase = (size_t)l * 128 * 384;
    const size_t bbase = (size_t)l * 384;
    float val, bv = 0.f;
    if (g == 0) {
        val = ldraw(W, wbase + d * 384 + 128 + jj, isf32);
        bv = ldraw(bvec, bbase + 128 + jj, isf32);
    } else {
        const int et = GENE ? ((g <= 2) ? 1 : 2) : 0;
        const bool isk = (g & 1);
        const void* mat = isk ? arel : mrel;
        const size_t mbase = (((size_t)(l * 3 + et) * H + h) << 10) + f;
        const int sb = isk ? 0 : 256;
        val = 0.f;
        for (int dd = 0; dd < 32; dd++)
            val += ldraw(W, wbase + d * 384 + sb + h * 32 + dd, isf32) *
                   ldraw(mat, mbase + dd * 32, isf32);
        if (d == 0)
            for (int dd = 0; dd < 32; dd++)
                bv += ldraw(bvec, bbase + sb + h * 32 + dd, isf32) *
                      ldraw(mat, mbase + dd * 32, isf32);
        if (isk) {
            const float sc = ldraw(prel, (size_t)(l * 3 + et) * H + h, isf32) *
                             (0.17677669529663689f * 1.4426950408889634f);
            val *= sc;
            bv *= sc;
        }
    }
    Wp[(size_t)l * 4 * OC * 32 + ((size_t)(d >> 5) * OC + col) * 32 + (d & 31)] = (f16)val;
    if (d == 0) bp[l * OC + col] = bv;
}

// ---------------------------------------------------------------------------
// Mega-prep: self-detect dtype, fold+pack all weights, zero cnt/ready,
// convert bout, compute sigmoid(skip) gates, publish flag.
__global__ __launch_bounds__(256) void k_prep0(
    const void* x0,
    const void* wkqvd_r, const void* bkqvd_r,
    const void* wkqvg_r, const void* bkqvg_r,
    const void* arel_r, const void* mrel_r, const void* prel_r,
    const void* woutd_r, const void* woutg_r,
    const void* boutd_r, const void* boutg_r,
    const void* skipd_r, const void* skipg_r,
    f16* __restrict__ Wp_d, float* __restrict__ bp_d,
    f16* __restrict__ Wp_g, float* __restrict__ bp_g,
    f16* __restrict__ Wpod, f16* __restrict__ Wpog,
    float* __restrict__ boutc_d, float* __restrict__ boutc_g,
    float* __restrict__ gates, int* __restrict__ flag,
    int* __restrict__ cnt, int* __restrict__ ready) {
    const int tid = threadIdx.x;
    __shared__ int sbad;
    if (tid == 0) sbad = 0;
    __syncthreads();
    {
        const unsigned short* xs = (const unsigned short*)x0;
        int bad = 0;
        for (int i = tid; i < 1024; i += 256)
            if (!(fabsf(bu(xs[i])) < 1e6f)) bad = 1;
        if (bad) sbad = 1;   // benign race
    }
    __syncthreads();
    const bool isf32 = (sbad != 0);

    const int b = blockIdx.x;
    if (b < 1280) {
        int idx = b * 256 + tid;
        const int nd = NLAYER * OCD * 128;
        const int ng = NLAYER * OCG * 128;
        const int np = 2 * NLAYER * 128 * 128;
        if (idx < nd) {
            combine_one(idx, 0, isf32, wkqvd_r, bkqvd_r, arel_r, mrel_r, prel_r, Wp_d, bp_d);
        } else if ((idx -= nd) < ng) {
            combine_one(idx, 1, isf32, wkqvg_r, bkqvg_r, arel_r, mrel_r, prel_r, Wp_g, bp_g);
        } else if ((idx -= ng) < np) {
            const int type = idx >= NLAYER * 128 * 128;
            int rem = idx - type * NLAYER * 128 * 128;
            const int l = rem / (128 * 128);
            rem -= l * 128 * 128;
            const int d = rem >> 7, col = rem & 127;
            const float w = ldraw(type ? woutg_r : woutd_r,
                                  (size_t)l * 128 * 128 + d * 128 + col, isf32);
            f16* out = (type ? Wpog : Wpod) +
                ((size_t)l * 4 + (d >> 5)) * 128 * 32 + col * 32 + (d & 31);
            *out = (f16)w;
        }
    } else if (b == 1280) {
        if (tid < NBG + NBD) ready[tid] = 0;
        if (tid == 0) {
            flag[0] = isf32 ? 1 : 0;
            gates[0] = 1.f / (1.f + expf(-ldraw(skipd_r, 0, isf32)));
            gates[1] = 1.f / (1.f + expf(-ldraw(skipg_r, 0, isf32)));
            gates[2] = 1.f / (1.f + expf(-ldraw(skipd_r, 1, isf32)));
            gates[3] = 1.f / (1.f + expf(-ldraw(skipg_r, 1, isf32)));
        }
        for (int i = tid; i < NLAYER * 128; i += 256) {
            boutc_d[i] = ldraw(boutd_r, i, isf32);
            boutc_g[i] = ldraw(boutg_r, i, isf32);
        }
    } else {
        const int base = (b - 1281) * 1000;   // zero cnt[0..39999] (cnt_g||cnt_d)
        for (int i = tid; i < 1000; i += 256) cnt[base + i] = 0;
    }
}

// ---------------------------------------------------------------------------
// histogram of destinations
__global__ __launch_bounds__(256) void k_hist(
    const int* __restrict__ dst_dg, const int* __restrict__ dst_gg,
    const int* __restrict__ dst_gd,
    int* __restrict__ cnt_g, int* __restrict__ cnt_d) {
    const int i = blockIdx.x * 256 + threadIdx.x;
    if (i < E_DG) atomicAdd(cnt_g + dst_dg[i], 1);
    else if (i < EG) atomicAdd(cnt_g + dst_gg[i - E_DG], 1);
    else if (i < NE) atomicAdd(cnt_d + dst_gd[i - EG], 1);
}

// ---------------------------------------------------------------------------
// Single-dispatch scan via decoupled lookback (40 co-resident blocks; block
// sum packed into the ready word as S+1).
__global__ __launch_bounds__(256) void k_scan(
    const int* __restrict__ cnt_g, const int* __restrict__ cnt_d,
    int* __restrict__ ready,
    int* __restrict__ rp_g, int* __restrict__ cur_g,
    int* __restrict__ rp_d, int* __restrict__ cur_d) {
    const int b = blockIdx.x;
    const int tid = threadIdx.x;
    const bool isg = (b < NBG);
    const int* cnt = isg ? cnt_g : cnt_d;
    int* rp = isg ? rp_g : rp_d;
    int* cur = isg ? cur_g : cur_d;
    const int n = isg ? NG : ND;
    const int lb = isg ? b : (b - NBG);
    const int i0 = lb * 1024 + tid * 4;
    int v[4];
    int t = 0;
#pragma unroll
    for (int j = 0; j < 4; j++) {
        v[j] = (i0 + j < n) ? cnt[i0 + j] : 0;
        t += v[j];
    }
    __shared__ int sdata[256];
    __shared__ int red2[256];
    __shared__ int s_off;
    sdata[tid] = t;
    __syncthreads();
    for (int d = 1; d < 256; d <<= 1) {
        const int u = (tid >= d) ? sdata[tid - d] : 0;
        __syncthreads();
        sdata[tid] += u;
        __syncthreads();
    }
    const int total = sdata[255];
    if (tid == 0) atomicExch(&ready[b], total + 1);
    const int p0 = isg ? 0 : NBG;
    const int npred = b - p0;
    int part = 0;
    for (int i = tid; i < npred; i += 256) {
        int vv;
        do { vv = atomicAdd(&ready[p0 + i], 0); } while (vv == 0);
        part += vv - 1;
    }
    red2[tid] = part;
    __syncthreads();
    for (int d = 128; d > 0; d >>= 1) {
        if (tid < d) red2[tid] += red2[tid + d];
        __syncthreads();
    }
    if (tid == 0) s_off = red2[0];
    __syncthreads();
    int run = s_off + sdata[tid] - t;
#pragma unroll
    for (int j = 0; j < 4; j++) {
        if (i0 + j < n) {
            cur[i0 + j] = run;
            run += v[j];
            rp[i0 + j + 1] = run;
        }
    }
    if (tid == 0 && lb == 0) rp[0] = 0;
}

// ---------------------------------------------------------------------------
// Fused scatter (blocks [0,NSCAT)) + layer-0 KQV GEMM (blocks [NSCAT,..)).
// GEMM: one block = 2 mtiles; raw x staged once into padded LDS (f16),
// waves loop over nt tiles. Kills the per-nt redundant A fetch.
__global__ __launch_bounds__(256) void k_scatter_gemm0(
    const int* __restrict__ src_dg, const int* __restrict__ dst_dg,
    const int* __restrict__ src_gg, const int* __restrict__ dst_gg,
    const int* __restrict__ src_gd, const int* __restrict__ dst_gd,
    int* __restrict__ cur_g, int* __restrict__ cur_d,
    int* __restrict__ edges_g, int* __restrict__ edges_d,
    const void* xd_r, const void* xg_r, const int* __restrict__ flag,
    const f16* __restrict__ Wpd, const float* __restrict__ bpd,
    const f16* __restrict__ Wpg, const float* __restrict__ bpg,
    f16* __restrict__ tab) {
    __shared__ f16 xls[32 * XLSTRIDE];
    if (blockIdx.x < NSCAT) {
        const int i = blockIdx.x * 256 + threadIdx.x;
        if (i < E_DG) {
            const int pos = atomicAdd(cur_g + dst_dg[i], 1);
            edges_g[pos] = src_dg[i] * OCD + 128;                 // et0: d->g
        } else if (i < EG) {
            const int j = i - E_DG;
            const int pos = atomicAdd(cur_g + dst_gg[j], 1);
            edges_g[pos] = (int)GOFF + src_gg[j] * OCG + 384;     // et2: g->g
        } else if (i < NE) {
            const int j = i - EG;
            const int pos = atomicAdd(cur_d + dst_gd[j], 1);
            edges_d[pos] = (int)GOFF + src_gd[j] * OCG + 128;     // et1: g->d
        }
        return;
    }
    const bool isf32 = (*flag != 0);
    const int tid = threadIdx.x;
    const int mt0 = (blockIdx.x - NSCAT) * 2;
    // stage A: 32 rows x 128 cols -> LDS f16 (padded rows)
    for (int i = tid; i < 1024; i += 256) {
        const int row = i >> 5;
        const int c4 = (i & 31) * 4;
        const int gnode = mt0 * 16 + row;
        const bool gene = (gnode >= ND);
        const void* xr = gene ? xg_r : xd_r;
        const size_t base = (size_t)(gene ? gnode - ND : gnode) * 128 + c4;
        float4 v;
        if (isf32) {
            v = *(const float4*)((const float*)xr + base);
        } else {
            const ushort4 u = *(const ushort4*)((const unsigned short*)xr + base);
            v = make_float4(bu(u.x), bu(u.y), bu(u.z), bu(u.w));
        }
        f16* dst = xls + row * XLSTRIDE + c4;
        dst[0] = (f16)v.x; dst[1] = (f16)v.y; dst[2] = (f16)v.z; dst[3] = (f16)v.w;
    }
    __syncthreads();

    const int wv = tid >> 6, lane = tid & 63;
    const int r = lane & 15, q4 = lane >> 4;
    const int n0 = (mt0 * 16 >= ND) ? 10 : 6;
    const int n1 = ((mt0 + 1) * 16 >= ND) ? 10 : 6;
    for (int it = wv; it < n0 + n1; it += 4) {
        const int mtl = (it < n0) ? 0 : 1;
        const int ntl = (it < n0) ? it : (it - n0);
        const int node0 = (mt0 + mtl) * 16;
        const bool gene = (node0 >= ND);
        const int OC = gene ? OCG : OCD;
        const f16* Wp = gene ? Wpg : Wpd;
        const float* bias = gene ? bpg : bpd;
        f16* out = gene ? (tab + GOFF) : tab;
        const int trow0 = node0 - (gene ? ND : 0);
        const int col0 = ntl << 6;
        f32x4 acc0 = {0.f, 0.f, 0.f, 0.f};
        f32x4 acc1 = acc0, acc2 = acc0, acc3 = acc0;
#pragma unroll
        for (int kb = 0; kb < 4; kb++) {
            const f16x8 a = *(const f16x8*)(xls + (mtl * 16 + r) * XLSTRIDE + kb * 32 + q4 * 8);
            const f16* wb = Wp + ((size_t)kb * OC + col0 + r) * 32 + q4 * 8;
            const f16x8 b0 = *(const f16x8*)(wb);
            const f16x8 b1 = *(const f16x8*)(wb + 512);
            const f16x8 b2 = *(const f16x8*)(wb + 1024);
            const f16x8 b3 = *(const f16x8*)(wb + 1536);
            acc0 = __builtin_amdgcn_mfma_f32_16x16x32_f16(a, b0, acc0, 0, 0, 0);
            acc1 = __builtin_amdgcn_mfma_f32_16x16x32_f16(a, b1, acc1, 0, 0, 0);
            acc2 = __builtin_amdgcn_mfma_f32_16x16x32_f16(a, b2, acc2, 0, 0, 0);
            acc3 = __builtin_amdgcn_mfma_f32_16x16x32_f16(a, b3, acc3, 0, 0, 0);
        }
        const f32x4 accs[4] = {acc0, acc1, acc2, acc3};
#pragma unroll
        for (int t = 0; t < 4; t++) {
            const int col = col0 + t * 16 + r;
            const float bb = bias[col];
#pragma unroll
            for (int reg = 0; reg < 4; reg++)
                out[(size_t)(trow0 + q4 * 4 + reg) * OC + col] = (f16)(accs[t][reg] + bb);
        }
    }
}

// ---------------------------------------------------------------------------
// Unified gather aggregation. No online-max: logits are bounded (|a|<~6 in
// log2 domain, exp2 range +-127), softmax is shift-invariant, so plain
// exp2 accumulation is exact enough and saves the rescale chain.
__global__ __launch_bounds__(256) void k_agg(
    const int* __restrict__ rp_g, const int* __restrict__ edges_g,
    const int* __restrict__ rp_d, const int* __restrict__ edges_d,
    const f16* __restrict__ tab, f16* __restrict__ gagg) {
    const int wid = blockIdx.x * 4 + (threadIdx.x >> 6);
    const int lane = threadIdx.x & 63;
    const int slot = lane >> 4, sub = lane & 15;

    int node, row;
    const int *rp, *edges;
    size_t qoff;
    if (wid < NG) {
        node = wid; rp = rp_g; edges = edges_g;
        qoff = GOFF + (size_t)node * OCG;
        row = ND + node;
    } else {
        node = wid - NG; rp = rp_d; edges = edges_d;
        qoff = (size_t)node * OCD;
        row = node;
    }

    union U { f16x8 v; f16x2 p[4]; };
    U q;
    q.v = *(const f16x8*)(tab + qoff + sub * 8);

    float s = 0.f;
    float acc[8];
#pragma unroll
    for (int i = 0; i < 8; i++) acc[i] = 0.f;

    const int r0 = rp[node], r1 = rp[node + 1];
    int e = r0 + slot;

    auto kvload = [&](int rec, U& k, U& v) {
        const f16* p = tab + (size_t)rec + sub * 8;
        k.v = *(const f16x8*)p;
        v.v = *(const f16x8*)(p + 128);
    };

    int recA0 = (e < r1) ? edges[e] : 0;
    int recB0 = (e + 4 < r1) ? edges[e + 4] : 0;
    U kA0, vA0, kB0, vB0;
    kvload(recA0, kA0, vA0);
    kvload(recB0, kB0, vB0);
    int recA1 = (e + 8 < r1) ? edges[e + 8] : 0;
    int recB1 = (e + 12 < r1) ? edges[e + 12] : 0;

    while (e < r1) {
        const int recA2 = (e + 16 < r1) ? edges[e + 16] : 0;
        const int recB2 = (e + 20 < r1) ? edges[e + 20] : 0;
        U kA1, vA1, kB1, vB1;
        kvload(recA1, kA1, vA1);
        kvload(recB1, kB1, vB1);

        float pA = __builtin_amdgcn_fdot2(q.p[0], kA0.p[0], 0.f, false);
        float pB = __builtin_amdgcn_fdot2(q.p[0], kB0.p[0], 0.f, false);
        pA = __builtin_amdgcn_fdot2(q.p[1], kA0.p[1], pA, false);
        pB = __builtin_amdgcn_fdot2(q.p[1], kB0.p[1], pB, false);
        pA = __builtin_amdgcn_fdot2(q.p[2], kA0.p[2], pA, false);
        pB = __builtin_amdgcn_fdot2(q.p[2], kB0.p[2], pB, false);
        pA = __builtin_amdgcn_fdot2(q.p[3], kA0.p[3], pA, false);
        pB = __builtin_amdgcn_fdot2(q.p[3], kB0.p[3], pB, false);
        pA += __shfl_xor(pA, 1);
        pB += __shfl_xor(pB, 1);
        pA += __shfl_xor(pA, 2);
        pB += __shfl_xor(pB, 2);
        const float eaA = exp2f(pA);
        const float eaB = (e + 4 < r1) ? exp2f(pB) : 0.f;
        s += eaA + eaB;
#pragma unroll
        for (int i = 0; i < 8; i++)
            acc[i] = fmaf(eaB, (float)vB0.v[i], fmaf(eaA, (float)vA0.v[i], acc[i]));
        recA0 = recA1; recB0 = recB1; recA1 = recA2; recB1 = recB2;
        kA0 = kA1; vA0 = vA1; kB0 = kB1; vB0 = vB1;
        e += 8;
    }

    // merge the 4 slot-chains (plain sums)
#pragma unroll
    for (int mask = 16; mask <= 32; mask <<= 1) {
        s += __shfl_xor(s, mask);
#pragma unroll
        for (int i = 0; i < 8; i++) acc[i] += __shfl_xor(acc[i], mask);
    }

    const float inv = (s > 0.f) ? (1.f / s) : 0.f;
    if (slot == 0) {
        f16x8 o;
#pragma unroll
        for (int i = 0; i < 8; i++) o[i] = (f16)gelu(acc[i] * inv);
        *(f16x8*)(gagg + (size_t)row * HD + sub * 8) = o;
    }
}

// ---------------------------------------------------------------------------
// Fused layer-0 update + layer-1 KQV GEMM. Block = 32 nodes (2 mtiles).
__global__ __launch_bounds__(256) void k_updgemm(
    const f16* __restrict__ gagg,
    const f16* __restrict__ Wpod0, const f16* __restrict__ Wpog0,
    const float* __restrict__ boutc_d0, const float* __restrict__ boutc_g0,
    const float* __restrict__ gates,   // [0]=d0 [1]=g0
    const void* xd_r, const void* xg_r, const int* __restrict__ flag,
    f16* __restrict__ xball,
    const f16* __restrict__ Wpd1, const float* __restrict__ bpd1,
    const f16* __restrict__ Wpg1, const float* __restrict__ bpg1,
    f16* __restrict__ tab) {
    __shared__ f16 xls[32 * XLSTRIDE];
    const bool isf32 = (*flag != 0);
    const int tid = threadIdx.x;
    const int wv = tid >> 6, lane = tid & 63;
    const int r = lane & 15, q4 = lane >> 4;

    // ---- phase 1: update ----
    {
        const int mtl = wv >> 1, nt = wv & 1;
        const int mtile = blockIdx.x * 2 + mtl;
        const int node0 = mtile * 16;
        const bool gene = (node0 >= ND);
        const f16* Wp = gene ? Wpog0 : Wpod0;
        const float* bias = gene ? boutc_g0 : boutc_d0;
        const float g = gates[gene ? 1 : 0];
        const int col0 = nt << 6;
        f32x4 acc0 = {0.f, 0.f, 0.f, 0.f};
        f32x4 acc1 = acc0, acc2 = acc0, acc3 = acc0;
#pragma unroll
        for (int kb = 0; kb < 4; kb++) {
            const f16x8 a = *(const f16x8*)(gagg + (size_t)(node0 + r) * 128 + kb * 32 + q4 * 8);
            const f16* wb = Wp + ((size_t)kb * 128 + col0 + r) * 32 + q4 * 8;
            const f16x8 b0 = *(const f16x8*)(wb);
            const f16x8 b1 = *(const f16x8*)(wb + 512);
            const f16x8 b2 = *(const f16x8*)(wb + 1024);
            const f16x8 b3 = *(const f16x8*)(wb + 1536);
            acc0 = __builtin_amdgcn_mfma_f32_16x16x32_f16(a, b0, acc0, 0, 0, 0);
            acc1 = __builtin_amdgcn_mfma_f32_16x16x32_f16(a, b1, acc1, 0, 0, 0);
            acc2 = __builtin_amdgcn_mfma_f32_16x16x32_f16(a, b2, acc2, 0, 0, 0);
            acc3 = __builtin_amdgcn_mfma_f32_16x16x32_f16(a, b3, acc3, 0, 0, 0);
        }
        const f32x4 accs[4] = {acc0, acc1, acc2, acc3};
        const void* xr = gene ? xg_r : xd_r;
        const int lrow0 = node0 - (gene ? ND : 0);
#pragma unroll
        for (int t = 0; t < 4; t++) {
            const int col = col0 + t * 16 + r;
            const float bb = bias[col];
#pragma unroll
            for (int reg = 0; reg < 4; reg++) {
                const int rr = q4 * 4 + reg;
                const float xo = ldraw(xr, (size_t)(lrow0 + rr) * 128 + col, isf32);
                const float xn = g * (accs[t][reg] + bb) + (1.f - g) * xo;
                xls[(mtl * 16 + rr) * XLSTRIDE + col] = (f16)xn;
                xball[(size_t)(node0 + rr) * 128 + col] = (f16)xn;
            }
        }
    }
    __syncthreads();

    // ---- phase 2: layer-1 KQV GEMM from LDS ----
    const int mt0 = blockIdx.x * 2;
    const int n0 = ((mt0 * 16) >= ND) ? 10 : 6;
    const int n1 = (((mt0 + 1) * 16) >= ND) ? 10 : 6;
    for (int it = wv; it < n0 + n1; it += 4) {
        const int mtl = (it < n0) ? 0 : 1;
        const int ntl = (it < n0) ? it : (it - n0);
        const int node0 = (mt0 + mtl) * 16;
        const bool gene = (node0 >= ND);
        const int OC = gene ? OCG : OCD;
        const f16* Wp = gene ? Wpg1 : Wpd1;
        const float* bias = gene ? bpg1 : bpd1;
        f16* out = gene ? (tab + GOFF) : tab;
        const int trow0 = node0 - (gene ? ND : 0);
        const int col0 = ntl << 6;
        f32x4 acc0 = {0.f, 0.f, 0.f, 0.f};
        f32x4 acc1 = acc0, acc2 = acc0, acc3 = acc0;
#pragma unroll
        for (int kb = 0; kb < 4; kb++) {
            const f16x8 a = *(const f16x8*)(xls + (mtl * 16 + r) * XLSTRIDE + kb * 32 + q4 * 8);
            const f16* wb = Wp + ((size_t)kb * OC + col0 + r) * 32 + q4 * 8;
            const f16x8 b0 = *(const f16x8*)(wb);
            const f16x8 b1 = *(const f16x8*)(wb + 512);
            const f16x8 b2 = *(const f16x8*)(wb + 1024);
            const f16x8 b3 = *(const f16x8*)(wb + 1536);
            acc0 = __builtin_amdgcn_mfma_f32_16x16x32_f16(a, b0, acc0, 0, 0, 0);
            acc1 = __builtin_amdgcn_mfma_f32_16x16x32_f16(a, b1, acc1, 0, 0, 0);
            acc2 = __builtin_amdgcn_mfma_f32_16x16x32_f16(a, b2, acc2, 0, 0, 0);
            acc3 = __builtin_amdgcn_mfma_f32_16x16x32_f16(a, b3, acc3, 0, 0, 0);
        }
        const f32x4 accs[4] = {acc0, acc1, acc2, acc3};
#pragma unroll
        for (int t = 0; t < 4; t++) {
            const int col = col0 + t * 16 + r;
            const float bb = bias[col];
#pragma unroll
            for (int reg = 0; reg < 4; reg++)
                out[(size_t)(trow0 + q4 * 4 + reg) * OC + col] = (f16)(accs[t][reg] + bb);
        }
    }
}

// ---------------------------------------------------------------------------
// Final update (layer 1): o = gagg @ Wout1 + b; dout = g*o + (1-g)*x1 (f16).
__global__ __launch_bounds__(256) void k_upd1(
    const f16* __restrict__ gagg,
    const f16* __restrict__ Wpod1, const f16* __restrict__ Wpog1,
    const float* __restrict__ boutc_d1, const float* __restrict__ boutc_g1,
    const float* __restrict__ gates,   // [0]=d1 [1]=g1 (pre-offset)
    const f16* __restrict__ xball, float* __restrict__ dout) {
    const int w = blockIdx.x * 4 + (threadIdx.x >> 6);
    const int nt = w / 2500, mt = w - nt * 2500;
    const int node0 = mt << 4;
    const bool gene = (node0 >= ND);
    const f16* Wp = gene ? Wpog1 : Wpod1;
    const float* bias = gene ? boutc_g1 : boutc_d1;
    const float g = gates[gene ? 1 : 0];
    const int lane = threadIdx.x & 63;
    const int r = lane & 15, q4 = lane >> 4;
    const int col0 = nt << 6;
    f32x4 acc0 = {0.f, 0.f, 0.f, 0.f};
    f32x4 acc1 = acc0, acc2 = acc0, acc3 = acc0;
#pragma unroll
    for (int kb = 0; kb < 4; kb++) {
        const f16x8 a = *(const f16x8*)(gagg + (size_t)(node0 + r) * 128 + kb * 32 + q4 * 8);
        const f16* wb = Wp + ((size_t)kb * 128 + col0 + r) * 32 + q4 * 8;
        const f16x8 b0 = *(const f16x8*)(wb);
        const f16x8 b1 = *(const f16x8*)(wb + 512);
        const f16x8 b2 = *(const f16x8*)(wb + 1024);
        const f16x8 b3 = *(const f16x8*)(wb + 1536);
        acc0 = __builtin_amdgcn_mfma_f32_16x16x32_f16(a, b0, acc0, 0, 0, 0);
        acc1 = __builtin_amdgcn_mfma_f32_16x16x32_f16(a, b1, acc1, 0, 0, 0);
        acc2 = __builtin_amdgcn_mfma_f32_16x16x32_f16(a, b2, acc2, 0, 0, 0);
        acc3 = __builtin_amdgcn_mfma_f32_16x16x32_f16(a, b3, acc3, 0, 0, 0);
    }
    const f32x4 accs[4] = {acc0, acc1, acc2, acc3};
#pragma unroll
    for (int t = 0; t < 4; t++) {
        const int col = col0 + t * 16 + r;
        const float bb = bias[col];
#pragma unroll
        for (int reg = 0; reg < 4; reg++) {
            const size_t idx = (size_t)(node0 + q4 * 4 + reg) * 128 + col;
            dout[idx] = g * (accs[t][reg] + bb) + (1.f - g) * (float)xball[idx];
        }
    }
}

// ---------------------------------------------------------------------------
static inline size_t alignup(size_t v) { return (v + 15) & ~(size_t)15; }

extern "C" void kernel_launch(void* const* d_in, const int* in_sizes, int n_in,
                              void* d_out, int out_size, void* d_ws, size_t ws_size,
                              hipStream_t stream) {
    (void)in_sizes; (void)n_in; (void)out_size; (void)ws_size;
    const int* src_dg = (const int*)d_in[2];
    const int* dst_dg = (const int*)d_in[3];
    const int* src_gd = (const int*)d_in[4];
    const int* dst_gd = (const int*)d_in[5];
    const int* src_gg = (const int*)d_in[6];
    const int* dst_gg = (const int*)d_in[7];

    // ---- workspace carve-up ----
    float* ws = (float*)d_ws;
    int* flag = (int*)ws; ws += 16;
    int* cnt_g  = (int*)ws; ws += alignup(NG);   // cnt_g||cnt_d contiguous
    int* cnt_d  = (int*)ws; ws += alignup(ND);
    int* rp_g   = (int*)ws; ws += alignup(NG + 1);
    int* rp_d   = (int*)ws; ws += alignup(ND + 1);
    int* cur_g  = (int*)ws; ws += alignup(NG);
    int* cur_d  = (int*)ws; ws += alignup(ND);
    int* ready  = (int*)ws; ws += 64;
    int* edges_g = (int*)ws; ws += alignup(EG);
    int* edges_d = (int*)ws; ws += alignup(E_GD);
    float* bp_d = ws; ws += alignup((size_t)NLAYER * OCD);
    float* bp_g = ws; ws += alignup((size_t)NLAYER * OCG);
    float* boutc_d = ws; ws += alignup((size_t)NLAYER * 128);
    float* boutc_g = ws; ws += alignup((size_t)NLAYER * 128);
    float* gates = ws; ws += 16;
    f16* Wp_d = (f16*)ws; ws += alignup((size_t)NLAYER * 4 * OCD * 32 / 2);
    f16* Wp_g = (f16*)ws; ws += alignup((size_t)NLAYER * 4 * OCG * 32 / 2);
    f16* Wpod = (f16*)ws; ws += alignup((size_t)NLAYER * 4 * 128 * 32 / 2);
    f16* Wpog = (f16*)ws; ws += alignup((size_t)NLAYER * 4 * 128 * 32 / 2);
    f16* xball = (f16*)ws; ws += alignup((size_t)(ND + NG) * HD / 2);
    f16* gagg  = (f16*)ws; ws += alignup((size_t)(ND + NG) * HD / 2);
    f16* tab   = (f16*)ws; ws += alignup(((size_t)ND * OCD + (size_t)NG * OCG) / 2);

    // 1) mega-prep
    k_prep0<<<1321, 256, 0, stream>>>(
        d_in[0],
        d_in[8], d_in[9], d_in[10], d_in[11],
        d_in[18], d_in[19], d_in[20],
        d_in[12], d_in[14], d_in[13], d_in[15], d_in[16], d_in[17],
        Wp_d, bp_d, Wp_g, bp_g, Wpod, Wpog, boutc_d, boutc_g,
        gates, flag, cnt_g, ready);
    // 2) histogram
    k_hist<<<NSCAT, 256, 0, stream>>>(dst_dg, dst_gg, dst_gd, cnt_g, cnt_d);
    // 3) single-dispatch lookback scan
    k_scan<<<NBG + NBD, 256, 0, stream>>>(cnt_g, cnt_d, ready, rp_g, cur_g, rp_d, cur_d);
    // 4) scatter + layer-0 KQV GEMM (LDS-staged A)
    k_scatter_gemm0<<<NSCAT + NGEMM0, 256, 0, stream>>>(
        src_dg, dst_dg, src_gg, dst_gg, src_gd, dst_gd,
        cur_g, cur_d, edges_g, edges_d,
        d_in[0], d_in[1], flag,
        Wp_d, bp_d, Wp_g, bp_g, tab);
    // 5) layer-0 aggregation
    k_agg<<<(NG + ND) / 4, 256, 0, stream>>>(rp_g, edges_g, rp_d, edges_d, tab, gagg);
    // 6) layer-0 update fused with layer-1 KQV GEMM
    k_updgemm<<<(ND + NG) / 32, 256, 0, stream>>>(
        gagg, Wpod, Wpog, boutc_d, boutc_g, gates,
        d_in[0], d_in[1], flag, xball,
        Wp_d + (size_t)4 * OCD * 32, bp_d + OCD,
        Wp_g + (size_t)4 * OCG * 32, bp_g + OCG, tab);
    // 7) layer-1 aggregation
    k_agg<<<(NG + ND) / 4, 256, 0, stream>>>(rp_g, edges_g, rp_d, edges_d, tab, gagg);
    // 8) final update -> d_out (fp32)
    k_upd1<<<(ND + NG) / 32, 256, 0, stream>>>(
        gagg, Wpod + (size_t)4 * 128 * 32, Wpog + (size_t)4 * 128 * 32,
        boutc_d + 128, boutc_g + 128, gates + 2, xball, (float*)d_out);
}